// Round 1
// baseline (338.967 us; speedup 1.0000x reference)
//
#include <hip/hip_runtime.h>
#include <hip/hip_bf16.h>
#include <cstdint>

typedef __hip_bfloat16 bf16;
typedef __attribute__((ext_vector_type(8))) short short8;
typedef __attribute__((ext_vector_type(4))) float f32x4;

#define T_   2048
#define CDIM 2048
#define NH   16
#define NKV  4
#define HD   128

__device__ __forceinline__ void gload_lds16(const void* g, void* l) {
  __builtin_amdgcn_global_load_lds(
      (const __attribute__((address_space(1))) void*)g,
      (__attribute__((address_space(3))) void*)l, 16, 0, 0);
}

// ---------------- cast x (fp32 -> bf16), vectorized ----------------
__global__ __launch_bounds__(256) void cast_x_kernel(const float4* __restrict__ in,
                                                     ushort4* __restrict__ out, int n4) {
  int i = blockIdx.x * 256 + threadIdx.x;
  if (i >= n4) return;
  float4 v = in[i];
  union { bf16 h[4]; ushort4 u; } cv;
  cv.h[0] = __float2bfloat16(v.x);
  cv.h[1] = __float2bfloat16(v.y);
  cv.h[2] = __float2bfloat16(v.z);
  cv.h[3] = __float2bfloat16(v.w);
  out[i] = cv.u;
}

// ---------------- cast + transpose W[K][N] fp32 -> WT[N][K] bf16 ----------------
__global__ __launch_bounds__(256) void cast_transpose(const float* __restrict__ W,
                                                      bf16* __restrict__ WT,
                                                      int K, int N) {
  __shared__ float tile[32][33];
  int k0 = blockIdx.y * 32, n0 = blockIdx.x * 32;
  int r = threadIdx.x >> 5, c = threadIdx.x & 31;  // r:0..7
  for (int i = 0; i < 4; ++i)
    tile[r + i * 8][c] = W[(size_t)(k0 + r + i * 8) * N + n0 + c];
  __syncthreads();
  for (int i = 0; i < 4; ++i)
    WT[(size_t)(n0 + r + i * 8) * K + k0 + c] = __float2bfloat16(tile[c][r + i * 8]);
}

// ---------------- GEMM: A[M][K] bf16 * BT[N][K] bf16 -> C[M][N] fp32 ----------------
// m97 structure: 128x128 tile, BK=32, 4 waves of 64x64, global_load_lds width 16.
__global__ __launch_bounds__(256) void gemm_bt(const bf16* __restrict__ A,
                                               const bf16* __restrict__ BT,
                                               float* __restrict__ C,
                                               int M, int N, int K) {
  __shared__ __align__(16) bf16 sA[128 * 32];
  __shared__ __align__(16) bf16 sB[128 * 32];
  int tid = threadIdx.x;
  int lane = tid & 63, w = tid >> 6;
  int wm = w >> 1, wn = w & 1;
  int lr = lane & 15, lk = lane >> 4;
  int m0 = blockIdx.y * 128, n0 = blockIdx.x * 128;

  f32x4 acc[4][4];
  for (int m = 0; m < 4; ++m)
    for (int n = 0; n < 4; ++n) acc[m][n] = (f32x4){0.f, 0.f, 0.f, 0.f};

  int nk = K >> 5;
  for (int kt = 0; kt < nk; ++kt) {
    int kb = kt << 5;
    for (int i = 0; i < 2; ++i) {
      int c = i * 256 + tid;
      int r = c >> 2;            // 4 x 16B chunks per 32-elem row
      int off = (c & 3) * 8;
      gload_lds16(A + (size_t)(m0 + r) * K + kb + off, (char*)sA + c * 16);
      gload_lds16(BT + (size_t)(n0 + r) * K + kb + off, (char*)sB + c * 16);
    }
    __syncthreads();
    short8 af[4], bfr[4];
    for (int m = 0; m < 4; ++m)
      af[m] = *(const short8*)(sA + (wm * 64 + m * 16 + lr) * 32 + lk * 8);
    for (int n = 0; n < 4; ++n)
      bfr[n] = *(const short8*)(sB + (wn * 64 + n * 16 + lr) * 32 + lk * 8);
    for (int m = 0; m < 4; ++m)
      for (int n = 0; n < 4; ++n)
        acc[m][n] = __builtin_amdgcn_mfma_f32_16x16x32_bf16(af[m], bfr[n], acc[m][n], 0, 0, 0);
    __syncthreads();
  }
  for (int m = 0; m < 4; ++m)
    for (int n = 0; n < 4; ++n)
      for (int jj = 0; jj < 4; ++jj)
        C[(size_t)(m0 + wm * 64 + m * 16 + lk * 4 + jj) * N + n0 + wn * 64 + n * 16 + lr] =
            acc[m][n][jj];
}

// ---------------- epilogue: gate, v-update(+transpose), RoPE + RMSNorm ----------------
__global__ __launch_bounds__(256) void epilogue_kernel(
    const float* __restrict__ qkv, const float* __restrict__ x,
    const float* __restrict__ ve, const float* __restrict__ cosT,
    const float* __restrict__ sinT, const float* __restrict__ Wg,
    bf16* __restrict__ qn, bf16* __restrict__ kn, bf16* __restrict__ vT) {
  int row = blockIdx.x;               // b*T + t
  int bi = row >> 11, t = row & 2047; // T_=2048
  int tid = threadIdx.x, lane = tid & 63, w = tid >> 6;
  __shared__ float gate[NKV];
  size_t rb = (size_t)row * 3072;

  if (tid < 128) {
    int g = tid >> 5, i = tid & 31;
    float p = x[(size_t)row * CDIM + i] * Wg[i * 4 + g];
    p += __shfl_xor(p, 1);  p += __shfl_xor(p, 2);
    p += __shfl_xor(p, 4);  p += __shfl_xor(p, 8);
    p += __shfl_xor(p, 16);
    if (i == 0) gate[g] = 2.f / (1.f + __expf(-p));
  }
  __syncthreads();

  float cv = cosT[t * 64 + lane];
  float sv = sinT[t * 64 + lane];

  // q heads: 4 iterations x 4 waves
  for (int it = 0; it < 4; ++it) {
    int h = it * 4 + w;
    float x1 = qkv[rb + h * 128 + lane];
    float x2 = qkv[rb + h * 128 + 64 + lane];
    float y1 = x1 * cv + x2 * sv;
    float y2 = x2 * cv - x1 * sv;
    float ss = y1 * y1 + y2 * y2;
    ss += __shfl_xor(ss, 1);  ss += __shfl_xor(ss, 2);  ss += __shfl_xor(ss, 4);
    ss += __shfl_xor(ss, 8);  ss += __shfl_xor(ss, 16); ss += __shfl_xor(ss, 32);
    float r = rsqrtf(ss * (1.f / 128.f) + 1e-6f);
    size_t ob = (size_t)row * (NH * HD) + h * 128;
    qn[ob + lane] = __float2bfloat16(y1 * r);
    qn[ob + 64 + lane] = __float2bfloat16(y2 * r);
  }
  // k heads (4 kv heads, one per wave)
  {
    int h = w;
    float x1 = qkv[rb + 2048 + h * 128 + lane];
    float x2 = qkv[rb + 2048 + h * 128 + 64 + lane];
    float y1 = x1 * cv + x2 * sv;
    float y2 = x2 * cv - x1 * sv;
    float ss = y1 * y1 + y2 * y2;
    ss += __shfl_xor(ss, 1);  ss += __shfl_xor(ss, 2);  ss += __shfl_xor(ss, 4);
    ss += __shfl_xor(ss, 8);  ss += __shfl_xor(ss, 16); ss += __shfl_xor(ss, 32);
    float r = rsqrtf(ss * (1.f / 128.f) + 1e-6f);
    size_t ob = (size_t)row * (NKV * HD) + h * 128;
    kn[ob + lane] = __float2bfloat16(y1 * r);
    kn[ob + 64 + lane] = __float2bfloat16(y2 * r);
  }
  // v update + transpose to [b][kv][d][t]
  for (int e = tid; e < 512; e += 256) {
    int kv = e >> 7, d = e & 127;
    float val = qkv[rb + 2560 + e] + gate[kv] * ve[(size_t)row * 512 + e];
    vT[((size_t)(bi * NKV + kv) * HD + d) * T_ + t] = __float2bfloat16(val);
  }
}

// ---------------- flash attention, forward window ----------------
// grid: (T/64, NH, B), block 256 (4 waves x 16 q-rows each), KV tile = 32
__global__ __launch_bounds__(256) void attn_kernel(
    const bf16* __restrict__ qn, const bf16* __restrict__ kn,
    const bf16* __restrict__ vT, bf16* __restrict__ y,
    const int* __restrict__ winp) {
  __shared__ __align__(16) bf16 sK[32 * 128];  // [kv][d]
  __shared__ __align__(16) bf16 sV[128 * 32];  // [d][kv]
  __shared__ __align__(16) bf16 sP[4][16 * 32];

  int win = *winp;
  int q0 = blockIdx.x * 64;
  int h = blockIdx.y;
  int bi = blockIdx.z;
  int kvh = h >> 2;
  int tid = threadIdx.x;
  int lane = tid & 63, w = tid >> 6;
  int lr = lane & 15, lk = lane >> 4;

  short8 qf[4];
  {
    const bf16* qrow = qn + (size_t)(bi * T_ + q0 + w * 16 + lr) * (NH * HD) + h * HD;
    for (int c = 0; c < 4; ++c) qf[c] = *(const short8*)(qrow + c * 32 + lk * 8);
  }

  f32x4 o[8];
  for (int i = 0; i < 8; ++i) o[i] = (f32x4){0.f, 0.f, 0.f, 0.f};
  float mrun[4], lrun[4];
  for (int j = 0; j < 4; ++j) { mrun[j] = -__builtin_inff(); lrun[j] = 0.f; }

  // forward window: query i attends keys j with j>=i && j-i<win
  int jt0 = q0 >> 5;
  int hi = q0 + 62 + win; if (hi > T_ - 1) hi = T_ - 1;
  int jt1 = hi >> 5;
  const float scale = 0.08838834764831845f;  // 1/sqrt(128)
  const float NEGINF = -__builtin_inff();

  for (int jt = jt0; jt <= jt1; ++jt) {
    int j0 = jt << 5;
    // stage K tile [32][128] and V^T tile [128][32]
    for (int i = 0; i < 2; ++i) {
      int c = i * 256 + tid;
      int r = c >> 4, off = (c & 15) * 8;
      gload_lds16(kn + (size_t)(bi * T_ + j0 + r) * (NKV * HD) + kvh * HD + off,
                  (char*)sK + c * 16);
    }
    for (int i = 0; i < 2; ++i) {
      int c = i * 256 + tid;
      int d = c >> 2, off = (c & 3) * 8;
      gload_lds16(vT + ((size_t)(bi * NKV + kvh) * HD + d) * T_ + j0 + off,
                  (char*)sV + c * 16);
    }
    __syncthreads();

    f32x4 s0 = (f32x4){0.f, 0.f, 0.f, 0.f}, s1 = (f32x4){0.f, 0.f, 0.f, 0.f};
    for (int c = 0; c < 4; ++c) {
      short8 kf0 = *(const short8*)(sK + (0 * 16 + lr) * 128 + c * 32 + lk * 8);
      short8 kf1 = *(const short8*)(sK + (1 * 16 + lr) * 128 + c * 32 + lk * 8);
      s0 = __builtin_amdgcn_mfma_f32_16x16x32_bf16(qf[c], kf0, s0, 0, 0, 0);
      s1 = __builtin_amdgcn_mfma_f32_16x16x32_bf16(qf[c], kf1, s1, 0, 0, 0);
    }

    float alpha[4];
    int ibase = q0 + w * 16 + lk * 4;
    for (int jj = 0; jj < 4; ++jj) {
      int irow = ibase + jj;
      int jp0 = j0 + lr, jp1 = j0 + 16 + lr;
      bool ok0 = (jp0 >= irow) && (jp0 - irow < win);
      bool ok1 = (jp1 >= irow) && (jp1 - irow < win);
      float v0 = ok0 ? s0[jj] * scale : NEGINF;
      float v1 = ok1 ? s1[jj] * scale : NEGINF;
      float rm = fmaxf(v0, v1);
      rm = fmaxf(rm, __shfl_xor(rm, 1));
      rm = fmaxf(rm, __shfl_xor(rm, 2));
      rm = fmaxf(rm, __shfl_xor(rm, 4));
      rm = fmaxf(rm, __shfl_xor(rm, 8));
      float mnew = fmaxf(mrun[jj], rm);
      float a = (mrun[jj] == NEGINF) ? 0.f : __expf(mrun[jj] - mnew);
      float p0 = ok0 ? __expf(v0 - mnew) : 0.f;
      float p1 = ok1 ? __expf(v1 - mnew) : 0.f;
      float rs = p0 + p1;
      rs += __shfl_xor(rs, 1); rs += __shfl_xor(rs, 2);
      rs += __shfl_xor(rs, 4); rs += __shfl_xor(rs, 8);
      lrun[jj] = lrun[jj] * a + rs;
      mrun[jj] = mnew;
      alpha[jj] = a;
      sP[w][(lk * 4 + jj) * 32 + lr] = __float2bfloat16(p0);
      sP[w][(lk * 4 + jj) * 32 + 16 + lr] = __float2bfloat16(p1);
    }
    for (int nb = 0; nb < 8; ++nb)
      for (int jj = 0; jj < 4; ++jj) o[nb][jj] *= alpha[jj];

    // PV: P[16][32] x V[32][128]  (per-wave sP, DS ops in-order within wave)
    short8 pf = *(const short8*)(&sP[w][lr * 32 + lk * 8]);
    for (int nb = 0; nb < 8; ++nb) {
      short8 vf = *(const short8*)(sV + (nb * 16 + lr) * 32 + lk * 8);
      o[nb] = __builtin_amdgcn_mfma_f32_16x16x32_bf16(pf, vf, o[nb], 0, 0, 0);
    }
    __syncthreads();  // protect sK/sV/sP before next stage
  }

  for (int jj = 0; jj < 4; ++jj) {
    float inv = 1.f / lrun[jj];
    size_t ob = (size_t)(bi * T_ + q0 + w * 16 + lk * 4 + jj) * (NH * HD) + h * HD;
    for (int nb = 0; nb < 8; ++nb)
      y[ob + nb * 16 + lr] = __float2bfloat16(o[nb][jj] * inv);
  }
}

extern "C" void kernel_launch(void* const* d_in, const int* in_sizes, int n_in,
                              void* d_out, int out_size, void* d_ws, size_t ws_size,
                              hipStream_t stream) {
  const float* x    = (const float*)d_in[0];
  const float* ve   = (const float*)d_in[1];
  const float* cosT = (const float*)d_in[2];
  const float* sinT = (const float*)d_in[3];
  const float* Wq   = (const float*)d_in[4];
  const float* Wk   = (const float*)d_in[5];
  const float* Wv   = (const float*)d_in[6];
  const float* Wg   = (const float*)d_in[7];
  const float* Wo   = (const float*)d_in[8];
  const int*   win  = (const int*)d_in[9];
  float* out = (float*)d_out;

  char* ws = (char*)d_ws;
  bf16*  xb  = (bf16*)(ws);                        // 16,777,216 B
  bf16*  wT  = (bf16*)(ws + 16777216);             // 12,582,912 B  [3072][2048]
  bf16*  woT = (bf16*)(ws + 29360128);             //  8,388,608 B  [2048][2048]
  float* qkv = (float*)(ws + 37748736);            // 50,331,648 B  [4096][3072]
  bf16*  qn  = (bf16*)(ws + 88080384);             // 16,777,216 B
  bf16*  kn  = (bf16*)(ws + 104857600);            //  4,194,304 B
  bf16*  vTb = (bf16*)(ws + 109051904);            //  4,194,304 B
  bf16*  y   = (bf16*)qkv;                         // alias (qkv dead after epilogue)

  cast_x_kernel<<<8192, 256, 0, stream>>>((const float4*)x, (ushort4*)xb, 2097152);
  cast_transpose<<<dim3(64, 64), 256, 0, stream>>>(Wq, wT, 2048, 2048);
  cast_transpose<<<dim3(16, 64), 256, 0, stream>>>(Wk, wT + (size_t)2048 * 2048, 2048, 512);
  cast_transpose<<<dim3(16, 64), 256, 0, stream>>>(Wv, wT + (size_t)2560 * 2048, 2048, 512);
  cast_transpose<<<dim3(64, 64), 256, 0, stream>>>(Wo, woT, 2048, 2048);

  gemm_bt<<<dim3(24, 32), 256, 0, stream>>>(xb, wT, qkv, 4096, 3072, 2048);
  epilogue_kernel<<<4096, 256, 0, stream>>>(qkv, x, ve, cosT, sinT, Wg, qn, kn, vTb);
  attn_kernel<<<dim3(32, 16, 2), 256, 0, stream>>>(qn, kn, vTb, y, win);
  gemm_bt<<<dim3(16, 32), 256, 0, stream>>>(y, woT, out, 4096, 2048, 2048);
}

// Round 2
// 272.203 us; speedup vs baseline: 1.2453x; 1.2453x over previous
//
#include <hip/hip_runtime.h>
#include <hip/hip_bf16.h>
#include <cstdint>

typedef __hip_bfloat16 bf16;
typedef __attribute__((ext_vector_type(8))) short short8;
typedef __attribute__((ext_vector_type(4))) float f32x4;

#define T_   2048
#define CDIM 2048
#define NH   16
#define NKV  4
#define HD   128

__device__ __forceinline__ void gload_lds16(const void* g, void* l) {
  __builtin_amdgcn_global_load_lds(
      (const __attribute__((address_space(1))) void*)g,
      (__attribute__((address_space(3))) void*)l, 16, 0, 0);
}

// ---------------- cast x (fp32 -> bf16), vectorized ----------------
__global__ __launch_bounds__(256) void cast_x_kernel(const float4* __restrict__ in,
                                                     ushort4* __restrict__ out, int n4) {
  int i = blockIdx.x * 256 + threadIdx.x;
  if (i >= n4) return;
  float4 v = in[i];
  union { bf16 h[4]; ushort4 u; } cv;
  cv.h[0] = __float2bfloat16(v.x);
  cv.h[1] = __float2bfloat16(v.y);
  cv.h[2] = __float2bfloat16(v.z);
  cv.h[3] = __float2bfloat16(v.w);
  out[i] = cv.u;
}

// ---------------- cast + transpose W[K][N] fp32 -> WT[N][K] bf16 ----------------
__global__ __launch_bounds__(256) void cast_transpose(const float* __restrict__ W,
                                                      bf16* __restrict__ WT,
                                                      int K, int N) {
  __shared__ float tile[32][33];
  int k0 = blockIdx.y * 32, n0 = blockIdx.x * 32;
  int r = threadIdx.x >> 5, c = threadIdx.x & 31;  // r:0..7
  for (int i = 0; i < 4; ++i)
    tile[r + i * 8][c] = W[(size_t)(k0 + r + i * 8) * N + n0 + c];
  __syncthreads();
  for (int i = 0; i < 4; ++i)
    WT[(size_t)(n0 + r + i * 8) * K + k0 + c] = __float2bfloat16(tile[c][r + i * 8]);
}

// ---------------- GEMM: A[M][K] bf16 * BT[N][K] bf16 -> C[M][N] fp32 ----------------
__global__ __launch_bounds__(256) void gemm_bt(const bf16* __restrict__ A,
                                               const bf16* __restrict__ BT,
                                               float* __restrict__ C,
                                               int M, int N, int K) {
  __shared__ __align__(16) bf16 sA[128 * 32];
  __shared__ __align__(16) bf16 sB[128 * 32];
  int tid = threadIdx.x;
  int lane = tid & 63, w = tid >> 6;
  int wm = w >> 1, wn = w & 1;
  int lr = lane & 15, lk = lane >> 4;
  int m0 = blockIdx.y * 128, n0 = blockIdx.x * 128;

  f32x4 acc[4][4];
  for (int m = 0; m < 4; ++m)
    for (int n = 0; n < 4; ++n) acc[m][n] = (f32x4){0.f, 0.f, 0.f, 0.f};

  int nk = K >> 5;
  for (int kt = 0; kt < nk; ++kt) {
    int kb = kt << 5;
    for (int i = 0; i < 2; ++i) {
      int c = i * 256 + tid;
      int r = c >> 2;
      int off = (c & 3) * 8;
      gload_lds16(A + (size_t)(m0 + r) * K + kb + off, (char*)sA + c * 16);
      gload_lds16(BT + (size_t)(n0 + r) * K + kb + off, (char*)sB + c * 16);
    }
    __syncthreads();
    short8 af[4], bfr[4];
    for (int m = 0; m < 4; ++m)
      af[m] = *(const short8*)(sA + (wm * 64 + m * 16 + lr) * 32 + lk * 8);
    for (int n = 0; n < 4; ++n)
      bfr[n] = *(const short8*)(sB + (wn * 64 + n * 16 + lr) * 32 + lk * 8);
    for (int m = 0; m < 4; ++m)
      for (int n = 0; n < 4; ++n)
        acc[m][n] = __builtin_amdgcn_mfma_f32_16x16x32_bf16(af[m], bfr[n], acc[m][n], 0, 0, 0);
    __syncthreads();
  }
  for (int m = 0; m < 4; ++m)
    for (int n = 0; n < 4; ++n)
      for (int jj = 0; jj < 4; ++jj)
        C[(size_t)(m0 + wm * 64 + m * 16 + lk * 4 + jj) * N + n0 + wn * 64 + n * 16 + lr] =
            acc[m][n][jj];
}

// ---------------- epilogue: gate, v-update(+transpose), RoPE + RMSNorm ----------------
__global__ __launch_bounds__(256) void epilogue_kernel(
    const float* __restrict__ qkv, const float* __restrict__ x,
    const float* __restrict__ ve, const float* __restrict__ cosT,
    const float* __restrict__ sinT, const float* __restrict__ Wg,
    bf16* __restrict__ qn, bf16* __restrict__ kn, bf16* __restrict__ vT) {
  int row = blockIdx.x;
  int bi = row >> 11, t = row & 2047;
  int tid = threadIdx.x, lane = tid & 63, w = tid >> 6;
  __shared__ float gate[NKV];
  size_t rb = (size_t)row * 3072;

  if (tid < 128) {
    int g = tid >> 5, i = tid & 31;
    float p = x[(size_t)row * CDIM + i] * Wg[i * 4 + g];
    p += __shfl_xor(p, 1);  p += __shfl_xor(p, 2);
    p += __shfl_xor(p, 4);  p += __shfl_xor(p, 8);
    p += __shfl_xor(p, 16);
    if (i == 0) gate[g] = 2.f / (1.f + __expf(-p));
  }
  __syncthreads();

  float cv = cosT[t * 64 + lane];
  float sv = sinT[t * 64 + lane];

  for (int it = 0; it < 4; ++it) {
    int h = it * 4 + w;
    float x1 = qkv[rb + h * 128 + lane];
    float x2 = qkv[rb + h * 128 + 64 + lane];
    float y1 = x1 * cv + x2 * sv;
    float y2 = x2 * cv - x1 * sv;
    float ss = y1 * y1 + y2 * y2;
    ss += __shfl_xor(ss, 1);  ss += __shfl_xor(ss, 2);  ss += __shfl_xor(ss, 4);
    ss += __shfl_xor(ss, 8);  ss += __shfl_xor(ss, 16); ss += __shfl_xor(ss, 32);
    float r = rsqrtf(ss * (1.f / 128.f) + 1e-6f);
    size_t ob = (size_t)row * (NH * HD) + h * 128;
    qn[ob + lane] = __float2bfloat16(y1 * r);
    qn[ob + 64 + lane] = __float2bfloat16(y2 * r);
  }
  {
    int h = w;
    float x1 = qkv[rb + 2048 + h * 128 + lane];
    float x2 = qkv[rb + 2048 + h * 128 + 64 + lane];
    float y1 = x1 * cv + x2 * sv;
    float y2 = x2 * cv - x1 * sv;
    float ss = y1 * y1 + y2 * y2;
    ss += __shfl_xor(ss, 1);  ss += __shfl_xor(ss, 2);  ss += __shfl_xor(ss, 4);
    ss += __shfl_xor(ss, 8);  ss += __shfl_xor(ss, 16); ss += __shfl_xor(ss, 32);
    float r = rsqrtf(ss * (1.f / 128.f) + 1e-6f);
    size_t ob = (size_t)row * (NKV * HD) + h * 128;
    kn[ob + lane] = __float2bfloat16(y1 * r);
    kn[ob + 64 + lane] = __float2bfloat16(y2 * r);
  }
  for (int e = tid; e < 512; e += 256) {
    int kv = e >> 7, d = e & 127;
    float val = qkv[rb + 2560 + e] + gate[kv] * ve[(size_t)row * 512 + e];
    vT[((size_t)(bi * NKV + kv) * HD + d) * T_ + t] = __float2bfloat16(val);
  }
}

// ---------------- flash attention, forward window, KVBLK=64, swizzled LDS ----------------
// 1-D grid of 1024 blocks; id&7 selects (bi,kvh) so each XCD owns one K/V slice.
__global__ __launch_bounds__(256) void attn_kernel(
    const bf16* __restrict__ qn, const bf16* __restrict__ kn,
    const bf16* __restrict__ vT, bf16* __restrict__ y,
    const int* __restrict__ winp) {
  __shared__ __align__(16) bf16 sK[64 * 128];      // [key][d], XOR-swizzled
  __shared__ __align__(16) bf16 sV[128 * 64];      // [d][key], XOR-swizzled
  __shared__ __align__(16) bf16 sP[4][16 * 64];    // per-wave P, XOR-swizzled

  int win = *winp;
  int id = blockIdx.x;
  int g  = id & 7;           // XCD group = (bi, kvh)
  int bi = g >> 2;
  int kvh = g & 3;
  int rem = id >> 3;
  int h  = kvh * 4 + (rem & 3);
  int q0 = (rem >> 2) << 6;
  int tid = threadIdx.x;
  int lane = tid & 63, w = tid >> 6;
  int lr = lane & 15, lk = lane >> 4;

  short8 qf[4];
  {
    const bf16* qrow = qn + (size_t)(bi * T_ + q0 + w * 16 + lr) * (NH * HD) + h * HD;
    for (int c = 0; c < 4; ++c) qf[c] = *(const short8*)(qrow + c * 32 + lk * 8);
  }

  f32x4 o[8];
  for (int i = 0; i < 8; ++i) o[i] = (f32x4){0.f, 0.f, 0.f, 0.f};
  float mrun[4], lrun[4];
  for (int j = 0; j < 4; ++j) { mrun[j] = -__builtin_inff(); lrun[j] = 0.f; }

  int jt0 = q0 >> 6;
  int hi = q0 + 62 + win; if (hi > T_ - 1) hi = T_ - 1;
  int jt1 = hi >> 6;
  const float scale2 = 0.08838834764831845f * 1.44269504088896340f;  // 1/sqrt(128)*log2e
  const float NEGINF = -__builtin_inff();

  const char* sKb = (const char*)sK;
  const char* sVb = (const char*)sV;
  char* sPb = (char*)(&sP[w][0]);
  int prx = (lr & 7) << 4;  // P-read row swizzle

  for (int jt = jt0; jt <= jt1; ++jt) {
    int j0 = jt << 6;
    // stage K [64][128]: 1024 chunks; source pre-swizzled (16 slots/row, XOR r&7)
    for (int i = 0; i < 4; ++i) {
      int c = i * 256 + tid;
      int r = c >> 4, sl = c & 15;
      gload_lds16(kn + (size_t)(bi * T_ + j0 + r) * (NKV * HD) + kvh * HD + ((sl ^ (r & 7)) * 8),
                  (char*)sK + c * 16);
    }
    // stage V^T [128][64]: 1024 chunks; 8 slots/row, XOR r&7
    for (int i = 0; i < 4; ++i) {
      int c = i * 256 + tid;
      int r = c >> 3, sl = c & 7;
      gload_lds16(vT + ((size_t)(bi * NKV + kvh) * HD + r) * T_ + j0 + ((sl ^ (r & 7)) * 8),
                  (char*)sV + c * 16);
    }
    __syncthreads();

    // QK^T: S[16 q][64 k] per wave
    f32x4 s[4];
    for (int sub = 0; sub < 4; ++sub) s[sub] = (f32x4){0.f, 0.f, 0.f, 0.f};
    for (int sub = 0; sub < 4; ++sub) {
      int kr = sub * 16 + lr;
      int rx = (kr & 7) << 4;
      const char* rowb = sKb + kr * 256;
      for (int c = 0; c < 4; ++c) {
        short8 kf = *(const short8*)(rowb + ((c * 64 + lk * 16) ^ rx));
        s[sub] = __builtin_amdgcn_mfma_f32_16x16x32_bf16(qf[c], kf, s[sub], 0, 0, 0);
      }
    }

    bool full = (j0 >= q0 + 64) && (j0 + 64 <= q0 + win);
    float alpha[4];
    int ibase = q0 + w * 16 + lk * 4;

    for (int jj = 0; jj < 4; ++jj) {
      int irow = ibase + jj;
      int pr = lk * 4 + jj;
      int pwx = (pr & 7) << 4;
      char* pb = sPb + pr * 128;
      float v0, v1, v2, v3;
      if (full) {
        v0 = s[0][jj] * scale2; v1 = s[1][jj] * scale2;
        v2 = s[2][jj] * scale2; v3 = s[3][jj] * scale2;
      } else {
        int j = j0 + lr;
        v0 = (j >= irow && j - irow < win)           ? s[0][jj] * scale2 : NEGINF;
        v1 = (j + 16 >= irow && j + 16 - irow < win) ? s[1][jj] * scale2 : NEGINF;
        v2 = (j + 32 >= irow && j + 32 - irow < win) ? s[2][jj] * scale2 : NEGINF;
        v3 = (j + 48 >= irow && j + 48 - irow < win) ? s[3][jj] * scale2 : NEGINF;
      }
      float rm = fmaxf(fmaxf(v0, v1), fmaxf(v2, v3));
      rm = fmaxf(rm, __shfl_xor(rm, 1));
      rm = fmaxf(rm, __shfl_xor(rm, 2));
      rm = fmaxf(rm, __shfl_xor(rm, 4));
      rm = fmaxf(rm, __shfl_xor(rm, 8));
      float mnew = fmaxf(mrun[jj], rm);   // finite after (and including) first tile
      float a = exp2f(mrun[jj] - mnew);   // -inf - finite -> 0, never NaN
      float p0 = exp2f(v0 - mnew), p1 = exp2f(v1 - mnew);
      float p2 = exp2f(v2 - mnew), p3 = exp2f(v3 - mnew);
      float rs = (p0 + p1) + (p2 + p3);
      rs += __shfl_xor(rs, 1); rs += __shfl_xor(rs, 2);
      rs += __shfl_xor(rs, 4); rs += __shfl_xor(rs, 8);
      lrun[jj] = lrun[jj] * a + rs;
      mrun[jj] = mnew;
      alpha[jj] = a;
      *(bf16*)(pb + ((lr * 2)      ^ pwx)) = __float2bfloat16(p0);
      *(bf16*)(pb + ((32 + lr * 2) ^ pwx)) = __float2bfloat16(p1);
      *(bf16*)(pb + ((64 + lr * 2) ^ pwx)) = __float2bfloat16(p2);
      *(bf16*)(pb + ((96 + lr * 2) ^ pwx)) = __float2bfloat16(p3);
    }

    bool chg = (alpha[0] < 1.f) | (alpha[1] < 1.f) | (alpha[2] < 1.f) | (alpha[3] < 1.f);
    if (__any(chg)) {
      for (int nb = 0; nb < 8; ++nb)
        for (int jj = 0; jj < 4; ++jj) o[nb][jj] *= alpha[jj];
    }

    // PV: P[16][64] x V[64][128]
    short8 pf0 = *(const short8*)(sPb + lr * 128 + ((lk * 16)      ^ prx));
    short8 pf1 = *(const short8*)(sPb + lr * 128 + ((64 + lk * 16) ^ prx));
    for (int nb = 0; nb < 8; ++nb) {
      int vr = nb * 16 + lr;
      int vrx = (vr & 7) << 4;
      const char* vb = sVb + vr * 128;
      short8 vf0 = *(const short8*)(vb + ((lk * 16)      ^ vrx));
      short8 vf1 = *(const short8*)(vb + ((64 + lk * 16) ^ vrx));
      o[nb] = __builtin_amdgcn_mfma_f32_16x16x32_bf16(pf0, vf0, o[nb], 0, 0, 0);
      o[nb] = __builtin_amdgcn_mfma_f32_16x16x32_bf16(pf1, vf1, o[nb], 0, 0, 0);
    }
    __syncthreads();
  }

  for (int jj = 0; jj < 4; ++jj) {
    float inv = 1.f / lrun[jj];
    size_t ob = (size_t)(bi * T_ + q0 + w * 16 + lk * 4 + jj) * (NH * HD) + h * HD;
    for (int nb = 0; nb < 8; ++nb)
      y[ob + nb * 16 + lr] = __float2bfloat16(o[nb][jj] * inv);
  }
}

extern "C" void kernel_launch(void* const* d_in, const int* in_sizes, int n_in,
                              void* d_out, int out_size, void* d_ws, size_t ws_size,
                              hipStream_t stream) {
  const float* x    = (const float*)d_in[0];
  const float* ve   = (const float*)d_in[1];
  const float* cosT = (const float*)d_in[2];
  const float* sinT = (const float*)d_in[3];
  const float* Wq   = (const float*)d_in[4];
  const float* Wk   = (const float*)d_in[5];
  const float* Wv   = (const float*)d_in[6];
  const float* Wg   = (const float*)d_in[7];
  const float* Wo   = (const float*)d_in[8];
  const int*   win  = (const int*)d_in[9];
  float* out = (float*)d_out;

  char* ws = (char*)d_ws;
  bf16*  xb  = (bf16*)(ws);
  bf16*  wT  = (bf16*)(ws + 16777216);
  bf16*  woT = (bf16*)(ws + 29360128);
  float* qkv = (float*)(ws + 37748736);
  bf16*  qn  = (bf16*)(ws + 88080384);
  bf16*  kn  = (bf16*)(ws + 104857600);
  bf16*  vTb = (bf16*)(ws + 109051904);
  bf16*  y   = (bf16*)qkv;

  cast_x_kernel<<<8192, 256, 0, stream>>>((const float4*)x, (ushort4*)xb, 2097152);
  cast_transpose<<<dim3(64, 64), 256, 0, stream>>>(Wq, wT, 2048, 2048);
  cast_transpose<<<dim3(16, 64), 256, 0, stream>>>(Wk, wT + (size_t)2048 * 2048, 2048, 512);
  cast_transpose<<<dim3(16, 64), 256, 0, stream>>>(Wv, wT + (size_t)2560 * 2048, 2048, 512);
  cast_transpose<<<dim3(64, 64), 256, 0, stream>>>(Wo, woT, 2048, 2048);

  gemm_bt<<<dim3(24, 32), 256, 0, stream>>>(xb, wT, qkv, 4096, 3072, 2048);
  epilogue_kernel<<<4096, 256, 0, stream>>>(qkv, x, ve, cosT, sinT, Wg, qn, kn, vTb);
  attn_kernel<<<1024, 256, 0, stream>>>(qn, kn, vTb, y, win);
  gemm_bt<<<dim3(16, 32), 256, 0, stream>>>(y, woT, out, 4096, 2048, 2048);
}

// Round 3
// 241.027 us; speedup vs baseline: 1.4063x; 1.1293x over previous
//
#include <hip/hip_runtime.h>
#include <hip/hip_bf16.h>
#include <cstdint>

typedef __hip_bfloat16 bf16;
typedef __attribute__((ext_vector_type(8))) short short8;
typedef __attribute__((ext_vector_type(4))) float f32x4;

#define T_   2048
#define CDIM 2048
#define NH   16
#define NKV  4
#define HD   128
// 1/sqrt(128) * log2(e), folded into q at the epilogue so attn scores are exp2-ready
#define QSCALE (0.08838834764831845f * 1.44269504088896340f)

__device__ __forceinline__ void gload_lds16(const void* g, void* l) {
  __builtin_amdgcn_global_load_lds(
      (const __attribute__((address_space(1))) void*)g,
      (__attribute__((address_space(3))) void*)l, 16, 0, 0);
}

// ---------------- cast x (fp32 -> bf16), vectorized ----------------
__global__ __launch_bounds__(256) void cast_x_kernel(const float4* __restrict__ in,
                                                     ushort4* __restrict__ out, int n4) {
  int i = blockIdx.x * 256 + threadIdx.x;
  if (i >= n4) return;
  float4 v = in[i];
  union { bf16 h[4]; ushort4 u; } cv;
  cv.h[0] = __float2bfloat16(v.x);
  cv.h[1] = __float2bfloat16(v.y);
  cv.h[2] = __float2bfloat16(v.z);
  cv.h[3] = __float2bfloat16(v.w);
  out[i] = cv.u;
}

// ---------------- cast + transpose W[K][N] fp32 -> WT[N][K] bf16 ----------------
__global__ __launch_bounds__(256) void cast_transpose(const float* __restrict__ W,
                                                      bf16* __restrict__ WT,
                                                      int K, int N) {
  __shared__ float tile[32][33];
  int k0 = blockIdx.y * 32, n0 = blockIdx.x * 32;
  int r = threadIdx.x >> 5, c = threadIdx.x & 31;  // r:0..7
  for (int i = 0; i < 4; ++i)
    tile[r + i * 8][c] = W[(size_t)(k0 + r + i * 8) * N + n0 + c];
  __syncthreads();
  for (int i = 0; i < 4; ++i)
    WT[(size_t)(n0 + r + i * 8) * K + k0 + c] = __float2bfloat16(tile[c][r + i * 8]);
}

// ---------------- GEMM: A[M][K] bf16 * BT[N][K] bf16 -> C[M][N] fp32 ----------------
__global__ __launch_bounds__(256) void gemm_bt(const bf16* __restrict__ A,
                                               const bf16* __restrict__ BT,
                                               float* __restrict__ C,
                                               int M, int N, int K) {
  __shared__ __align__(16) bf16 sA[128 * 32];
  __shared__ __align__(16) bf16 sB[128 * 32];
  int tid = threadIdx.x;
  int lane = tid & 63, w = tid >> 6;
  int wm = w >> 1, wn = w & 1;
  int lr = lane & 15, lk = lane >> 4;
  int m0 = blockIdx.y * 128, n0 = blockIdx.x * 128;

  f32x4 acc[4][4];
  for (int m = 0; m < 4; ++m)
    for (int n = 0; n < 4; ++n) acc[m][n] = (f32x4){0.f, 0.f, 0.f, 0.f};

  int nk = K >> 5;
  for (int kt = 0; kt < nk; ++kt) {
    int kb = kt << 5;
    for (int i = 0; i < 2; ++i) {
      int c = i * 256 + tid;
      int r = c >> 2;
      int off = (c & 3) * 8;
      gload_lds16(A + (size_t)(m0 + r) * K + kb + off, (char*)sA + c * 16);
      gload_lds16(BT + (size_t)(n0 + r) * K + kb + off, (char*)sB + c * 16);
    }
    __syncthreads();
    short8 af[4], bfr[4];
    for (int m = 0; m < 4; ++m)
      af[m] = *(const short8*)(sA + (wm * 64 + m * 16 + lr) * 32 + lk * 8);
    for (int n = 0; n < 4; ++n)
      bfr[n] = *(const short8*)(sB + (wn * 64 + n * 16 + lr) * 32 + lk * 8);
    for (int m = 0; m < 4; ++m)
      for (int n = 0; n < 4; ++n)
        acc[m][n] = __builtin_amdgcn_mfma_f32_16x16x32_bf16(af[m], bfr[n], acc[m][n], 0, 0, 0);
    __syncthreads();
  }
  for (int m = 0; m < 4; ++m)
    for (int n = 0; n < 4; ++n)
      for (int jj = 0; jj < 4; ++jj)
        C[(size_t)(m0 + wm * 64 + m * 16 + lk * 4 + jj) * N + n0 + wn * 64 + n * 16 + lr] =
            acc[m][n][jj];
}

// ---------------- epilogue: gate, v-update(+transpose), RoPE + RMSNorm ----------------
// q output is pre-scaled by QSCALE so attn scores are already in exp2 domain.
__global__ __launch_bounds__(256) void epilogue_kernel(
    const float* __restrict__ qkv, const float* __restrict__ x,
    const float* __restrict__ ve, const float* __restrict__ cosT,
    const float* __restrict__ sinT, const float* __restrict__ Wg,
    bf16* __restrict__ qn, bf16* __restrict__ kn, bf16* __restrict__ vT) {
  int row = blockIdx.x;
  int bi = row >> 11, t = row & 2047;
  int tid = threadIdx.x, lane = tid & 63, w = tid >> 6;
  __shared__ float gate[NKV];
  size_t rb = (size_t)row * 3072;

  if (tid < 128) {
    int g = tid >> 5, i = tid & 31;
    float p = x[(size_t)row * CDIM + i] * Wg[i * 4 + g];
    p += __shfl_xor(p, 1);  p += __shfl_xor(p, 2);
    p += __shfl_xor(p, 4);  p += __shfl_xor(p, 8);
    p += __shfl_xor(p, 16);
    if (i == 0) gate[g] = 2.f / (1.f + __expf(-p));
  }
  __syncthreads();

  float cv = cosT[t * 64 + lane];
  float sv = sinT[t * 64 + lane];

  for (int it = 0; it < 4; ++it) {
    int h = it * 4 + w;
    float x1 = qkv[rb + h * 128 + lane];
    float x2 = qkv[rb + h * 128 + 64 + lane];
    float y1 = x1 * cv + x2 * sv;
    float y2 = x2 * cv - x1 * sv;
    float ss = y1 * y1 + y2 * y2;
    ss += __shfl_xor(ss, 1);  ss += __shfl_xor(ss, 2);  ss += __shfl_xor(ss, 4);
    ss += __shfl_xor(ss, 8);  ss += __shfl_xor(ss, 16); ss += __shfl_xor(ss, 32);
    float r = rsqrtf(ss * (1.f / 128.f) + 1e-6f) * QSCALE;
    size_t ob = (size_t)row * (NH * HD) + h * 128;
    qn[ob + lane] = __float2bfloat16(y1 * r);
    qn[ob + 64 + lane] = __float2bfloat16(y2 * r);
  }
  {
    int h = w;
    float x1 = qkv[rb + 2048 + h * 128 + lane];
    float x2 = qkv[rb + 2048 + h * 128 + 64 + lane];
    float y1 = x1 * cv + x2 * sv;
    float y2 = x2 * cv - x1 * sv;
    float ss = y1 * y1 + y2 * y2;
    ss += __shfl_xor(ss, 1);  ss += __shfl_xor(ss, 2);  ss += __shfl_xor(ss, 4);
    ss += __shfl_xor(ss, 8);  ss += __shfl_xor(ss, 16); ss += __shfl_xor(ss, 32);
    float r = rsqrtf(ss * (1.f / 128.f) + 1e-6f);
    size_t ob = (size_t)row * (NKV * HD) + h * 128;
    kn[ob + lane] = __float2bfloat16(y1 * r);
    kn[ob + 64 + lane] = __float2bfloat16(y2 * r);
  }
  for (int e = tid; e < 512; e += 256) {
    int kv = e >> 7, d = e & 127;
    float val = qkv[rb + 2560 + e] + gate[kv] * ve[(size_t)row * 512 + e];
    vT[((size_t)(bi * NKV + kv) * HD + d) * T_ + t] = __float2bfloat16(val);
  }
}

// ---------------- flash attention v3: no-max softmax, double-buffered K/V ----------------
// Bounds argument: RMSNorm => ||q||=||k||=sqrt(128); |score*log2e/sqrt(128)| <= 16.33,
// so exp2(s) <= 8.3e4, row-sum l <= 8.5e7 -> fp32-safe without max subtraction.
// Grid: 1024 blocks; id&7 = (bi,kvh) pins each K/V slice to one XCD's L2.
// q0 slots per CU chosen so each CU's 4 blocks sum to exactly 51 key-tiles.
__global__ __launch_bounds__(256) void attn_kernel(
    const bf16* __restrict__ qn, const bf16* __restrict__ kn,
    const bf16* __restrict__ vT, bf16* __restrict__ y,
    const int* __restrict__ winp) {
  __shared__ __align__(16) bf16 sK[2][64 * 128];   // [key][d], XOR-swizzled
  __shared__ __align__(16) bf16 sV[2][128 * 64];   // [d][key], XOR-swizzled
  __shared__ __align__(16) bf16 sP[4][16 * 64];    // per-wave P, XOR-swizzled

  int win = *winp;
  int id = blockIdx.x;
  int g  = id & 7;
  int bi = g >> 2;
  int kvh = g & 3;
  int rem = id >> 3;
  int h  = kvh * 4 + (rem & 3);
  int jslot = (rem >> 2) & 7;
  int s5 = rem >> 5;
  int q0i = (s5 == 0) ? (2 * jslot) : (s5 == 1) ? (2 * jslot + 1)
          : (s5 == 2) ? (16 + jslot) : (31 - jslot);
  int q0 = q0i << 6;
  int tid = threadIdx.x;
  int lane = tid & 63, w = tid >> 6;
  int lr = lane & 15, lk = lane >> 4;

  short8 qf[4];
  {
    const bf16* qrow = qn + (size_t)(bi * T_ + q0 + w * 16 + lr) * (NH * HD) + h * HD;
    for (int c = 0; c < 4; ++c) qf[c] = *(const short8*)(qrow + c * 32 + lk * 8);
  }

  f32x4 o[8];
  for (int i = 0; i < 8; ++i) o[i] = (f32x4){0.f, 0.f, 0.f, 0.f};
  float lpart[4] = {0.f, 0.f, 0.f, 0.f};

  int jt0 = q0 >> 6;
  int hi = q0 + 62 + win; if (hi > T_ - 1) hi = T_ - 1;
  int jt1 = hi >> 6;
  const float NEGINF = -__builtin_inff();

  char* sPb = (char*)(&sP[w][0]);
  int prx = (lr & 7) << 4;

  auto stageKV = [&](int b, int jtx) {
    int j0x = jtx << 6;
    for (int i = 0; i < 4; ++i) {
      int c = i * 256 + tid;
      int r = c >> 4, sl = c & 15;
      gload_lds16(kn + (size_t)(bi * T_ + j0x + r) * (NKV * HD) + kvh * HD + ((sl ^ (r & 7)) * 8),
                  (char*)(&sK[b][0]) + c * 16);
    }
    for (int i = 0; i < 4; ++i) {
      int c = i * 256 + tid;
      int r = c >> 3, sl = c & 7;
      gload_lds16(vT + ((size_t)(bi * NKV + kvh) * HD + r) * T_ + j0x + ((sl ^ (r & 7)) * 8),
                  (char*)(&sV[b][0]) + c * 16);
    }
  };

  stageKV(0, jt0);
  __syncthreads();

  int buf = 0;
  for (int jt = jt0; jt <= jt1; ++jt) {
    int j0 = jt << 6;
    if (jt < jt1) stageKV(buf ^ 1, jt + 1);   // prefetch next tile (other buffer)

    const char* sKb = (const char*)(&sK[buf][0]);
    const char* sVb = (const char*)(&sV[buf][0]);

    // QK^T: S[16 q][64 k] per wave (q pre-scaled to exp2 domain)
    f32x4 s[4];
    for (int sub = 0; sub < 4; ++sub) s[sub] = (f32x4){0.f, 0.f, 0.f, 0.f};
    for (int sub = 0; sub < 4; ++sub) {
      int kr = sub * 16 + lr;
      int rx = (kr & 7) << 4;
      const char* rowb = sKb + kr * 256;
      for (int c = 0; c < 4; ++c) {
        short8 kf = *(const short8*)(rowb + ((c * 64 + lk * 16) ^ rx));
        s[sub] = __builtin_amdgcn_mfma_f32_16x16x32_bf16(qf[c], kf, s[sub], 0, 0, 0);
      }
    }

    bool full = (j0 >= q0 + 64) && (j0 + 64 <= q0 + win);
    int ibase = q0 + w * 16 + lk * 4;

    for (int jj = 0; jj < 4; ++jj) {
      int irow = ibase + jj;
      int pr = lk * 4 + jj;
      int pwx = (pr & 7) << 4;
      char* pb = sPb + pr * 128;
      float v0, v1, v2, v3;
      if (full) {
        v0 = s[0][jj]; v1 = s[1][jj]; v2 = s[2][jj]; v3 = s[3][jj];
      } else {
        int j = j0 + lr;
        v0 = (j >= irow && j - irow < win)           ? s[0][jj] : NEGINF;
        v1 = (j + 16 >= irow && j + 16 - irow < win) ? s[1][jj] : NEGINF;
        v2 = (j + 32 >= irow && j + 32 - irow < win) ? s[2][jj] : NEGINF;
        v3 = (j + 48 >= irow && j + 48 - irow < win) ? s[3][jj] : NEGINF;
      }
      float p0 = exp2f(v0), p1 = exp2f(v1);
      float p2 = exp2f(v2), p3 = exp2f(v3);
      lpart[jj] += (p0 + p1) + (p2 + p3);
      *(bf16*)(pb + ((lr * 2)      ^ pwx)) = __float2bfloat16(p0);
      *(bf16*)(pb + ((32 + lr * 2) ^ pwx)) = __float2bfloat16(p1);
      *(bf16*)(pb + ((64 + lr * 2) ^ pwx)) = __float2bfloat16(p2);
      *(bf16*)(pb + ((96 + lr * 2) ^ pwx)) = __float2bfloat16(p3);
    }

    // PV: P[16][64] x V[64][128]
    short8 pf0 = *(const short8*)(sPb + lr * 128 + ((lk * 16)      ^ prx));
    short8 pf1 = *(const short8*)(sPb + lr * 128 + ((64 + lk * 16) ^ prx));
    for (int nb = 0; nb < 8; ++nb) {
      int vr = nb * 16 + lr;
      int vrx = (vr & 7) << 4;
      const char* vb = sVb + vr * 128;
      short8 vf0 = *(const short8*)(vb + ((lk * 16)      ^ vrx));
      short8 vf1 = *(const short8*)(vb + ((64 + lk * 16) ^ vrx));
      o[nb] = __builtin_amdgcn_mfma_f32_16x16x32_bf16(pf0, vf0, o[nb], 0, 0, 0);
      o[nb] = __builtin_amdgcn_mfma_f32_16x16x32_bf16(pf1, vf1, o[nb], 0, 0, 0);
    }
    __syncthreads();  // drains stage loads; protects sK/sV/sP for next iter
    buf ^= 1;
  }

  for (int jj = 0; jj < 4; ++jj) {
    float l = lpart[jj];
    l += __shfl_xor(l, 1); l += __shfl_xor(l, 2);
    l += __shfl_xor(l, 4); l += __shfl_xor(l, 8);
    float inv = 1.f / l;
    size_t ob = (size_t)(bi * T_ + q0 + w * 16 + lk * 4 + jj) * (NH * HD) + h * HD;
    for (int nb = 0; nb < 8; ++nb)
      y[ob + nb * 16 + lr] = __float2bfloat16(o[nb][jj] * inv);
  }
}

extern "C" void kernel_launch(void* const* d_in, const int* in_sizes, int n_in,
                              void* d_out, int out_size, void* d_ws, size_t ws_size,
                              hipStream_t stream) {
  const float* x    = (const float*)d_in[0];
  const float* ve   = (const float*)d_in[1];
  const float* cosT = (const float*)d_in[2];
  const float* sinT = (const float*)d_in[3];
  const float* Wq   = (const float*)d_in[4];
  const float* Wk   = (const float*)d_in[5];
  const float* Wv   = (const float*)d_in[6];
  const float* Wg   = (const float*)d_in[7];
  const float* Wo   = (const float*)d_in[8];
  const int*   win  = (const int*)d_in[9];
  float* out = (float*)d_out;

  char* ws = (char*)d_ws;
  bf16*  xb  = (bf16*)(ws);
  bf16*  wT  = (bf16*)(ws + 16777216);
  bf16*  woT = (bf16*)(ws + 29360128);
  float* qkv = (float*)(ws + 37748736);
  bf16*  qn  = (bf16*)(ws + 88080384);
  bf16*  kn  = (bf16*)(ws + 104857600);
  bf16*  vTb = (bf16*)(ws + 109051904);
  bf16*  y   = (bf16*)qkv;

  cast_x_kernel<<<8192, 256, 0, stream>>>((const float4*)x, (ushort4*)xb, 2097152);
  cast_transpose<<<dim3(64, 64), 256, 0, stream>>>(Wq, wT, 2048, 2048);
  cast_transpose<<<dim3(16, 64), 256, 0, stream>>>(Wk, wT + (size_t)2048 * 2048, 2048, 512);
  cast_transpose<<<dim3(16, 64), 256, 0, stream>>>(Wv, wT + (size_t)2560 * 2048, 2048, 512);
  cast_transpose<<<dim3(64, 64), 256, 0, stream>>>(Wo, woT, 2048, 2048);

  gemm_bt<<<dim3(24, 32), 256, 0, stream>>>(xb, wT, qkv, 4096, 3072, 2048);
  epilogue_kernel<<<4096, 256, 0, stream>>>(qkv, x, ve, cosT, sinT, Wg, qn, kn, vTb);
  attn_kernel<<<1024, 256, 0, stream>>>(qn, kn, vTb, y, win);
  gemm_bt<<<dim3(16, 32), 256, 0, stream>>>(y, woT, out, 4096, 2048, 2048);
}

// Round 4
// 230.071 us; speedup vs baseline: 1.4733x; 1.0476x over previous
//
#include <hip/hip_runtime.h>
#include <hip/hip_bf16.h>
#include <cstdint>

typedef __hip_bfloat16 bf16;
typedef __attribute__((ext_vector_type(8))) short short8;
typedef __attribute__((ext_vector_type(4))) float f32x4;

#define T_   2048
#define CDIM 2048
#define NH   16
#define NKV  4
#define HD   128
// 1/sqrt(128) * log2(e), folded into q at the epilogue so attn scores are exp2-ready
#define QSCALE (0.08838834764831845f * 1.44269504088896340f)

__device__ __forceinline__ void gload_lds16(const void* g, void* l) {
  __builtin_amdgcn_global_load_lds(
      (const __attribute__((address_space(1))) void*)g,
      (__attribute__((address_space(3))) void*)l, 16, 0, 0);
}

// ---------------- cast x (fp32 -> bf16), vectorized ----------------
__global__ __launch_bounds__(256) void cast_x_kernel(const float4* __restrict__ in,
                                                     ushort4* __restrict__ out, int n4) {
  int i = blockIdx.x * 256 + threadIdx.x;
  if (i >= n4) return;
  float4 v = in[i];
  union { bf16 h[4]; ushort4 u; } cv;
  cv.h[0] = __float2bfloat16(v.x);
  cv.h[1] = __float2bfloat16(v.y);
  cv.h[2] = __float2bfloat16(v.z);
  cv.h[3] = __float2bfloat16(v.w);
  out[i] = cv.u;
}

// ---------------- cast + transpose W[K][N] fp32 -> WT[N][K] bf16 ----------------
__global__ __launch_bounds__(256) void cast_transpose(const float* __restrict__ W,
                                                      bf16* __restrict__ WT,
                                                      int K, int N) {
  __shared__ float tile[32][33];
  int k0 = blockIdx.y * 32, n0 = blockIdx.x * 32;
  int r = threadIdx.x >> 5, c = threadIdx.x & 31;  // r:0..7
  for (int i = 0; i < 4; ++i)
    tile[r + i * 8][c] = W[(size_t)(k0 + r + i * 8) * N + n0 + c];
  __syncthreads();
  for (int i = 0; i < 4; ++i)
    WT[(size_t)(n0 + r + i * 8) * K + k0 + c] = __float2bfloat16(tile[c][r + i * 8]);
}

// ---------------- GEMM v2: A[M][K] bf16 * BT[N][K] bf16 -> C[M][N] (CT = float|bf16)
// 128x128 tile, BK=64, double-buffered LDS, counted vmcnt(8) (never 0 in steady
// state), raw s_barrier, XOR-swizzled LDS (8x16B slots per 128B row, XOR row&7;
// source pre-swizzled since global_load_lds dest is linear). XCD-chunked bid swizzle.
template <typename CT>
__global__ __launch_bounds__(256) void gemm_bt2(const bf16* __restrict__ A,
                                                const bf16* __restrict__ BT,
                                                CT* __restrict__ C,
                                                int M, int N, int K, int nbx) {
  __shared__ __align__(16) bf16 sA[2][128 * 64];
  __shared__ __align__(16) bf16 sB[2][128 * 64];
  int tid = threadIdx.x;
  int lane = tid & 63, w = tid >> 6;
  int wm = w >> 1, wn = w & 1;
  int lr = lane & 15, lk = lane >> 4;

  // XCD-chunked swizzle (grid % 8 == 0): consecutive swizzled ids share A-panels
  int nwg = gridDim.x;
  int cpx = nwg >> 3;
  int bid = blockIdx.x;
  int sw = (bid & 7) * cpx + (bid >> 3);
  int by = sw / nbx, bx = sw - by * nbx;
  int m0 = by * 128, n0 = bx * 128;

  f32x4 acc[4][4];
  for (int m = 0; m < 4; ++m)
    for (int n = 0; n < 4; ++n) acc[m][n] = (f32x4){0.f, 0.f, 0.f, 0.f};

  const bf16* Abase = A + (size_t)m0 * K;
  const bf16* Bbase = BT + (size_t)n0 * K;

  auto stage = [&](int b, int kt) {
    int kb = kt << 6;
    for (int i = 0; i < 4; ++i) {
      int c = i * 256 + tid;
      int r = c >> 3, sl = c & 7;
      int src = r * K + kb + ((sl ^ (r & 7)) << 3);
      gload_lds16(Abase + src, (char*)(&sA[b][0]) + c * 16);
      gload_lds16(Bbase + src, (char*)(&sB[b][0]) + c * 16);
    }
  };

  int nk = K >> 6;
  stage(0, 0);
  stage(1, 1);
  asm volatile("s_waitcnt vmcnt(8)\n\ts_barrier" ::: "memory");

  for (int kt = 0; kt < nk; ++kt) {
    int b = kt & 1;
    const char* sAb = (const char*)(&sA[b][0]);
    const char* sBb = (const char*)(&sB[b][0]);
    short8 af[4][2], bfr[4][2];
    for (int m = 0; m < 4; ++m) {
      int row = wm * 64 + m * 16 + lr;
      const char* rb = sAb + row * 128;
      int rx = (row & 7) << 4;
      af[m][0] = *(const short8*)(rb + ((lk * 16) ^ rx));
      af[m][1] = *(const short8*)(rb + ((64 + lk * 16) ^ rx));
    }
    for (int n = 0; n < 4; ++n) {
      int row = wn * 64 + n * 16 + lr;
      const char* rb = sBb + row * 128;
      int rx = (row & 7) << 4;
      bfr[n][0] = *(const short8*)(rb + ((lk * 16) ^ rx));
      bfr[n][1] = *(const short8*)(rb + ((64 + lk * 16) ^ rx));
    }
    for (int kk = 0; kk < 2; ++kk)
      for (int m = 0; m < 4; ++m)
        for (int n = 0; n < 4; ++n)
          acc[m][n] = __builtin_amdgcn_mfma_f32_16x16x32_bf16(af[m][kk], bfr[n][kk],
                                                              acc[m][n], 0, 0, 0);
    // all my ds_reads complete (lgkmcnt 0), then signal: buf b free to restage
    asm volatile("s_waitcnt lgkmcnt(0)\n\ts_barrier" ::: "memory");
    if (kt + 2 < nk) {
      stage(b, kt + 2);
      // wait: tile kt+1's 8 loads landed (only kt+2's 8 remain in flight)
      asm volatile("s_waitcnt vmcnt(8)\n\ts_barrier" ::: "memory");
    } else {
      asm volatile("s_waitcnt vmcnt(0)\n\ts_barrier" ::: "memory");
    }
  }

  for (int m = 0; m < 4; ++m)
    for (int n = 0; n < 4; ++n)
      for (int jj = 0; jj < 4; ++jj) {
        size_t idx = (size_t)(m0 + wm * 64 + m * 16 + lk * 4 + jj) * N +
                     n0 + wn * 64 + n * 16 + lr;
        if constexpr (__is_same(CT, float))
          C[idx] = acc[m][n][jj];
        else
          C[idx] = __float2bfloat16(acc[m][n][jj]);
      }
}

// ---------------- epilogue: gate, v-update(+transpose), RoPE + RMSNorm ----------------
// qkv input is bf16 now; q output pre-scaled by QSCALE (exp2-domain scores).
__global__ __launch_bounds__(256) void epilogue_kernel(
    const bf16* __restrict__ qkv, const float* __restrict__ x,
    const float* __restrict__ ve, const float* __restrict__ cosT,
    const float* __restrict__ sinT, const float* __restrict__ Wg,
    bf16* __restrict__ qn, bf16* __restrict__ kn, bf16* __restrict__ vT) {
  int row = blockIdx.x;
  int bi = row >> 11, t = row & 2047;
  int tid = threadIdx.x, lane = tid & 63, w = tid >> 6;
  __shared__ float gate[NKV];
  size_t rb = (size_t)row * 3072;

  if (tid < 128) {
    int g = tid >> 5, i = tid & 31;
    float p = x[(size_t)row * CDIM + i] * Wg[i * 4 + g];
    p += __shfl_xor(p, 1);  p += __shfl_xor(p, 2);
    p += __shfl_xor(p, 4);  p += __shfl_xor(p, 8);
    p += __shfl_xor(p, 16);
    if (i == 0) gate[g] = 2.f / (1.f + __expf(-p));
  }
  __syncthreads();

  float cv = cosT[t * 64 + lane];
  float sv = sinT[t * 64 + lane];

  for (int it = 0; it < 4; ++it) {
    int h = it * 4 + w;
    float x1 = __bfloat162float(qkv[rb + h * 128 + lane]);
    float x2 = __bfloat162float(qkv[rb + h * 128 + 64 + lane]);
    float y1 = x1 * cv + x2 * sv;
    float y2 = x2 * cv - x1 * sv;
    float ss = y1 * y1 + y2 * y2;
    ss += __shfl_xor(ss, 1);  ss += __shfl_xor(ss, 2);  ss += __shfl_xor(ss, 4);
    ss += __shfl_xor(ss, 8);  ss += __shfl_xor(ss, 16); ss += __shfl_xor(ss, 32);
    float r = rsqrtf(ss * (1.f / 128.f) + 1e-6f) * QSCALE;
    size_t ob = (size_t)row * (NH * HD) + h * 128;
    qn[ob + lane] = __float2bfloat16(y1 * r);
    qn[ob + 64 + lane] = __float2bfloat16(y2 * r);
  }
  {
    int h = w;
    float x1 = __bfloat162float(qkv[rb + 2048 + h * 128 + lane]);
    float x2 = __bfloat162float(qkv[rb + 2048 + h * 128 + 64 + lane]);
    float y1 = x1 * cv + x2 * sv;
    float y2 = x2 * cv - x1 * sv;
    float ss = y1 * y1 + y2 * y2;
    ss += __shfl_xor(ss, 1);  ss += __shfl_xor(ss, 2);  ss += __shfl_xor(ss, 4);
    ss += __shfl_xor(ss, 8);  ss += __shfl_xor(ss, 16); ss += __shfl_xor(ss, 32);
    float r = rsqrtf(ss * (1.f / 128.f) + 1e-6f);
    size_t ob = (size_t)row * (NKV * HD) + h * 128;
    kn[ob + lane] = __float2bfloat16(y1 * r);
    kn[ob + 64 + lane] = __float2bfloat16(y2 * r);
  }
  for (int e = tid; e < 512; e += 256) {
    int kv = e >> 7, d = e & 127;
    float val = __bfloat162float(qkv[rb + 2560 + e]) + gate[kv] * ve[(size_t)row * 512 + e];
    vT[((size_t)(bi * NKV + kv) * HD + d) * T_ + t] = __float2bfloat16(val);
  }
}

// ---------------- flash attention: no-max softmax, double-buffered K/V ----------------
// RMSNorm => ||q||=||k||=sqrt(128); |score*log2e/sqrt(128)| <= 16.33 -> fp32-safe
// without max subtraction. id&7 = (bi,kvh) pins each K/V slice to one XCD's L2.
__global__ __launch_bounds__(256) void attn_kernel(
    const bf16* __restrict__ qn, const bf16* __restrict__ kn,
    const bf16* __restrict__ vT, bf16* __restrict__ y,
    const int* __restrict__ winp) {
  __shared__ __align__(16) bf16 sK[2][64 * 128];
  __shared__ __align__(16) bf16 sV[2][128 * 64];
  __shared__ __align__(16) bf16 sP[4][16 * 64];

  int win = *winp;
  int id = blockIdx.x;
  int g  = id & 7;
  int bi = g >> 2;
  int kvh = g & 3;
  int rem = id >> 3;
  int h  = kvh * 4 + (rem & 3);
  int jslot = (rem >> 2) & 7;
  int s5 = rem >> 5;
  int q0i = (s5 == 0) ? (2 * jslot) : (s5 == 1) ? (2 * jslot + 1)
          : (s5 == 2) ? (16 + jslot) : (31 - jslot);
  int q0 = q0i << 6;
  int tid = threadIdx.x;
  int lane = tid & 63, w = tid >> 6;
  int lr = lane & 15, lk = lane >> 4;

  short8 qf[4];
  {
    const bf16* qrow = qn + (size_t)(bi * T_ + q0 + w * 16 + lr) * (NH * HD) + h * HD;
    for (int c = 0; c < 4; ++c) qf[c] = *(const short8*)(qrow + c * 32 + lk * 8);
  }

  f32x4 o[8];
  for (int i = 0; i < 8; ++i) o[i] = (f32x4){0.f, 0.f, 0.f, 0.f};
  float lpart[4] = {0.f, 0.f, 0.f, 0.f};

  int jt0 = q0 >> 6;
  int hi = q0 + 62 + win; if (hi > T_ - 1) hi = T_ - 1;
  int jt1 = hi >> 6;
  const float NEGINF = -__builtin_inff();

  char* sPb = (char*)(&sP[w][0]);
  int prx = (lr & 7) << 4;

  auto stageKV = [&](int b, int jtx) {
    int j0x = jtx << 6;
    for (int i = 0; i < 4; ++i) {
      int c = i * 256 + tid;
      int r = c >> 4, sl = c & 15;
      gload_lds16(kn + (size_t)(bi * T_ + j0x + r) * (NKV * HD) + kvh * HD + ((sl ^ (r & 7)) * 8),
                  (char*)(&sK[b][0]) + c * 16);
    }
    for (int i = 0; i < 4; ++i) {
      int c = i * 256 + tid;
      int r = c >> 3, sl = c & 7;
      gload_lds16(vT + ((size_t)(bi * NKV + kvh) * HD + r) * T_ + j0x + ((sl ^ (r & 7)) * 8),
                  (char*)(&sV[b][0]) + c * 16);
    }
  };

  stageKV(0, jt0);
  __syncthreads();

  int buf = 0;
  for (int jt = jt0; jt <= jt1; ++jt) {
    int j0 = jt << 6;
    if (jt < jt1) stageKV(buf ^ 1, jt + 1);

    const char* sKb = (const char*)(&sK[buf][0]);
    const char* sVb = (const char*)(&sV[buf][0]);

    f32x4 s[4];
    for (int sub = 0; sub < 4; ++sub) s[sub] = (f32x4){0.f, 0.f, 0.f, 0.f};
    for (int sub = 0; sub < 4; ++sub) {
      int kr = sub * 16 + lr;
      int rx = (kr & 7) << 4;
      const char* rowb = sKb + kr * 256;
      for (int c = 0; c < 4; ++c) {
        short8 kf = *(const short8*)(rowb + ((c * 64 + lk * 16) ^ rx));
        s[sub] = __builtin_amdgcn_mfma_f32_16x16x32_bf16(qf[c], kf, s[sub], 0, 0, 0);
      }
    }

    bool full = (j0 >= q0 + 64) && (j0 + 64 <= q0 + win);
    int ibase = q0 + w * 16 + lk * 4;

    for (int jj = 0; jj < 4; ++jj) {
      int irow = ibase + jj;
      int pr = lk * 4 + jj;
      int pwx = (pr & 7) << 4;
      char* pb = sPb + pr * 128;
      float v0, v1, v2, v3;
      if (full) {
        v0 = s[0][jj]; v1 = s[1][jj]; v2 = s[2][jj]; v3 = s[3][jj];
      } else {
        int j = j0 + lr;
        v0 = (j >= irow && j - irow < win)           ? s[0][jj] : NEGINF;
        v1 = (j + 16 >= irow && j + 16 - irow < win) ? s[1][jj] : NEGINF;
        v2 = (j + 32 >= irow && j + 32 - irow < win) ? s[2][jj] : NEGINF;
        v3 = (j + 48 >= irow && j + 48 - irow < win) ? s[3][jj] : NEGINF;
      }
      float p0 = exp2f(v0), p1 = exp2f(v1);
      float p2 = exp2f(v2), p3 = exp2f(v3);
      lpart[jj] += (p0 + p1) + (p2 + p3);
      *(bf16*)(pb + ((lr * 2)      ^ pwx)) = __float2bfloat16(p0);
      *(bf16*)(pb + ((32 + lr * 2) ^ pwx)) = __float2bfloat16(p1);
      *(bf16*)(pb + ((64 + lr * 2) ^ pwx)) = __float2bfloat16(p2);
      *(bf16*)(pb + ((96 + lr * 2) ^ pwx)) = __float2bfloat16(p3);
    }

    short8 pf0 = *(const short8*)(sPb + lr * 128 + ((lk * 16)      ^ prx));
    short8 pf1 = *(const short8*)(sPb + lr * 128 + ((64 + lk * 16) ^ prx));
    for (int nb = 0; nb < 8; ++nb) {
      int vr = nb * 16 + lr;
      int vrx = (vr & 7) << 4;
      const char* vb = sVb + vr * 128;
      short8 vf0 = *(const short8*)(vb + ((lk * 16)      ^ vrx));
      short8 vf1 = *(const short8*)(vb + ((64 + lk * 16) ^ vrx));
      o[nb] = __builtin_amdgcn_mfma_f32_16x16x32_bf16(pf0, vf0, o[nb], 0, 0, 0);
      o[nb] = __builtin_amdgcn_mfma_f32_16x16x32_bf16(pf1, vf1, o[nb], 0, 0, 0);
    }
    __syncthreads();
    buf ^= 1;
  }

  for (int jj = 0; jj < 4; ++jj) {
    float l = lpart[jj];
    l += __shfl_xor(l, 1); l += __shfl_xor(l, 2);
    l += __shfl_xor(l, 4); l += __shfl_xor(l, 8);
    float inv = 1.f / l;
    size_t ob = (size_t)(bi * T_ + q0 + w * 16 + lk * 4 + jj) * (NH * HD) + h * HD;
    for (int nb = 0; nb < 8; ++nb)
      y[ob + nb * 16 + lr] = __float2bfloat16(o[nb][jj] * inv);
  }
}

extern "C" void kernel_launch(void* const* d_in, const int* in_sizes, int n_in,
                              void* d_out, int out_size, void* d_ws, size_t ws_size,
                              hipStream_t stream) {
  const float* x    = (const float*)d_in[0];
  const float* ve   = (const float*)d_in[1];
  const float* cosT = (const float*)d_in[2];
  const float* sinT = (const float*)d_in[3];
  const float* Wq   = (const float*)d_in[4];
  const float* Wk   = (const float*)d_in[5];
  const float* Wv   = (const float*)d_in[6];
  const float* Wg   = (const float*)d_in[7];
  const float* Wo   = (const float*)d_in[8];
  const int*   win  = (const int*)d_in[9];
  float* out = (float*)d_out;

  char* ws = (char*)d_ws;
  bf16*  xb   = (bf16*)(ws);                       // 16,777,216 B
  bf16*  wT   = (bf16*)(ws + 16777216);            // 12,582,912 B
  bf16*  woT  = (bf16*)(ws + 29360128);            //  8,388,608 B
  bf16*  qkvb = (bf16*)(ws + 37748736);            // 25,165,824 B  [4096][3072] bf16
  bf16*  qn   = (bf16*)(ws + 62914560);            // 16,777,216 B
  bf16*  kn   = (bf16*)(ws + 79691776);            //  4,194,304 B
  bf16*  vTb  = (bf16*)(ws + 83886080);            //  4,194,304 B
  bf16*  y    = qkvb;                              // alias (qkv dead after epilogue)

  cast_x_kernel<<<8192, 256, 0, stream>>>((const float4*)x, (ushort4*)xb, 2097152);
  cast_transpose<<<dim3(64, 64), 256, 0, stream>>>(Wq, wT, 2048, 2048);
  cast_transpose<<<dim3(16, 64), 256, 0, stream>>>(Wk, wT + (size_t)2048 * 2048, 2048, 512);
  cast_transpose<<<dim3(16, 64), 256, 0, stream>>>(Wv, wT + (size_t)2560 * 2048, 2048, 512);
  cast_transpose<<<dim3(64, 64), 256, 0, stream>>>(Wo, woT, 2048, 2048);

  gemm_bt2<bf16><<<768, 256, 0, stream>>>(xb, wT, qkvb, 4096, 3072, 2048, 24);
  epilogue_kernel<<<4096, 256, 0, stream>>>(qkvb, x, ve, cosT, sinT, Wg, qn, kn, vTb);
  attn_kernel<<<1024, 256, 0, stream>>>(qn, kn, vTb, y, win);
  gemm_bt2<float><<<512, 256, 0, stream>>>(y, woT, out, 4096, 2048, 2048, 16);
}

// Round 5
// 217.727 us; speedup vs baseline: 1.5568x; 1.0567x over previous
//
#include <hip/hip_runtime.h>
#include <hip/hip_bf16.h>
#include <cstdint>

typedef __hip_bfloat16 bf16;
typedef __attribute__((ext_vector_type(8))) short short8;
typedef __attribute__((ext_vector_type(4))) float f32x4;

#define T_   2048
#define CDIM 2048
#define NH   16
#define NKV  4
#define HD   128
// 1/sqrt(128) * log2(e), folded into q at the epilogue so attn scores are exp2-ready
#define QSCALE (0.08838834764831845f * 1.44269504088896340f)

__device__ __forceinline__ void gload_lds16(const void* g, void* l) {
  __builtin_amdgcn_global_load_lds(
      (const __attribute__((address_space(1))) void*)g,
      (__attribute__((address_space(3))) void*)l, 16, 0, 0);
}

// ---------------- cast x (fp32 -> bf16), vectorized ----------------
__global__ __launch_bounds__(256) void cast_x_kernel(const float4* __restrict__ in,
                                                     ushort4* __restrict__ out, int n4) {
  int i = blockIdx.x * 256 + threadIdx.x;
  if (i >= n4) return;
  float4 v = in[i];
  union { bf16 h[4]; ushort4 u; } cv;
  cv.h[0] = __float2bfloat16(v.x);
  cv.h[1] = __float2bfloat16(v.y);
  cv.h[2] = __float2bfloat16(v.z);
  cv.h[3] = __float2bfloat16(v.w);
  out[i] = cv.u;
}

// ---------------- cast + transpose W[K][N] fp32 -> WT[N][K] bf16 ----------------
__global__ __launch_bounds__(256) void cast_transpose(const float* __restrict__ W,
                                                      bf16* __restrict__ WT,
                                                      int K, int N) {
  __shared__ float tile[32][33];
  int k0 = blockIdx.y * 32, n0 = blockIdx.x * 32;
  int r = threadIdx.x >> 5, c = threadIdx.x & 31;  // r:0..7
  for (int i = 0; i < 4; ++i)
    tile[r + i * 8][c] = W[(size_t)(k0 + r + i * 8) * N + n0 + c];
  __syncthreads();
  for (int i = 0; i < 4; ++i)
    WT[(size_t)(n0 + r + i * 8) * K + k0 + c] = __float2bfloat16(tile[c][r + i * 8]);
}

// ---------------- GEMM 8-phase: A[M][K] bf16 * BT[N][K] bf16 -> C[M][N] ---------------
// 8 waves (2M x 4N), BN=256, BM=MREP*32 (MREP=8 -> 256, MREP=4 -> 128), BK=64.
// Per-wave output MREP*16 x 64. Double-buffered LDS (K-tile granularity), raw
// s_barrier + counted vmcnt (never 0 in steady state), XOR-swizzled LDS rows
// (8x16B slots per 128B row, slot ^= row&7; source pre-swizzled, linear dest).
// Phase split: B-frags once per K-tile, then MREP/2 phases of {4 ds_read A,
// setprio(1), 16 MFMA, setprio(0)}. Stage of tile kt+2 issues after the
// lgkm-barrier so the vmcnt-barrier wait overlaps load issue.
// Block->tile: 8 XCD regions in a 4x2 layout, each region RY x RX tiles.
template <int MREP, typename CT>
__global__ __launch_bounds__(512, 2) void gemm_8p(const bf16* __restrict__ A,
                                                  const bf16* __restrict__ BT,
                                                  CT* __restrict__ C,
                                                  int N, int K, int RY, int RX) {
  constexpr int BM = MREP * 32;
  constexpr int ALOADS = BM / 64;   // gload_lds per thread per K-tile for A
  __shared__ __align__(16) bf16 sA[2][BM * 64];
  __shared__ __align__(16) bf16 sB[2][256 * 64];

  int tid = threadIdx.x;
  int lane = tid & 63, w = tid >> 6;
  int wm = w >> 2, wn = w & 3;
  int lr = lane & 15, lk = lane >> 4;

  int xcd = blockIdx.x & 7, t = blockIdx.x >> 3;
  int by = (xcd >> 1) * RY + t / RX;
  int bx = (xcd & 1) * RX + t % RX;
  int m0 = by * BM, n0 = bx * 256;

  f32x4 acc[MREP][4];
#pragma unroll
  for (int m = 0; m < MREP; ++m)
#pragma unroll
    for (int n = 0; n < 4; ++n) acc[m][n] = (f32x4){0.f, 0.f, 0.f, 0.f};

  const bf16* Abase = A + (size_t)m0 * K;
  const bf16* Bbase = BT + (size_t)n0 * K;

  auto stage = [&](int b, int kt) {
    int kb = kt << 6;
#pragma unroll
    for (int i = 0; i < ALOADS; ++i) {
      int c = i * 512 + tid;
      int r = c >> 3, sl = c & 7;
      gload_lds16(Abase + (size_t)r * K + kb + ((sl ^ (r & 7)) << 3),
                  (char*)(&sA[b][0]) + c * 16);
    }
#pragma unroll
    for (int i = 0; i < 4; ++i) {
      int c = i * 512 + tid;
      int r = c >> 3, sl = c & 7;
      gload_lds16(Bbase + (size_t)r * K + kb + ((sl ^ (r & 7)) << 3),
                  (char*)(&sB[b][0]) + c * 16);
    }
  };

  int nk = K >> 6;
  stage(0, 0);
  stage(1, 1);
  if constexpr (MREP == 8)
    asm volatile("s_waitcnt vmcnt(8)\n\ts_barrier" ::: "memory");
  else
    asm volatile("s_waitcnt vmcnt(6)\n\ts_barrier" ::: "memory");

  for (int kt = 0; kt < nk; ++kt) {
    int d = kt & 1;
    const char* sAb = (const char*)(&sA[d][0]);
    const char* sBb = (const char*)(&sB[d][0]);

    short8 bfr[4][2];
#pragma unroll
    for (int n = 0; n < 4; ++n) {
      int row = wn * 64 + n * 16 + lr;
      const char* rb = sBb + row * 128;
      int rx = (row & 7) << 4;
      bfr[n][0] = *(const short8*)(rb + ((lk * 16) ^ rx));
      bfr[n][1] = *(const short8*)(rb + ((64 + lk * 16) ^ rx));
    }

#pragma unroll
    for (int p = 0; p < MREP / 2; ++p) {
      short8 af[2][2];
#pragma unroll
      for (int mi = 0; mi < 2; ++mi) {
        int row = wm * (MREP * 16) + (p * 2 + mi) * 16 + lr;
        const char* rb = sAb + row * 128;
        int rx = (row & 7) << 4;
        af[mi][0] = *(const short8*)(rb + ((lk * 16) ^ rx));
        af[mi][1] = *(const short8*)(rb + ((64 + lk * 16) ^ rx));
      }
      __builtin_amdgcn_s_setprio(1);
#pragma unroll
      for (int kk = 0; kk < 2; ++kk)
#pragma unroll
        for (int mi = 0; mi < 2; ++mi)
#pragma unroll
          for (int n = 0; n < 4; ++n)
            acc[p * 2 + mi][n] = __builtin_amdgcn_mfma_f32_16x16x32_bf16(
                af[mi][kk], bfr[n][kk], acc[p * 2 + mi][n], 0, 0, 0);
      __builtin_amdgcn_s_setprio(0);
    }

    // all waves' ds_reads of buffer d complete -> d is free to restage
    asm volatile("s_waitcnt lgkmcnt(0)\n\ts_barrier" ::: "memory");
    if (kt + 2 < nk) {
      stage(d, kt + 2);
      // wait: tile kt+1's loads landed (only kt+2's stay in flight)
      if constexpr (MREP == 8)
        asm volatile("s_waitcnt vmcnt(8)\n\ts_barrier" ::: "memory");
      else
        asm volatile("s_waitcnt vmcnt(6)\n\ts_barrier" ::: "memory");
    } else {
      asm volatile("s_waitcnt vmcnt(0)\n\ts_barrier" ::: "memory");
    }
  }

#pragma unroll
  for (int m = 0; m < MREP; ++m)
#pragma unroll
    for (int n = 0; n < 4; ++n)
#pragma unroll
      for (int jj = 0; jj < 4; ++jj) {
        size_t idx = (size_t)(m0 + wm * (MREP * 16) + m * 16 + lk * 4 + jj) * N +
                     n0 + wn * 64 + n * 16 + lr;
        if constexpr (__is_same(CT, float))
          C[idx] = acc[m][n][jj];
        else
          C[idx] = __float2bfloat16(acc[m][n][jj]);
      }
}

// ---------------- epilogue: gate, v-update(+transpose), RoPE + RMSNorm ----------------
// qkv input is bf16; q output pre-scaled by QSCALE (exp2-domain scores).
__global__ __launch_bounds__(256) void epilogue_kernel(
    const bf16* __restrict__ qkv, const float* __restrict__ x,
    const float* __restrict__ ve, const float* __restrict__ cosT,
    const float* __restrict__ sinT, const float* __restrict__ Wg,
    bf16* __restrict__ qn, bf16* __restrict__ kn, bf16* __restrict__ vT) {
  int row = blockIdx.x;
  int bi = row >> 11, t = row & 2047;
  int tid = threadIdx.x, lane = tid & 63, w = tid >> 6;
  __shared__ float gate[NKV];
  size_t rb = (size_t)row * 3072;

  if (tid < 128) {
    int g = tid >> 5, i = tid & 31;
    float p = x[(size_t)row * CDIM + i] * Wg[i * 4 + g];
    p += __shfl_xor(p, 1);  p += __shfl_xor(p, 2);
    p += __shfl_xor(p, 4);  p += __shfl_xor(p, 8);
    p += __shfl_xor(p, 16);
    if (i == 0) gate[g] = 2.f / (1.f + __expf(-p));
  }
  __syncthreads();

  float cv = cosT[t * 64 + lane];
  float sv = sinT[t * 64 + lane];

  for (int it = 0; it < 4; ++it) {
    int h = it * 4 + w;
    float x1 = __bfloat162float(qkv[rb + h * 128 + lane]);
    float x2 = __bfloat162float(qkv[rb + h * 128 + 64 + lane]);
    float y1 = x1 * cv + x2 * sv;
    float y2 = x2 * cv - x1 * sv;
    float ss = y1 * y1 + y2 * y2;
    ss += __shfl_xor(ss, 1);  ss += __shfl_xor(ss, 2);  ss += __shfl_xor(ss, 4);
    ss += __shfl_xor(ss, 8);  ss += __shfl_xor(ss, 16); ss += __shfl_xor(ss, 32);
    float r = rsqrtf(ss * (1.f / 128.f) + 1e-6f) * QSCALE;
    size_t ob = (size_t)row * (NH * HD) + h * 128;
    qn[ob + lane] = __float2bfloat16(y1 * r);
    qn[ob + 64 + lane] = __float2bfloat16(y2 * r);
  }
  {
    int h = w;
    float x1 = __bfloat162float(qkv[rb + 2048 + h * 128 + lane]);
    float x2 = __bfloat162float(qkv[rb + 2048 + h * 128 + 64 + lane]);
    float y1 = x1 * cv + x2 * sv;
    float y2 = x2 * cv - x1 * sv;
    float ss = y1 * y1 + y2 * y2;
    ss += __shfl_xor(ss, 1);  ss += __shfl_xor(ss, 2);  ss += __shfl_xor(ss, 4);
    ss += __shfl_xor(ss, 8);  ss += __shfl_xor(ss, 16); ss += __shfl_xor(ss, 32);
    float r = rsqrtf(ss * (1.f / 128.f) + 1e-6f);
    size_t ob = (size_t)row * (NKV * HD) + h * 128;
    kn[ob + lane] = __float2bfloat16(y1 * r);
    kn[ob + 64 + lane] = __float2bfloat16(y2 * r);
  }
  for (int e = tid; e < 512; e += 256) {
    int kv = e >> 7, d = e & 127;
    float val = __bfloat162float(qkv[rb + 2560 + e]) + gate[kv] * ve[(size_t)row * 512 + e];
    vT[((size_t)(bi * NKV + kv) * HD + d) * T_ + t] = __float2bfloat16(val);
  }
}

// ---------------- flash attention: no-max softmax, double-buffered K/V ----------------
// RMSNorm => ||q||=||k||=sqrt(128); |score*log2e/sqrt(128)| <= 16.33 -> fp32-safe
// without max subtraction. id&7 = (bi,kvh) pins each K/V slice to one XCD's L2.
__global__ __launch_bounds__(256) void attn_kernel(
    const bf16* __restrict__ qn, const bf16* __restrict__ kn,
    const bf16* __restrict__ vT, bf16* __restrict__ y,
    const int* __restrict__ winp) {
  __shared__ __align__(16) bf16 sK[2][64 * 128];
  __shared__ __align__(16) bf16 sV[2][128 * 64];
  __shared__ __align__(16) bf16 sP[4][16 * 64];

  int win = *winp;
  int id = blockIdx.x;
  int g  = id & 7;
  int bi = g >> 2;
  int kvh = g & 3;
  int rem = id >> 3;
  int h  = kvh * 4 + (rem & 3);
  int jslot = (rem >> 2) & 7;
  int s5 = rem >> 5;
  int q0i = (s5 == 0) ? (2 * jslot) : (s5 == 1) ? (2 * jslot + 1)
          : (s5 == 2) ? (16 + jslot) : (31 - jslot);
  int q0 = q0i << 6;
  int tid = threadIdx.x;
  int lane = tid & 63, w = tid >> 6;
  int lr = lane & 15, lk = lane >> 4;

  short8 qf[4];
  {
    const bf16* qrow = qn + (size_t)(bi * T_ + q0 + w * 16 + lr) * (NH * HD) + h * HD;
    for (int c = 0; c < 4; ++c) qf[c] = *(const short8*)(qrow + c * 32 + lk * 8);
  }

  f32x4 o[8];
  for (int i = 0; i < 8; ++i) o[i] = (f32x4){0.f, 0.f, 0.f, 0.f};
  float lpart[4] = {0.f, 0.f, 0.f, 0.f};

  int jt0 = q0 >> 6;
  int hi = q0 + 62 + win; if (hi > T_ - 1) hi = T_ - 1;
  int jt1 = hi >> 6;
  const float NEGINF = -__builtin_inff();

  char* sPb = (char*)(&sP[w][0]);
  int prx = (lr & 7) << 4;

  auto stageKV = [&](int b, int jtx) {
    int j0x = jtx << 6;
    for (int i = 0; i < 4; ++i) {
      int c = i * 256 + tid;
      int r = c >> 4, sl = c & 15;
      gload_lds16(kn + (size_t)(bi * T_ + j0x + r) * (NKV * HD) + kvh * HD + ((sl ^ (r & 7)) * 8),
                  (char*)(&sK[b][0]) + c * 16);
    }
    for (int i = 0; i < 4; ++i) {
      int c = i * 256 + tid;
      int r = c >> 3, sl = c & 7;
      gload_lds16(vT + ((size_t)(bi * NKV + kvh) * HD + r) * T_ + j0x + ((sl ^ (r & 7)) * 8),
                  (char*)(&sV[b][0]) + c * 16);
    }
  };

  stageKV(0, jt0);
  __syncthreads();

  int buf = 0;
  for (int jt = jt0; jt <= jt1; ++jt) {
    int j0 = jt << 6;
    if (jt < jt1) stageKV(buf ^ 1, jt + 1);

    const char* sKb = (const char*)(&sK[buf][0]);
    const char* sVb = (const char*)(&sV[buf][0]);

    f32x4 s[4];
    for (int sub = 0; sub < 4; ++sub) s[sub] = (f32x4){0.f, 0.f, 0.f, 0.f};
    for (int sub = 0; sub < 4; ++sub) {
      int kr = sub * 16 + lr;
      int rx = (kr & 7) << 4;
      const char* rowb = sKb + kr * 256;
      for (int c = 0; c < 4; ++c) {
        short8 kf = *(const short8*)(rowb + ((c * 64 + lk * 16) ^ rx));
        s[sub] = __builtin_amdgcn_mfma_f32_16x16x32_bf16(qf[c], kf, s[sub], 0, 0, 0);
      }
    }

    bool full = (j0 >= q0 + 64) && (j0 + 64 <= q0 + win);
    int ibase = q0 + w * 16 + lk * 4;

    for (int jj = 0; jj < 4; ++jj) {
      int irow = ibase + jj;
      int pr = lk * 4 + jj;
      int pwx = (pr & 7) << 4;
      char* pb = sPb + pr * 128;
      float v0, v1, v2, v3;
      if (full) {
        v0 = s[0][jj]; v1 = s[1][jj]; v2 = s[2][jj]; v3 = s[3][jj];
      } else {
        int j = j0 + lr;
        v0 = (j >= irow && j - irow < win)           ? s[0][jj] : NEGINF;
        v1 = (j + 16 >= irow && j + 16 - irow < win) ? s[1][jj] : NEGINF;
        v2 = (j + 32 >= irow && j + 32 - irow < win) ? s[2][jj] : NEGINF;
        v3 = (j + 48 >= irow && j + 48 - irow < win) ? s[3][jj] : NEGINF;
      }
      float p0 = exp2f(v0), p1 = exp2f(v1);
      float p2 = exp2f(v2), p3 = exp2f(v3);
      lpart[jj] += (p0 + p1) + (p2 + p3);
      *(bf16*)(pb + ((lr * 2)      ^ pwx)) = __float2bfloat16(p0);
      *(bf16*)(pb + ((32 + lr * 2) ^ pwx)) = __float2bfloat16(p1);
      *(bf16*)(pb + ((64 + lr * 2) ^ pwx)) = __float2bfloat16(p2);
      *(bf16*)(pb + ((96 + lr * 2) ^ pwx)) = __float2bfloat16(p3);
    }

    short8 pf0 = *(const short8*)(sPb + lr * 128 + ((lk * 16)      ^ prx));
    short8 pf1 = *(const short8*)(sPb + lr * 128 + ((64 + lk * 16) ^ prx));
    for (int nb = 0; nb < 8; ++nb) {
      int vr = nb * 16 + lr;
      int vrx = (vr & 7) << 4;
      const char* vb = sVb + vr * 128;
      short8 vf0 = *(const short8*)(vb + ((lk * 16)      ^ vrx));
      short8 vf1 = *(const short8*)(vb + ((64 + lk * 16) ^ vrx));
      o[nb] = __builtin_amdgcn_mfma_f32_16x16x32_bf16(pf0, vf0, o[nb], 0, 0, 0);
      o[nb] = __builtin_amdgcn_mfma_f32_16x16x32_bf16(pf1, vf1, o[nb], 0, 0, 0);
    }
    __syncthreads();
    buf ^= 1;
  }

  for (int jj = 0; jj < 4; ++jj) {
    float l = lpart[jj];
    l += __shfl_xor(l, 1); l += __shfl_xor(l, 2);
    l += __shfl_xor(l, 4); l += __shfl_xor(l, 8);
    float inv = 1.f / l;
    size_t ob = (size_t)(bi * T_ + q0 + w * 16 + lk * 4 + jj) * (NH * HD) + h * HD;
    for (int nb = 0; nb < 8; ++nb)
      y[ob + nb * 16 + lr] = __float2bfloat16(o[nb][jj] * inv);
  }
}

extern "C" void kernel_launch(void* const* d_in, const int* in_sizes, int n_in,
                              void* d_out, int out_size, void* d_ws, size_t ws_size,
                              hipStream_t stream) {
  const float* x    = (const float*)d_in[0];
  const float* ve   = (const float*)d_in[1];
  const float* cosT = (const float*)d_in[2];
  const float* sinT = (const float*)d_in[3];
  const float* Wq   = (const float*)d_in[4];
  const float* Wk   = (const float*)d_in[5];
  const float* Wv   = (const float*)d_in[6];
  const float* Wg   = (const float*)d_in[7];
  const float* Wo   = (const float*)d_in[8];
  const int*   win  = (const int*)d_in[9];
  float* out = (float*)d_out;

  char* ws = (char*)d_ws;
  bf16*  xb   = (bf16*)(ws);                       // 16,777,216 B
  bf16*  wT   = (bf16*)(ws + 16777216);            // 12,582,912 B
  bf16*  woT  = (bf16*)(ws + 29360128);            //  8,388,608 B
  bf16*  qkvb = (bf16*)(ws + 37748736);            // 25,165,824 B  [4096][3072] bf16
  bf16*  qn   = (bf16*)(ws + 62914560);            // 16,777,216 B
  bf16*  kn   = (bf16*)(ws + 79691776);            //  4,194,304 B
  bf16*  vTb  = (bf16*)(ws + 83886080);            //  4,194,304 B
  bf16*  y    = qkvb;                              // alias (qkv dead after epilogue)

  cast_x_kernel<<<8192, 256, 0, stream>>>((const float4*)x, (ushort4*)xb, 2097152);
  cast_transpose<<<dim3(64, 64), 256, 0, stream>>>(Wq, wT, 2048, 2048);
  cast_transpose<<<dim3(16, 64), 256, 0, stream>>>(Wk, wT + (size_t)2048 * 2048, 2048, 512);
  cast_transpose<<<dim3(16, 64), 256, 0, stream>>>(Wv, wT + (size_t)2560 * 2048, 2048, 512);
  cast_transpose<<<dim3(64, 64), 256, 0, stream>>>(Wo, woT, 2048, 2048);

  // QKV: M=4096 (16 tile-rows), N=3072 (12 tile-cols), 192 blocks; regions 4x6
  gemm_8p<8, bf16><<<192, 512, 0, stream>>>(xb, wT, qkvb, 3072, 2048, 4, 6);
  epilogue_kernel<<<4096, 256, 0, stream>>>(qkvb, x, ve, cosT, sinT, Wg, qn, kn, vTb);
  attn_kernel<<<1024, 256, 0, stream>>>(qn, kn, vTb, y, win);
  // Wo: BM=128 -> M=4096 (32 tile-rows), N=2048 (8 tile-cols), 256 blocks; regions 8x4
  gemm_8p<4, float><<<256, 512, 0, stream>>>(y, woT, out, 2048, 2048, 8, 4);
}

// Round 6
// 212.313 us; speedup vs baseline: 1.5965x; 1.0255x over previous
//
#include <hip/hip_runtime.h>
#include <hip/hip_bf16.h>
#include <cstdint>

typedef __hip_bfloat16 bf16;
typedef __attribute__((ext_vector_type(8))) short short8;
typedef __attribute__((ext_vector_type(4))) float f32x4;

#define T_   2048
#define CDIM 2048
#define NH   16
#define NKV  4
#define HD   128
// 1/sqrt(128) * log2(e), folded into q at the epilogue so attn scores are exp2-ready
#define QSCALE (0.08838834764831845f * 1.44269504088896340f)

__device__ __forceinline__ void gload_lds16(const void* g, void* l) {
  __builtin_amdgcn_global_load_lds(
      (const __attribute__((address_space(1))) void*)g,
      (__attribute__((address_space(3))) void*)l, 16, 0, 0);
}

// ---------------- cast x (fp32 -> bf16), vectorized ----------------
__global__ __launch_bounds__(256) void cast_x_kernel(const float4* __restrict__ in,
                                                     ushort4* __restrict__ out, int n4) {
  int i = blockIdx.x * 256 + threadIdx.x;
  if (i >= n4) return;
  float4 v = in[i];
  union { bf16 h[4]; ushort4 u; } cv;
  cv.h[0] = __float2bfloat16(v.x);
  cv.h[1] = __float2bfloat16(v.y);
  cv.h[2] = __float2bfloat16(v.z);
  cv.h[3] = __float2bfloat16(v.w);
  out[i] = cv.u;
}

// ---------------- cast + transpose W[K][N] fp32 -> WT[N][K] bf16 ----------------
__global__ __launch_bounds__(256) void cast_transpose(const float* __restrict__ W,
                                                      bf16* __restrict__ WT,
                                                      int K, int N) {
  __shared__ float tile[32][33];
  int k0 = blockIdx.y * 32, n0 = blockIdx.x * 32;
  int r = threadIdx.x >> 5, c = threadIdx.x & 31;  // r:0..7
  for (int i = 0; i < 4; ++i)
    tile[r + i * 8][c] = W[(size_t)(k0 + r + i * 8) * N + n0 + c];
  __syncthreads();
  for (int i = 0; i < 4; ++i)
    WT[(size_t)(n0 + r + i * 8) * K + k0 + c] = __float2bfloat16(tile[c][r + i * 8]);
}

// ---------------- QKV GEMM: per-phase interleaved 256x256x64 pipeline ----------------
// 8 waves (2M x 4N), wave tile 128x64. 4 quadrant-phases per K-tile; each phase:
// {ds_read quadrant (4) [+B(8) at q0] | stage one region of tile kt+2 ->
//  lgkmcnt(0)+sched_barrier -> setprio(1) 16 MFMA setprio(0) -> s_barrier}.
// Region staging placed one phase after the region's last read (race-free via the
// phase-end lgkm-drain + barrier). Counted vmcnt(7) once per K-tile (8 loads = one
// tile in flight). LDS XOR-swizzle (slot ^= row&7), source pre-swizzled.
__global__ __launch_bounds__(512, 2) void gemm_qkv8(const bf16* __restrict__ A,
                                                    const bf16* __restrict__ BT,
                                                    bf16* __restrict__ C,
                                                    int N, int K, int RY, int RX) {
  __shared__ __align__(16) bf16 sA[2][256 * 64];
  __shared__ __align__(16) bf16 sB[2][256 * 64];

  int tid = threadIdx.x;
  int lane = tid & 63, w = tid >> 6;
  int wm = w >> 2, wn = w & 3;
  int lr = lane & 15, lk = lane >> 4;

  int xcd = blockIdx.x & 7, t = blockIdx.x >> 3;
  int by = (xcd >> 1) * RY + t / RX;
  int bx = (xcd & 1) * RX + t % RX;
  int m0 = by * 256, n0 = bx * 256;

  f32x4 acc[8][4];
#pragma unroll
  for (int m = 0; m < 8; ++m)
#pragma unroll
    for (int n = 0; n < 4; ++n) acc[m][n] = (f32x4){0.f, 0.f, 0.f, 0.f};

  const bf16* Abase = A + (size_t)m0 * K;
  const bf16* Bbase = BT + (size_t)n0 * K;

  // B tile [256][64]: 4 loads/thread
  auto stageB = [&](int p, int kt) {
    int kb = kt << 6;
#pragma unroll
    for (int i = 0; i < 4; ++i) {
      int c = i * 512 + tid;
      int r = c >> 3, sl = c & 7;
      gload_lds16(Bbase + (size_t)r * K + kb + ((sl ^ (r & 7)) << 3),
                  (char*)(&sB[p][0]) + c * 16);
    }
  };
  // A quadrant q: rows {32q..32q+31} u {128+32q..128+32q+31}, 1 load/thread
  auto stageAq = [&](int p, int kt, int q) {
    int kb = kt << 6;
    int rbase = 32 * q + ((w & 3) << 3) + ((w >> 2) << 7);  // wave-uniform
    int r = rbase + (lane >> 3), sl = lane & 7;
    gload_lds16(Abase + (size_t)r * K + kb + ((sl ^ (r & 7)) << 3),
                (char*)(&sA[p][0]) + rbase * 128 + lane * 16);
  };

  int nk = K >> 6;
  // prologue: tile0 full (8 loads) + tile1 B,Aq0,Aq1,Aq2 (7 loads)
  stageB(0, 0);
  stageAq(0, 0, 0); stageAq(0, 0, 1); stageAq(0, 0, 2); stageAq(0, 0, 3);
  stageB(1, 1);
  stageAq(1, 1, 0); stageAq(1, 1, 1); stageAq(1, 1, 2);
  asm volatile("s_waitcnt vmcnt(7)" ::: "memory");
  __builtin_amdgcn_s_barrier();

#define READ_A(Q)                                                          \
  {                                                                        \
    _Pragma("unroll")                                                      \
    for (int mi = 0; mi < 2; ++mi) {                                       \
      int row = wm * 128 + (2 * (Q) + mi) * 16 + lr;                       \
      const char* rb = sAb + row * 128;                                    \
      int rx = (row & 7) << 4;                                             \
      af[mi][0] = *(const short8*)(rb + ((lk * 16) ^ rx));                 \
      af[mi][1] = *(const short8*)(rb + ((64 + lk * 16) ^ rx));            \
    }                                                                      \
  }
#define MFMA_Q(Q)                                                          \
  __builtin_amdgcn_s_setprio(1);                                          \
  _Pragma("unroll")                                                        \
  for (int kk = 0; kk < 2; ++kk)                                           \
    _Pragma("unroll")                                                      \
    for (int mi = 0; mi < 2; ++mi)                                         \
      _Pragma("unroll")                                                    \
      for (int n = 0; n < 4; ++n)                                          \
        acc[2 * (Q) + mi][n] = __builtin_amdgcn_mfma_f32_16x16x32_bf16(    \
            af[mi][kk], bfr[n][kk], acc[2 * (Q) + mi][n], 0, 0, 0);        \
  __builtin_amdgcn_s_setprio(0);
#define LGKM_FENCE                                                         \
  asm volatile("s_waitcnt lgkmcnt(0)" ::: "memory");                       \
  __builtin_amdgcn_sched_barrier(0);

  for (int kt = 0; kt < nk; ++kt) {
    int p = kt & 1;
    const char* sAb = (const char*)(&sA[p][0]);
    const char* sBb = (const char*)(&sB[p][0]);
    short8 bfr[4][2], af[2][2];

    // ---- phase 0: B(8) + A-q0(4); stage Aq3 of tile kt+1 ----
#pragma unroll
    for (int n = 0; n < 4; ++n) {
      int row = wn * 64 + n * 16 + lr;
      const char* rb = sBb + row * 128;
      int rx = (row & 7) << 4;
      bfr[n][0] = *(const short8*)(rb + ((lk * 16) ^ rx));
      bfr[n][1] = *(const short8*)(rb + ((64 + lk * 16) ^ rx));
    }
    READ_A(0);
    if (kt + 1 < nk) stageAq(p ^ 1, kt + 1, 3);
    LGKM_FENCE;
    MFMA_Q(0);
    __builtin_amdgcn_s_barrier();

    // ---- phase 1: A-q1; stage B + Aq0 of tile kt+2 ----
    READ_A(1);
    if (kt + 2 < nk) { stageB(p, kt + 2); stageAq(p, kt + 2, 0); }
    LGKM_FENCE;
    MFMA_Q(1);
    __builtin_amdgcn_s_barrier();

    // ---- phase 2: A-q2; stage Aq1 of tile kt+2 ----
    READ_A(2);
    if (kt + 2 < nk) stageAq(p, kt + 2, 1);
    LGKM_FENCE;
    MFMA_Q(2);
    __builtin_amdgcn_s_barrier();

    // ---- phase 3: A-q3; stage Aq2 of tile kt+2; iter gate vmcnt(7) ----
    READ_A(3);
    if (kt + 2 < nk) stageAq(p, kt + 2, 2);
    LGKM_FENCE;
    MFMA_Q(3);
    if (kt + 2 < nk)
      asm volatile("s_waitcnt vmcnt(7)" ::: "memory");
    else
      asm volatile("s_waitcnt vmcnt(0)" ::: "memory");
    __builtin_amdgcn_s_barrier();
  }
#undef READ_A
#undef MFMA_Q
#undef LGKM_FENCE

#pragma unroll
  for (int m = 0; m < 8; ++m)
#pragma unroll
    for (int n = 0; n < 4; ++n)
#pragma unroll
      for (int jj = 0; jj < 4; ++jj)
        C[(size_t)(m0 + wm * 128 + m * 16 + lk * 4 + jj) * N +
          n0 + wn * 64 + n * 16 + lr] = __float2bfloat16(acc[m][n][jj]);
}

// ---------------- GEMM 8-phase (round-5 structure), used for Wo ----------------
template <int MREP, typename CT>
__global__ __launch_bounds__(512, 2) void gemm_8p(const bf16* __restrict__ A,
                                                  const bf16* __restrict__ BT,
                                                  CT* __restrict__ C,
                                                  int N, int K, int RY, int RX) {
  constexpr int BM = MREP * 32;
  constexpr int ALOADS = BM / 64;
  __shared__ __align__(16) bf16 sA[2][BM * 64];
  __shared__ __align__(16) bf16 sB[2][256 * 64];

  int tid = threadIdx.x;
  int lane = tid & 63, w = tid >> 6;
  int wm = w >> 2, wn = w & 3;
  int lr = lane & 15, lk = lane >> 4;

  int xcd = blockIdx.x & 7, t = blockIdx.x >> 3;
  int by = (xcd >> 1) * RY + t / RX;
  int bx = (xcd & 1) * RX + t % RX;
  int m0 = by * BM, n0 = bx * 256;

  f32x4 acc[MREP][4];
#pragma unroll
  for (int m = 0; m < MREP; ++m)
#pragma unroll
    for (int n = 0; n < 4; ++n) acc[m][n] = (f32x4){0.f, 0.f, 0.f, 0.f};

  const bf16* Abase = A + (size_t)m0 * K;
  const bf16* Bbase = BT + (size_t)n0 * K;

  auto stage = [&](int b, int kt) {
    int kb = kt << 6;
#pragma unroll
    for (int i = 0; i < ALOADS; ++i) {
      int c = i * 512 + tid;
      int r = c >> 3, sl = c & 7;
      gload_lds16(Abase + (size_t)r * K + kb + ((sl ^ (r & 7)) << 3),
                  (char*)(&sA[b][0]) + c * 16);
    }
#pragma unroll
    for (int i = 0; i < 4; ++i) {
      int c = i * 512 + tid;
      int r = c >> 3, sl = c & 7;
      gload_lds16(Bbase + (size_t)r * K + kb + ((sl ^ (r & 7)) << 3),
                  (char*)(&sB[b][0]) + c * 16);
    }
  };

  int nk = K >> 6;
  stage(0, 0);
  stage(1, 1);
  asm volatile("s_waitcnt vmcnt(6)" ::: "memory");
  __builtin_amdgcn_s_barrier();

  for (int kt = 0; kt < nk; ++kt) {
    int d = kt & 1;
    const char* sAb = (const char*)(&sA[d][0]);
    const char* sBb = (const char*)(&sB[d][0]);

    short8 bfr[4][2];
#pragma unroll
    for (int n = 0; n < 4; ++n) {
      int row = wn * 64 + n * 16 + lr;
      const char* rb = sBb + row * 128;
      int rx = (row & 7) << 4;
      bfr[n][0] = *(const short8*)(rb + ((lk * 16) ^ rx));
      bfr[n][1] = *(const short8*)(rb + ((64 + lk * 16) ^ rx));
    }

#pragma unroll
    for (int p = 0; p < MREP / 2; ++p) {
      short8 af[2][2];
#pragma unroll
      for (int mi = 0; mi < 2; ++mi) {
        int row = wm * (MREP * 16) + (p * 2 + mi) * 16 + lr;
        const char* rb = sAb + row * 128;
        int rx = (row & 7) << 4;
        af[mi][0] = *(const short8*)(rb + ((lk * 16) ^ rx));
        af[mi][1] = *(const short8*)(rb + ((64 + lk * 16) ^ rx));
      }
      __builtin_amdgcn_s_setprio(1);
#pragma unroll
      for (int kk = 0; kk < 2; ++kk)
#pragma unroll
        for (int mi = 0; mi < 2; ++mi)
#pragma unroll
          for (int n = 0; n < 4; ++n)
            acc[p * 2 + mi][n] = __builtin_amdgcn_mfma_f32_16x16x32_bf16(
                af[mi][kk], bfr[n][kk], acc[p * 2 + mi][n], 0, 0, 0);
      __builtin_amdgcn_s_setprio(0);
    }

    asm volatile("s_waitcnt lgkmcnt(0)\n\ts_barrier" ::: "memory");
    if (kt + 2 < nk) {
      stage(d, kt + 2);
      asm volatile("s_waitcnt vmcnt(6)\n\ts_barrier" ::: "memory");
    } else {
      asm volatile("s_waitcnt vmcnt(0)\n\ts_barrier" ::: "memory");
    }
  }

#pragma unroll
  for (int m = 0; m < MREP; ++m)
#pragma unroll
    for (int n = 0; n < 4; ++n)
#pragma unroll
      for (int jj = 0; jj < 4; ++jj) {
        size_t idx = (size_t)(m0 + wm * (MREP * 16) + m * 16 + lk * 4 + jj) * N +
                     n0 + wn * 64 + n * 16 + lr;
        if constexpr (__is_same(CT, float))
          C[idx] = acc[m][n][jj];
        else
          C[idx] = __float2bfloat16(acc[m][n][jj]);
      }
}

// ---------------- epilogue: gate, v-update(+transpose), RoPE + RMSNorm ----------------
__global__ __launch_bounds__(256) void epilogue_kernel(
    const bf16* __restrict__ qkv, const float* __restrict__ x,
    const float* __restrict__ ve, const float* __restrict__ cosT,
    const float* __restrict__ sinT, const float* __restrict__ Wg,
    bf16* __restrict__ qn, bf16* __restrict__ kn, bf16* __restrict__ vT) {
  int row = blockIdx.x;
  int bi = row >> 11, t = row & 2047;
  int tid = threadIdx.x, lane = tid & 63, w = tid >> 6;
  __shared__ float gate[NKV];
  size_t rb = (size_t)row * 3072;

  if (tid < 128) {
    int g = tid >> 5, i = tid & 31;
    float p = x[(size_t)row * CDIM + i] * Wg[i * 4 + g];
    p += __shfl_xor(p, 1);  p += __shfl_xor(p, 2);
    p += __shfl_xor(p, 4);  p += __shfl_xor(p, 8);
    p += __shfl_xor(p, 16);
    if (i == 0) gate[g] = 2.f / (1.f + __expf(-p));
  }
  __syncthreads();

  float cv = cosT[t * 64 + lane];
  float sv = sinT[t * 64 + lane];

  for (int it = 0; it < 4; ++it) {
    int h = it * 4 + w;
    float x1 = __bfloat162float(qkv[rb + h * 128 + lane]);
    float x2 = __bfloat162float(qkv[rb + h * 128 + 64 + lane]);
    float y1 = x1 * cv + x2 * sv;
    float y2 = x2 * cv - x1 * sv;
    float ss = y1 * y1 + y2 * y2;
    ss += __shfl_xor(ss, 1);  ss += __shfl_xor(ss, 2);  ss += __shfl_xor(ss, 4);
    ss += __shfl_xor(ss, 8);  ss += __shfl_xor(ss, 16); ss += __shfl_xor(ss, 32);
    float r = rsqrtf(ss * (1.f / 128.f) + 1e-6f) * QSCALE;
    size_t ob = (size_t)row * (NH * HD) + h * 128;
    qn[ob + lane] = __float2bfloat16(y1 * r);
    qn[ob + 64 + lane] = __float2bfloat16(y2 * r);
  }
  {
    int h = w;
    float x1 = __bfloat162float(qkv[rb + 2048 + h * 128 + lane]);
    float x2 = __bfloat162float(qkv[rb + 2048 + h * 128 + 64 + lane]);
    float y1 = x1 * cv + x2 * sv;
    float y2 = x2 * cv - x1 * sv;
    float ss = y1 * y1 + y2 * y2;
    ss += __shfl_xor(ss, 1);  ss += __shfl_xor(ss, 2);  ss += __shfl_xor(ss, 4);
    ss += __shfl_xor(ss, 8);  ss += __shfl_xor(ss, 16); ss += __shfl_xor(ss, 32);
    float r = rsqrtf(ss * (1.f / 128.f) + 1e-6f);
    size_t ob = (size_t)row * (NKV * HD) + h * 128;
    kn[ob + lane] = __float2bfloat16(y1 * r);
    kn[ob + 64 + lane] = __float2bfloat16(y2 * r);
  }
  for (int e = tid; e < 512; e += 256) {
    int kv = e >> 7, d = e & 127;
    float val = __bfloat162float(qkv[rb + 2560 + e]) + gate[kv] * ve[(size_t)row * 512 + e];
    vT[((size_t)(bi * NKV + kv) * HD + d) * T_ + t] = __float2bfloat16(val);
  }
}

// ---------------- flash attention: no-max softmax, double-buffered K/V ----------------
__global__ __launch_bounds__(256) void attn_kernel(
    const bf16* __restrict__ qn, const bf16* __restrict__ kn,
    const bf16* __restrict__ vT, bf16* __restrict__ y,
    const int* __restrict__ winp) {
  __shared__ __align__(16) bf16 sK[2][64 * 128];
  __shared__ __align__(16) bf16 sV[2][128 * 64];
  __shared__ __align__(16) bf16 sP[4][16 * 64];

  int win = *winp;
  int id = blockIdx.x;
  int g  = id & 7;
  int bi = g >> 2;
  int kvh = g & 3;
  int rem = id >> 3;
  int h  = kvh * 4 + (rem & 3);
  int jslot = (rem >> 2) & 7;
  int s5 = rem >> 5;
  int q0i = (s5 == 0) ? (2 * jslot) : (s5 == 1) ? (2 * jslot + 1)
          : (s5 == 2) ? (16 + jslot) : (31 - jslot);
  int q0 = q0i << 6;
  int tid = threadIdx.x;
  int lane = tid & 63, w = tid >> 6;
  int lr = lane & 15, lk = lane >> 4;

  short8 qf[4];
  {
    const bf16* qrow = qn + (size_t)(bi * T_ + q0 + w * 16 + lr) * (NH * HD) + h * HD;
    for (int c = 0; c < 4; ++c) qf[c] = *(const short8*)(qrow + c * 32 + lk * 8);
  }

  f32x4 o[8];
  for (int i = 0; i < 8; ++i) o[i] = (f32x4){0.f, 0.f, 0.f, 0.f};
  float lpart[4] = {0.f, 0.f, 0.f, 0.f};

  int jt0 = q0 >> 6;
  int hi = q0 + 62 + win; if (hi > T_ - 1) hi = T_ - 1;
  int jt1 = hi >> 6;
  const float NEGINF = -__builtin_inff();

  char* sPb = (char*)(&sP[w][0]);
  int prx = (lr & 7) << 4;

  auto stageKV = [&](int b, int jtx) {
    int j0x = jtx << 6;
    for (int i = 0; i < 4; ++i) {
      int c = i * 256 + tid;
      int r = c >> 4, sl = c & 15;
      gload_lds16(kn + (size_t)(bi * T_ + j0x + r) * (NKV * HD) + kvh * HD + ((sl ^ (r & 7)) * 8),
                  (char*)(&sK[b][0]) + c * 16);
    }
    for (int i = 0; i < 4; ++i) {
      int c = i * 256 + tid;
      int r = c >> 3, sl = c & 7;
      gload_lds16(vT + ((size_t)(bi * NKV + kvh) * HD + r) * T_ + j0x + ((sl ^ (r & 7)) * 8),
                  (char*)(&sV[b][0]) + c * 16);
    }
  };

  stageKV(0, jt0);
  __syncthreads();

  int buf = 0;
  for (int jt = jt0; jt <= jt1; ++jt) {
    int j0 = jt << 6;
    if (jt < jt1) stageKV(buf ^ 1, jt + 1);

    const char* sKb = (const char*)(&sK[buf][0]);
    const char* sVb = (const char*)(&sV[buf][0]);

    f32x4 s[4];
    for (int sub = 0; sub < 4; ++sub) s[sub] = (f32x4){0.f, 0.f, 0.f, 0.f};
    for (int sub = 0; sub < 4; ++sub) {
      int kr = sub * 16 + lr;
      int rx = (kr & 7) << 4;
      const char* rowb = sKb + kr * 256;
      for (int c = 0; c < 4; ++c) {
        short8 kf = *(const short8*)(rowb + ((c * 64 + lk * 16) ^ rx));
        s[sub] = __builtin_amdgcn_mfma_f32_16x16x32_bf16(qf[c], kf, s[sub], 0, 0, 0);
      }
    }

    bool full = (j0 >= q0 + 64) && (j0 + 64 <= q0 + win);
    int ibase = q0 + w * 16 + lk * 4;

    for (int jj = 0; jj < 4; ++jj) {
      int irow = ibase + jj;
      int pr = lk * 4 + jj;
      int pwx = (pr & 7) << 4;
      char* pb = sPb + pr * 128;
      float v0, v1, v2, v3;
      if (full) {
        v0 = s[0][jj]; v1 = s[1][jj]; v2 = s[2][jj]; v3 = s[3][jj];
      } else {
        int j = j0 + lr;
        v0 = (j >= irow && j - irow < win)           ? s[0][jj] : NEGINF;
        v1 = (j + 16 >= irow && j + 16 - irow < win) ? s[1][jj] : NEGINF;
        v2 = (j + 32 >= irow && j + 32 - irow < win) ? s[2][jj] : NEGINF;
        v3 = (j + 48 >= irow && j + 48 - irow < win) ? s[3][jj] : NEGINF;
      }
      float p0 = exp2f(v0), p1 = exp2f(v1);
      float p2 = exp2f(v2), p3 = exp2f(v3);
      lpart[jj] += (p0 + p1) + (p2 + p3);
      *(bf16*)(pb + ((lr * 2)      ^ pwx)) = __float2bfloat16(p0);
      *(bf16*)(pb + ((32 + lr * 2) ^ pwx)) = __float2bfloat16(p1);
      *(bf16*)(pb + ((64 + lr * 2) ^ pwx)) = __float2bfloat16(p2);
      *(bf16*)(pb + ((96 + lr * 2) ^ pwx)) = __float2bfloat16(p3);
    }

    short8 pf0 = *(const short8*)(sPb + lr * 128 + ((lk * 16)      ^ prx));
    short8 pf1 = *(const short8*)(sPb + lr * 128 + ((64 + lk * 16) ^ prx));
    for (int nb = 0; nb < 8; ++nb) {
      int vr = nb * 16 + lr;
      int vrx = (vr & 7) << 4;
      const char* vb = sVb + vr * 128;
      short8 vf0 = *(const short8*)(vb + ((lk * 16)      ^ vrx));
      short8 vf1 = *(const short8*)(vb + ((64 + lk * 16) ^ vrx));
      o[nb] = __builtin_amdgcn_mfma_f32_16x16x32_bf16(pf0, vf0, o[nb], 0, 0, 0);
      o[nb] = __builtin_amdgcn_mfma_f32_16x16x32_bf16(pf1, vf1, o[nb], 0, 0, 0);
    }
    __syncthreads();
    buf ^= 1;
  }

  for (int jj = 0; jj < 4; ++jj) {
    float l = lpart[jj];
    l += __shfl_xor(l, 1); l += __shfl_xor(l, 2);
    l += __shfl_xor(l, 4); l += __shfl_xor(l, 8);
    float inv = 1.f / l;
    size_t ob = (size_t)(bi * T_ + q0 + w * 16 + lk * 4 + jj) * (NH * HD) + h * HD;
    for (int nb = 0; nb < 8; ++nb)
      y[ob + nb * 16 + lr] = __float2bfloat16(o[nb][jj] * inv);
  }
}

extern "C" void kernel_launch(void* const* d_in, const int* in_sizes, int n_in,
                              void* d_out, int out_size, void* d_ws, size_t ws_size,
                              hipStream_t stream) {
  const float* x    = (const float*)d_in[0];
  const float* ve   = (const float*)d_in[1];
  const float* cosT = (const float*)d_in[2];
  const float* sinT = (const float*)d_in[3];
  const float* Wq   = (const float*)d_in[4];
  const float* Wk   = (const float*)d_in[5];
  const float* Wv   = (const float*)d_in[6];
  const float* Wg   = (const float*)d_in[7];
  const float* Wo   = (const float*)d_in[8];
  const int*   win  = (const int*)d_in[9];
  float* out = (float*)d_out;

  char* ws = (char*)d_ws;
  bf16*  xb   = (bf16*)(ws);
  bf16*  wT   = (bf16*)(ws + 16777216);
  bf16*  woT  = (bf16*)(ws + 29360128);
  bf16*  qkvb = (bf16*)(ws + 37748736);
  bf16*  qn   = (bf16*)(ws + 62914560);
  bf16*  kn   = (bf16*)(ws + 79691776);
  bf16*  vTb  = (bf16*)(ws + 83886080);
  bf16*  y    = qkvb;

  cast_x_kernel<<<8192, 256, 0, stream>>>((const float4*)x, (ushort4*)xb, 2097152);
  cast_transpose<<<dim3(64, 64), 256, 0, stream>>>(Wq, wT, 2048, 2048);
  cast_transpose<<<dim3(16, 64), 256, 0, stream>>>(Wk, wT + (size_t)2048 * 2048, 2048, 512);
  cast_transpose<<<dim3(16, 64), 256, 0, stream>>>(Wv, wT + (size_t)2560 * 2048, 2048, 512);
  cast_transpose<<<dim3(64, 64), 256, 0, stream>>>(Wo, woT, 2048, 2048);

  // QKV: 16x12 tiles of 256x256, 192 blocks; XCD regions 4x6
  gemm_qkv8<<<192, 512, 0, stream>>>(xb, wT, qkvb, 3072, 2048, 4, 6);
  epilogue_kernel<<<4096, 256, 0, stream>>>(qkvb, x, ve, cosT, sinT, Wg, qn, kn, vTb);
  attn_kernel<<<1024, 256, 0, stream>>>(qn, kn, vTb, y, win);
  // Wo: BM=128 -> 32x8 tiles, 256 blocks; regions 8x4
  gemm_8p<4, float><<<256, 512, 0, stream>>>(y, woT, out, 2048, 2048, 8, 4);
}

// Round 7
// 200.934 us; speedup vs baseline: 1.6870x; 1.0566x over previous
//
#include <hip/hip_runtime.h>
#include <hip/hip_bf16.h>
#include <cstdint>

typedef __hip_bfloat16 bf16;
typedef __attribute__((ext_vector_type(8))) short short8;
typedef __attribute__((ext_vector_type(4))) short short4v;
typedef __attribute__((ext_vector_type(4))) float f32x4;

#define T_   2048
#define CDIM 2048
#define NH   16
#define NKV  4
#define HD   128
// 1/sqrt(128) * log2(e), folded into q at the epilogue so attn scores are exp2-ready
#define QSCALE (0.08838834764831845f * 1.44269504088896340f)

__device__ __forceinline__ void gload_lds16(const void* g, void* l) {
  __builtin_amdgcn_global_load_lds(
      (const __attribute__((address_space(1))) void*)g,
      (__attribute__((address_space(3))) void*)l, 16, 0, 0);
}

// ---------------- cast x (fp32 -> bf16), vectorized ----------------
__global__ __launch_bounds__(256) void cast_x_kernel(const float4* __restrict__ in,
                                                     ushort4* __restrict__ out, int n4) {
  int i = blockIdx.x * 256 + threadIdx.x;
  if (i >= n4) return;
  float4 v = in[i];
  union { bf16 h[4]; ushort4 u; } cv;
  cv.h[0] = __float2bfloat16(v.x);
  cv.h[1] = __float2bfloat16(v.y);
  cv.h[2] = __float2bfloat16(v.z);
  cv.h[3] = __float2bfloat16(v.w);
  out[i] = cv.u;
}

// ---------------- cast + transpose W[K][N] fp32 -> WT[N][K] bf16 ----------------
__global__ __launch_bounds__(256) void cast_transpose(const float* __restrict__ W,
                                                      bf16* __restrict__ WT,
                                                      int K, int N) {
  __shared__ float tile[32][33];
  int k0 = blockIdx.y * 32, n0 = blockIdx.x * 32;
  int r = threadIdx.x >> 5, c = threadIdx.x & 31;  // r:0..7
  for (int i = 0; i < 4; ++i)
    tile[r + i * 8][c] = W[(size_t)(k0 + r + i * 8) * N + n0 + c];
  __syncthreads();
  for (int i = 0; i < 4; ++i)
    WT[(size_t)(n0 + r + i * 8) * K + k0 + c] = __float2bfloat16(tile[c][r + i * 8]);
}

// ---------------- QKV GEMM: per-phase interleaved 256x256x64 pipeline ----------------
__global__ __launch_bounds__(512, 2) void gemm_qkv8(const bf16* __restrict__ A,
                                                    const bf16* __restrict__ BT,
                                                    bf16* __restrict__ C,
                                                    int N, int K, int RY, int RX) {
  __shared__ __align__(16) bf16 sA[2][256 * 64];
  __shared__ __align__(16) bf16 sB[2][256 * 64];

  int tid = threadIdx.x;
  int lane = tid & 63, w = tid >> 6;
  int wm = w >> 2, wn = w & 3;
  int lr = lane & 15, lk = lane >> 4;

  int xcd = blockIdx.x & 7, t = blockIdx.x >> 3;
  int by = (xcd >> 1) * RY + t / RX;
  int bx = (xcd & 1) * RX + t % RX;
  int m0 = by * 256, n0 = bx * 256;

  f32x4 acc[8][4];
#pragma unroll
  for (int m = 0; m < 8; ++m)
#pragma unroll
    for (int n = 0; n < 4; ++n) acc[m][n] = (f32x4){0.f, 0.f, 0.f, 0.f};

  const bf16* Abase = A + (size_t)m0 * K;
  const bf16* Bbase = BT + (size_t)n0 * K;

  auto stageB = [&](int p, int kt) {
    int kb = kt << 6;
#pragma unroll
    for (int i = 0; i < 4; ++i) {
      int c = i * 512 + tid;
      int r = c >> 3, sl = c & 7;
      gload_lds16(Bbase + (size_t)r * K + kb + ((sl ^ (r & 7)) << 3),
                  (char*)(&sB[p][0]) + c * 16);
    }
  };
  auto stageAq = [&](int p, int kt, int q) {
    int kb = kt << 6;
    int rbase = 32 * q + ((w & 3) << 3) + ((w >> 2) << 7);
    int r = rbase + (lane >> 3), sl = lane & 7;
    gload_lds16(Abase + (size_t)r * K + kb + ((sl ^ (r & 7)) << 3),
                (char*)(&sA[p][0]) + rbase * 128 + lane * 16);
  };

  int nk = K >> 6;
  stageB(0, 0);
  stageAq(0, 0, 0); stageAq(0, 0, 1); stageAq(0, 0, 2); stageAq(0, 0, 3);
  stageB(1, 1);
  stageAq(1, 1, 0); stageAq(1, 1, 1); stageAq(1, 1, 2);
  asm volatile("s_waitcnt vmcnt(7)" ::: "memory");
  __builtin_amdgcn_s_barrier();

#define READ_A(Q)                                                          \
  {                                                                        \
    _Pragma("unroll")                                                      \
    for (int mi = 0; mi < 2; ++mi) {                                       \
      int row = wm * 128 + (2 * (Q) + mi) * 16 + lr;                       \
      const char* rb = sAb + row * 128;                                    \
      int rx = (row & 7) << 4;                                             \
      af[mi][0] = *(const short8*)(rb + ((lk * 16) ^ rx));                 \
      af[mi][1] = *(const short8*)(rb + ((64 + lk * 16) ^ rx));            \
    }                                                                      \
  }
#define MFMA_Q(Q)                                                          \
  __builtin_amdgcn_s_setprio(1);                                          \
  _Pragma("unroll")                                                        \
  for (int kk = 0; kk < 2; ++kk)                                           \
    _Pragma("unroll")                                                      \
    for (int mi = 0; mi < 2; ++mi)                                         \
      _Pragma("unroll")                                                    \
      for (int n = 0; n < 4; ++n)                                          \
        acc[2 * (Q) + mi][n] = __builtin_amdgcn_mfma_f32_16x16x32_bf16(    \
            af[mi][kk], bfr[n][kk], acc[2 * (Q) + mi][n], 0, 0, 0);        \
  __builtin_amdgcn_s_setprio(0);
#define LGKM_FENCE                                                         \
  asm volatile("s_waitcnt lgkmcnt(0)" ::: "memory");                       \
  __builtin_amdgcn_sched_barrier(0);

  for (int kt = 0; kt < nk; ++kt) {
    int p = kt & 1;
    const char* sAb = (const char*)(&sA[p][0]);
    const char* sBb = (const char*)(&sB[p][0]);
    short8 bfr[4][2], af[2][2];

#pragma unroll
    for (int n = 0; n < 4; ++n) {
      int row = wn * 64 + n * 16 + lr;
      const char* rb = sBb + row * 128;
      int rx = (row & 7) << 4;
      bfr[n][0] = *(const short8*)(rb + ((lk * 16) ^ rx));
      bfr[n][1] = *(const short8*)(rb + ((64 + lk * 16) ^ rx));
    }
    READ_A(0);
    if (kt + 1 < nk) stageAq(p ^ 1, kt + 1, 3);
    LGKM_FENCE;
    MFMA_Q(0);
    __builtin_amdgcn_s_barrier();

    READ_A(1);
    if (kt + 2 < nk) { stageB(p, kt + 2); stageAq(p, kt + 2, 0); }
    LGKM_FENCE;
    MFMA_Q(1);
    __builtin_amdgcn_s_barrier();

    READ_A(2);
    if (kt + 2 < nk) stageAq(p, kt + 2, 1);
    LGKM_FENCE;
    MFMA_Q(2);
    __builtin_amdgcn_s_barrier();

    READ_A(3);
    if (kt + 2 < nk) stageAq(p, kt + 2, 2);
    LGKM_FENCE;
    MFMA_Q(3);
    if (kt + 2 < nk)
      asm volatile("s_waitcnt vmcnt(7)" ::: "memory");
    else
      asm volatile("s_waitcnt vmcnt(0)" ::: "memory");
    __builtin_amdgcn_s_barrier();
  }
#undef READ_A
#undef MFMA_Q
#undef LGKM_FENCE

#pragma unroll
  for (int m = 0; m < 8; ++m)
#pragma unroll
    for (int n = 0; n < 4; ++n)
#pragma unroll
      for (int jj = 0; jj < 4; ++jj)
        C[(size_t)(m0 + wm * 128 + m * 16 + lk * 4 + jj) * N +
          n0 + wn * 64 + n * 16 + lr] = __float2bfloat16(acc[m][n][jj]);
}

// ---------------- GEMM 8-phase (round-5 structure), used for Wo ----------------
template <int MREP, typename CT>
__global__ __launch_bounds__(512, 2) void gemm_8p(const bf16* __restrict__ A,
                                                  const bf16* __restrict__ BT,
                                                  CT* __restrict__ C,
                                                  int N, int K, int RY, int RX) {
  constexpr int BM = MREP * 32;
  constexpr int ALOADS = BM / 64;
  __shared__ __align__(16) bf16 sA[2][BM * 64];
  __shared__ __align__(16) bf16 sB[2][256 * 64];

  int tid = threadIdx.x;
  int lane = tid & 63, w = tid >> 6;
  int wm = w >> 2, wn = w & 3;
  int lr = lane & 15, lk = lane >> 4;

  int xcd = blockIdx.x & 7, t = blockIdx.x >> 3;
  int by = (xcd >> 1) * RY + t / RX;
  int bx = (xcd & 1) * RX + t % RX;
  int m0 = by * BM, n0 = bx * 256;

  f32x4 acc[MREP][4];
#pragma unroll
  for (int m = 0; m < MREP; ++m)
#pragma unroll
    for (int n = 0; n < 4; ++n) acc[m][n] = (f32x4){0.f, 0.f, 0.f, 0.f};

  const bf16* Abase = A + (size_t)m0 * K;
  const bf16* Bbase = BT + (size_t)n0 * K;

  auto stage = [&](int b, int kt) {
    int kb = kt << 6;
#pragma unroll
    for (int i = 0; i < ALOADS; ++i) {
      int c = i * 512 + tid;
      int r = c >> 3, sl = c & 7;
      gload_lds16(Abase + (size_t)r * K + kb + ((sl ^ (r & 7)) << 3),
                  (char*)(&sA[b][0]) + c * 16);
    }
#pragma unroll
    for (int i = 0; i < 4; ++i) {
      int c = i * 512 + tid;
      int r = c >> 3, sl = c & 7;
      gload_lds16(Bbase + (size_t)r * K + kb + ((sl ^ (r & 7)) << 3),
                  (char*)(&sB[b][0]) + c * 16);
    }
  };

  int nk = K >> 6;
  stage(0, 0);
  stage(1, 1);
  asm volatile("s_waitcnt vmcnt(6)" ::: "memory");
  __builtin_amdgcn_s_barrier();

  for (int kt = 0; kt < nk; ++kt) {
    int d = kt & 1;
    const char* sAb = (const char*)(&sA[d][0]);
    const char* sBb = (const char*)(&sB[d][0]);

    short8 bfr[4][2];
#pragma unroll
    for (int n = 0; n < 4; ++n) {
      int row = wn * 64 + n * 16 + lr;
      const char* rb = sBb + row * 128;
      int rx = (row & 7) << 4;
      bfr[n][0] = *(const short8*)(rb + ((lk * 16) ^ rx));
      bfr[n][1] = *(const short8*)(rb + ((64 + lk * 16) ^ rx));
    }

#pragma unroll
    for (int p = 0; p < MREP / 2; ++p) {
      short8 af[2][2];
#pragma unroll
      for (int mi = 0; mi < 2; ++mi) {
        int row = wm * (MREP * 16) + (p * 2 + mi) * 16 + lr;
        const char* rb = sAb + row * 128;
        int rx = (row & 7) << 4;
        af[mi][0] = *(const short8*)(rb + ((lk * 16) ^ rx));
        af[mi][1] = *(const short8*)(rb + ((64 + lk * 16) ^ rx));
      }
      __builtin_amdgcn_s_setprio(1);
#pragma unroll
      for (int kk = 0; kk < 2; ++kk)
#pragma unroll
        for (int mi = 0; mi < 2; ++mi)
#pragma unroll
          for (int n = 0; n < 4; ++n)
            acc[p * 2 + mi][n] = __builtin_amdgcn_mfma_f32_16x16x32_bf16(
                af[mi][kk], bfr[n][kk], acc[p * 2 + mi][n], 0, 0, 0);
      __builtin_amdgcn_s_setprio(0);
    }

    asm volatile("s_waitcnt lgkmcnt(0)\n\ts_barrier" ::: "memory");
    if (kt + 2 < nk) {
      stage(d, kt + 2);
      asm volatile("s_waitcnt vmcnt(6)\n\ts_barrier" ::: "memory");
    } else {
      asm volatile("s_waitcnt vmcnt(0)\n\ts_barrier" ::: "memory");
    }
  }

#pragma unroll
  for (int m = 0; m < MREP; ++m)
#pragma unroll
    for (int n = 0; n < 4; ++n)
#pragma unroll
      for (int jj = 0; jj < 4; ++jj) {
        size_t idx = (size_t)(m0 + wm * (MREP * 16) + m * 16 + lk * 4 + jj) * N +
                     n0 + wn * 64 + n * 16 + lr;
        if constexpr (__is_same(CT, float))
          C[idx] = acc[m][n][jj];
        else
          C[idx] = __float2bfloat16(acc[m][n][jj]);
      }
}

// ---------------- epilogue: gate, v-update(+transpose), RoPE + RMSNorm ----------------
__global__ __launch_bounds__(256) void epilogue_kernel(
    const bf16* __restrict__ qkv, const float* __restrict__ x,
    const float* __restrict__ ve, const float* __restrict__ cosT,
    const float* __restrict__ sinT, const float* __restrict__ Wg,
    bf16* __restrict__ qn, bf16* __restrict__ kn, bf16* __restrict__ vT) {
  int row = blockIdx.x;
  int bi = row >> 11, t = row & 2047;
  int tid = threadIdx.x, lane = tid & 63, w = tid >> 6;
  __shared__ float gate[NKV];
  size_t rb = (size_t)row * 3072;

  if (tid < 128) {
    int g = tid >> 5, i = tid & 31;
    float p = x[(size_t)row * CDIM + i] * Wg[i * 4 + g];
    p += __shfl_xor(p, 1);  p += __shfl_xor(p, 2);
    p += __shfl_xor(p, 4);  p += __shfl_xor(p, 8);
    p += __shfl_xor(p, 16);
    if (i == 0) gate[g] = 2.f / (1.f + __expf(-p));
  }
  __syncthreads();

  float cv = cosT[t * 64 + lane];
  float sv = sinT[t * 64 + lane];

  for (int it = 0; it < 4; ++it) {
    int h = it * 4 + w;
    float x1 = __bfloat162float(qkv[rb + h * 128 + lane]);
    float x2 = __bfloat162float(qkv[rb + h * 128 + 64 + lane]);
    float y1 = x1 * cv + x2 * sv;
    float y2 = x2 * cv - x1 * sv;
    float ss = y1 * y1 + y2 * y2;
    ss += __shfl_xor(ss, 1);  ss += __shfl_xor(ss, 2);  ss += __shfl_xor(ss, 4);
    ss += __shfl_xor(ss, 8);  ss += __shfl_xor(ss, 16); ss += __shfl_xor(ss, 32);
    float r = rsqrtf(ss * (1.f / 128.f) + 1e-6f) * QSCALE;
    size_t ob = (size_t)row * (NH * HD) + h * 128;
    qn[ob + lane] = __float2bfloat16(y1 * r);
    qn[ob + 64 + lane] = __float2bfloat16(y2 * r);
  }
  {
    int h = w;
    float x1 = __bfloat162float(qkv[rb + 2048 + h * 128 + lane]);
    float x2 = __bfloat162float(qkv[rb + 2048 + h * 128 + 64 + lane]);
    float y1 = x1 * cv + x2 * sv;
    float y2 = x2 * cv - x1 * sv;
    float ss = y1 * y1 + y2 * y2;
    ss += __shfl_xor(ss, 1);  ss += __shfl_xor(ss, 2);  ss += __shfl_xor(ss, 4);
    ss += __shfl_xor(ss, 8);  ss += __shfl_xor(ss, 16); ss += __shfl_xor(ss, 32);
    float r = rsqrtf(ss * (1.f / 128.f) + 1e-6f);
    size_t ob = (size_t)row * (NKV * HD) + h * 128;
    kn[ob + lane] = __float2bfloat16(y1 * r);
    kn[ob + 64 + lane] = __float2bfloat16(y2 * r);
  }
  for (int e = tid; e < 512; e += 256) {
    int kv = e >> 7, d = e & 127;
    float val = __bfloat162float(qkv[rb + 2560 + e]) + gate[kv] * ve[(size_t)row * 512 + e];
    vT[((size_t)(bi * NKV + kv) * HD + d) * T_ + t] = __float2bfloat16(val);
  }
}

// ---------------- flash attention v5: swapped QK^T, in-register P, T14 staging ------
// Swapped mfma(K,Q): lane holds P[q=lr][16 lane-local keys]. V columns are PERMUTED in
// LDS (position lk*8+e <- key 16*(e>>2)+4lk+(e&3)) so each lane's own packed P values
// feed PV's A-fragment directly: zero shuffles, no sP buffer. K/V staged via registers
// (global->reg during compute, reg->LDS swizzled write after the read barrier). No-max
// softmax (RMSNorm bounds |score| <= 16.33 in exp2 domain -> fp32-safe).
__global__ __launch_bounds__(256, 3) void attn_kernel(
    const bf16* __restrict__ qn, const bf16* __restrict__ kn,
    const bf16* __restrict__ vT, bf16* __restrict__ y,
    const int* __restrict__ winp) {
  __shared__ __align__(16) bf16 sK[64 * 128];   // [key][d], 16-slot XOR swizzle
  __shared__ __align__(16) bf16 sV[128 * 64];   // [d][key-permuted], XOR swizzle

  int win = *winp;
  int id = blockIdx.x;
  int g  = id & 7;
  int bi = g >> 2, kvh = g & 3;
  int rem = id >> 3;
  int h  = kvh * 4 + (rem & 3);
  int jslot = (rem >> 2) & 7;
  int s5 = rem >> 5;
  int q0i = (s5 == 0) ? (2 * jslot) : (s5 == 1) ? (2 * jslot + 1)
          : (s5 == 2) ? (16 + jslot) : (31 - jslot);
  int q0 = q0i << 6;
  int tid = threadIdx.x;
  int lane = tid & 63, w = tid >> 6;
  int lr = lane & 15, lk = lane >> 4;

  short8 qf[4];
  {
    const bf16* qrow = qn + (size_t)(bi * T_ + q0 + w * 16 + lr) * (NH * HD) + h * HD;
#pragma unroll
    for (int c = 0; c < 4; ++c) qf[c] = *(const short8*)(qrow + c * 32 + lk * 8);
  }

  // staging addresses (lane-static, computed once)
  int kge[4], klb[4], vge[4], vlbA[4], vlbB[4];
#pragma unroll
  for (int i = 0; i < 4; ++i) {
    int c = i * 256 + tid;
    int kr = c >> 4, ks = c & 15;
    kge[i] = kr * (NKV * HD) + ks * 8;
    klb[i] = kr * 256 + ((ks ^ (kr & 7)) << 4);
    int vr = c >> 3, vs = c & 7;
    vge[i] = vr * T_ + vs * 8;
    int hh = vs >> 2, m = vs & 3, a = m >> 1;
    int sA = 8 * ((2 * m) & 3) + 4 * a;        // keys 8m..8m+3 -> slot base
    int sB = 8 * ((2 * m + 1) & 3) + 4 * a;    // keys 8m+4..8m+7
    int tA = 64 * hh + 2 * sA, tB = 64 * hh + 2 * sB;
    vlbA[i] = vr * 128 + (((tA >> 4) ^ (vr & 7)) << 4) + (tA & 15);
    vlbB[i] = vr * 128 + (((tB >> 4) ^ (vr & 7)) << 4) + (tB & 15);
  }
  const bf16* kpane = kn + (size_t)bi * T_ * (NKV * HD) + kvh * HD;
  const bf16* vpane = vT + (size_t)(bi * NKV + kvh) * HD * T_;

  short8 kreg[4], vreg[4];
  auto LOAD = [&](int jtx) {
    const bf16* kb = kpane + (size_t)(jtx << 6) * (NKV * HD);
    const bf16* vb = vpane + (jtx << 6);
#pragma unroll
    for (int i = 0; i < 4; ++i) kreg[i] = *(const short8*)(kb + kge[i]);
#pragma unroll
    for (int i = 0; i < 4; ++i) vreg[i] = *(const short8*)(vb + vge[i]);
  };
  auto WRITE = [&]() {
#pragma unroll
    for (int i = 0; i < 4; ++i) *(short8*)((char*)sK + klb[i]) = kreg[i];
#pragma unroll
    for (int i = 0; i < 4; ++i) {
      union { short8 s8; short4v s4[2]; } u;
      u.s8 = vreg[i];
      *(short4v*)((char*)sV + vlbA[i]) = u.s4[0];
      *(short4v*)((char*)sV + vlbB[i]) = u.s4[1];
    }
  };

  f32x4 o[8];
#pragma unroll
  for (int i = 0; i < 8; ++i) o[i] = (f32x4){0.f, 0.f, 0.f, 0.f};
  float lpart = 0.f;

  int jt0 = q0 >> 6;
  int hi = q0 + 62 + win; if (hi > T_ - 1) hi = T_ - 1;
  int jt1 = hi >> 6;

  LOAD(jt0);
  WRITE();
  if (jt0 < jt1) LOAD(jt0 + 1);
  asm volatile("s_waitcnt lgkmcnt(0)\n\ts_barrier" ::: "memory");

  int irow = q0 + w * 16 + lr;   // this lane's q row
  int klo = lk * 4;

  for (int jt = jt0; jt <= jt1; ++jt) {
    int j0 = jt << 6;

    // QK^T swapped: s[sub][jj] = S[key=j0+sub*16+klo+jj][q=irow]
    f32x4 s[4];
#pragma unroll
    for (int sub = 0; sub < 4; ++sub) s[sub] = (f32x4){0.f, 0.f, 0.f, 0.f};
    __builtin_amdgcn_s_setprio(1);
#pragma unroll
    for (int sub = 0; sub < 4; ++sub) {
      int kr = sub * 16 + lr;
      int rx = (kr & 7) << 4;
      const char* rowb = (const char*)sK + kr * 256;
#pragma unroll
      for (int c = 0; c < 4; ++c) {
        short8 kf = *(const short8*)(rowb + ((c * 64 + lk * 16) ^ rx));
        s[sub] = __builtin_amdgcn_mfma_f32_16x16x32_bf16(kf, qf[c], s[sub], 0, 0, 0);
      }
    }
    __builtin_amdgcn_s_setprio(0);

    bool full = (j0 >= q0 + 64) && (j0 + 64 <= q0 + win);
    int koff = j0 - irow;

    unsigned pk[8];
#pragma unroll
    for (int sub = 0; sub < 4; ++sub) {
      float p0 = exp2f(s[sub][0]), p1 = exp2f(s[sub][1]);
      float p2 = exp2f(s[sub][2]), p3 = exp2f(s[sub][3]);
      if (!full) {
        int base = koff + sub * 16 + klo;
        p0 = ((unsigned)(base + 0) < (unsigned)win) ? p0 : 0.f;
        p1 = ((unsigned)(base + 1) < (unsigned)win) ? p1 : 0.f;
        p2 = ((unsigned)(base + 2) < (unsigned)win) ? p2 : 0.f;
        p3 = ((unsigned)(base + 3) < (unsigned)win) ? p3 : 0.f;
      }
      lpart += (p0 + p1) + (p2 + p3);
      asm("v_cvt_pk_bf16_f32 %0, %1, %2" : "=v"(pk[sub * 2])     : "v"(p0), "v"(p1));
      asm("v_cvt_pk_bf16_f32 %0, %1, %2" : "=v"(pk[sub * 2 + 1]) : "v"(p2), "v"(p3));
    }
    union { unsigned u[4]; short8 s8; } c0, c1;
    c0.u[0] = pk[0]; c0.u[1] = pk[1]; c0.u[2] = pk[2]; c0.u[3] = pk[3];
    c1.u[0] = pk[4]; c1.u[1] = pk[5]; c1.u[2] = pk[6]; c1.u[3] = pk[7];
    short8 pf0 = c0.s8, pf1 = c1.s8;

    // PV: lane-local P fragments x permuted V columns
    __builtin_amdgcn_s_setprio(1);
#pragma unroll
    for (int nb = 0; nb < 8; ++nb) {
      int vr = nb * 16 + lr;
      int vrx = (vr & 7) << 4;
      const char* vb = (const char*)sV + vr * 128;
      short8 vf0 = *(const short8*)(vb + ((lk * 16) ^ vrx));
      short8 vf1 = *(const short8*)(vb + ((64 + lk * 16) ^ vrx));
      o[nb] = __builtin_amdgcn_mfma_f32_16x16x32_bf16(pf0, vf0, o[nb], 0, 0, 0);
      o[nb] = __builtin_amdgcn_mfma_f32_16x16x32_bf16(pf1, vf1, o[nb], 0, 0, 0);
    }
    __builtin_amdgcn_s_setprio(0);

    asm volatile("s_waitcnt lgkmcnt(0)\n\ts_barrier" ::: "memory");  // reads done
    if (jt < jt1) {
      WRITE();                      // compiler waits vmcnt for kreg/vreg
      if (jt + 1 < jt1) LOAD(jt + 2);
      asm volatile("s_waitcnt lgkmcnt(0)\n\ts_barrier" ::: "memory");  // writes visible
    }
  }

  float l = lpart;
  l += __shfl_xor(l, 16);
  l += __shfl_xor(l, 32);          // lane now holds full l[q=lr]
#pragma unroll
  for (int jj = 0; jj < 4; ++jj) {
    float inv = 1.f / __shfl(l, klo + jj);
    size_t ob = (size_t)(bi * T_ + q0 + w * 16 + klo + jj) * (NH * HD) + h * HD;
#pragma unroll
    for (int nb = 0; nb < 8; ++nb)
      y[ob + nb * 16 + lr] = __float2bfloat16(o[nb][jj] * inv);
  }
}

extern "C" void kernel_launch(void* const* d_in, const int* in_sizes, int n_in,
                              void* d_out, int out_size, void* d_ws, size_t ws_size,
                              hipStream_t stream) {
  const float* x    = (const float*)d_in[0];
  const float* ve   = (const float*)d_in[1];
  const float* cosT = (const float*)d_in[2];
  const float* sinT = (const float*)d_in[3];
  const float* Wq   = (const float*)d_in[4];
  const float* Wk   = (const float*)d_in[5];
  const float* Wv   = (const float*)d_in[6];
  const float* Wg   = (const float*)d_in[7];
  const float* Wo   = (const float*)d_in[8];
  const int*   win  = (const int*)d_in[9];
  float* out = (float*)d_out;

  char* ws = (char*)d_ws;
  bf16*  xb   = (bf16*)(ws);
  bf16*  wT   = (bf16*)(ws + 16777216);
  bf16*  woT  = (bf16*)(ws + 29360128);
  bf16*  qkvb = (bf16*)(ws + 37748736);
  bf16*  qn   = (bf16*)(ws + 62914560);
  bf16*  kn   = (bf16*)(ws + 79691776);
  bf16*  vTb  = (bf16*)(ws + 83886080);
  bf16*  y    = qkvb;

  cast_x_kernel<<<8192, 256, 0, stream>>>((const float4*)x, (ushort4*)xb, 2097152);
  cast_transpose<<<dim3(64, 64), 256, 0, stream>>>(Wq, wT, 2048, 2048);
  cast_transpose<<<dim3(16, 64), 256, 0, stream>>>(Wk, wT + (size_t)2048 * 2048, 2048, 512);
  cast_transpose<<<dim3(16, 64), 256, 0, stream>>>(Wv, wT + (size_t)2560 * 2048, 2048, 512);
  cast_transpose<<<dim3(64, 64), 256, 0, stream>>>(Wo, woT, 2048, 2048);

  gemm_qkv8<<<192, 512, 0, stream>>>(xb, wT, qkvb, 3072, 2048, 4, 6);
  epilogue_kernel<<<4096, 256, 0, stream>>>(qkvb, x, ve, cosT, sinT, Wg, qn, kn, vTb);
  attn_kernel<<<1024, 256, 0, stream>>>(qn, kn, vTb, y, win);
  gemm_8p<4, float><<<256, 512, 0, stream>>>(y, woT, out, 2048, 2048, 8, 4);
}

// Round 8
// 198.066 us; speedup vs baseline: 1.7114x; 1.0145x over previous
//
#include <hip/hip_runtime.h>
#include <hip/hip_bf16.h>
#include <cstdint>

typedef __hip_bfloat16 bf16;
typedef __attribute__((ext_vector_type(8))) short short8;
typedef __attribute__((ext_vector_type(4))) short short4v;
typedef __attribute__((ext_vector_type(4))) float f32x4;

#define T_   2048
#define CDIM 2048
#define NH   16
#define NKV  4
#define HD   128
// 1/sqrt(128) * log2(e), folded into q at the epilogue so attn scores are exp2-ready
#define QSCALE (0.08838834764831845f * 1.44269504088896340f)

__device__ __forceinline__ void gload_lds16(const void* g, void* l) {
  __builtin_amdgcn_global_load_lds(
      (const __attribute__((address_space(1))) void*)g,
      (__attribute__((address_space(3))) void*)l, 16, 0, 0);
}

template <int G> __device__ __forceinline__ void vm_gate() {
  if constexpr (G == 6)      asm volatile("s_waitcnt vmcnt(6)" ::: "memory");
  else if constexpr (G == 5) asm volatile("s_waitcnt vmcnt(5)" ::: "memory");
  else                       asm volatile("s_waitcnt vmcnt(0)" ::: "memory");
}

// ---------------- cast x (fp32 -> bf16), vectorized ----------------
__global__ __launch_bounds__(256) void cast_x_kernel(const float4* __restrict__ in,
                                                     ushort4* __restrict__ out, int n4) {
  int i = blockIdx.x * 256 + threadIdx.x;
  if (i >= n4) return;
  float4 v = in[i];
  union { bf16 h[4]; ushort4 u; } cv;
  cv.h[0] = __float2bfloat16(v.x);
  cv.h[1] = __float2bfloat16(v.y);
  cv.h[2] = __float2bfloat16(v.z);
  cv.h[3] = __float2bfloat16(v.w);
  out[i] = cv.u;
}

// ---------------- cast + transpose W[K][N] fp32 -> WT[N][K] bf16 ----------------
__global__ __launch_bounds__(256) void cast_transpose(const float* __restrict__ W,
                                                      bf16* __restrict__ WT,
                                                      int K, int N) {
  __shared__ float tile[32][33];
  int k0 = blockIdx.y * 32, n0 = blockIdx.x * 32;
  int r = threadIdx.x >> 5, c = threadIdx.x & 31;  // r:0..7
  for (int i = 0; i < 4; ++i)
    tile[r + i * 8][c] = W[(size_t)(k0 + r + i * 8) * N + n0 + c];
  __syncthreads();
  for (int i = 0; i < 4; ++i)
    WT[(size_t)(n0 + r + i * 8) * K + k0 + c] = __float2bfloat16(tile[c][r + i * 8]);
}

// ---------------- unified per-phase GEMM: A[M][K] x BT[N][K] -> C[M][N] ----------------
// 8 waves (2M x 4N). BM=MREP*32, BN=NREP*64, BK=64; wave tile (MREP*16)x(NREP*16).
// 4 phases per K-tile: {ds_read A-frags [+B at ph0] | stage one region -> lgkmcnt(0)+
// sched_barrier -> setprio(1) MFMA setprio(0) -> s_barrier}. A staged in QN quanta
// (QN=4 for BM=256, 2 for BM=128), each staged exactly one phase after its last read.
// End-of-iter gate vmcnt(NREP+QN-1): tile kt+1 PROVABLY landed (incl. its last A-quad,
// issued this iter at ph0) before iter kt+1 reads it. LDS rows 128B, 8x16B slots XOR
// row&7, source pre-swizzled (global_load_lds dest linear). XCD regions: 4x2 layout.
template <int MREP, int NREP, typename CT>
__global__ __launch_bounds__(512, 2) void gemm_pp(const bf16* __restrict__ A,
                                                  const bf16* __restrict__ BT,
                                                  CT* __restrict__ C,
                                                  int N, int K, int RY, int RX) {
  constexpr int BM = MREP * 32;
  constexpr int BN = NREP * 64;
  constexpr int QN = (MREP == 8) ? 4 : 2;   // A stage quanta per tile
  constexpr int MI = MREP / 4;              // A frags per phase
  constexpr int GATE = NREP + QN - 1;       // steady-state vmcnt
  __shared__ __align__(16) bf16 sA[2][BM * 64];
  __shared__ __align__(16) bf16 sB[2][BN * 64];

  int tid = threadIdx.x;
  int lane = tid & 63, w = tid >> 6;
  int wm = w >> 2, wn = w & 3;
  int lr = lane & 15, lk = lane >> 4;

  int xcd = blockIdx.x & 7, t = blockIdx.x >> 3;
  int by = (xcd >> 1) * RY + t / RX;
  int bx = (xcd & 1) * RX + t % RX;
  int m0 = by * BM, n0 = bx * BN;

  f32x4 acc[MREP][NREP];
#pragma unroll
  for (int m = 0; m < MREP; ++m)
#pragma unroll
    for (int n = 0; n < NREP; ++n) acc[m][n] = (f32x4){0.f, 0.f, 0.f, 0.f};

  const bf16* Abase = A + (size_t)m0 * K;
  const bf16* Bbase = BT + (size_t)n0 * K;

  auto stageB = [&](int p, int kt) {
    int kb = kt << 6;
#pragma unroll
    for (int i = 0; i < NREP; ++i) {
      int c = i * 512 + tid;
      int r = c >> 3, sl = c & 7;
      gload_lds16(Bbase + (size_t)r * K + kb + ((sl ^ (r & 7)) << 3),
                  (char*)(&sB[p][0]) + c * 16);
    }
  };
  // A quantum q: rows {32q..32q+31} u {BM/2+32q..}, 1 load/thread (64 rows)
  auto stageAq = [&](int p, int kt, int q) {
    int kb = kt << 6;
    int rbase = 32 * q + ((w & 3) << 3) + ((w >> 2) * (BM / 2));
    int r = rbase + (lane >> 3), sl = lane & 7;
    gload_lds16(Abase + (size_t)r * K + kb + ((sl ^ (r & 7)) << 3),
                (char*)(&sA[p][0]) + rbase * 128 + lane * 16);
  };

  int nk = K >> 6;
  // prologue: tile0 full, tile1 all but last A-quantum (= GATE loads outstanding)
  stageB(0, 0);
#pragma unroll
  for (int q = 0; q < QN; ++q) stageAq(0, 0, q);
  stageB(1, 1);
#pragma unroll
  for (int q = 0; q < QN - 1; ++q) stageAq(1, 1, q);
  vm_gate<GATE>();
  __builtin_amdgcn_s_barrier();

#define READ_A_FRAGS(PH)                                                   \
  {                                                                        \
    _Pragma("unroll")                                                      \
    for (int mi = 0; mi < MI; ++mi) {                                      \
      int row = wm * (MREP * 16) + ((PH) * MI + mi) * 16 + lr;             \
      const char* rb = sAb + row * 128;                                    \
      int rx = (row & 7) << 4;                                             \
      af[mi][0] = *(const short8*)(rb + ((lk * 16) ^ rx));                 \
      af[mi][1] = *(const short8*)(rb + ((64 + lk * 16) ^ rx));            \
    }                                                                      \
  }
#define MFMA_PH(PH)                                                        \
  __builtin_amdgcn_s_setprio(1);                                           \
  _Pragma("unroll")                                                        \
  for (int kk = 0; kk < 2; ++kk)                                           \
    _Pragma("unroll")                                                      \
    for (int mi = 0; mi < MI; ++mi)                                        \
      _Pragma("unroll")                                                    \
      for (int n = 0; n < NREP; ++n)                                       \
        acc[(PH) * MI + mi][n] = __builtin_amdgcn_mfma_f32_16x16x32_bf16(  \
            af[mi][kk], bfr[n][kk], acc[(PH) * MI + mi][n], 0, 0, 0);      \
  __builtin_amdgcn_s_setprio(0);
#define LGKM_FENCE                                                         \
  asm volatile("s_waitcnt lgkmcnt(0)" ::: "memory");                       \
  __builtin_amdgcn_sched_barrier(0);

  for (int kt = 0; kt < nk; ++kt) {
    int p = kt & 1;
    const char* sAb = (const char*)(&sA[p][0]);
    const char* sBb = (const char*)(&sB[p][0]);
    short8 bfr[NREP][2], af[MI][2];

    // ---- phase 0: B + A-frags(0); stage last A-quantum of tile kt+1 ----
#pragma unroll
    for (int n = 0; n < NREP; ++n) {
      int row = wn * (NREP * 16) + n * 16 + lr;
      const char* rb = sBb + row * 128;
      int rx = (row & 7) << 4;
      bfr[n][0] = *(const short8*)(rb + ((lk * 16) ^ rx));
      bfr[n][1] = *(const short8*)(rb + ((64 + lk * 16) ^ rx));
    }
    READ_A_FRAGS(0);
    if (kt + 1 < nk) stageAq(p ^ 1, kt + 1, QN - 1);
    LGKM_FENCE;
    MFMA_PH(0);
    __builtin_amdgcn_s_barrier();

    // ---- phase 1: A-frags(1); stage B(kt+2) [+Aq0 when QN==4] ----
    READ_A_FRAGS(1);
    if (kt + 2 < nk) {
      stageB(p, kt + 2);
      if constexpr (QN == 4) stageAq(p, kt + 2, 0);
    }
    LGKM_FENCE;
    MFMA_PH(1);
    __builtin_amdgcn_s_barrier();

    // ---- phase 2: A-frags(2); stage Aq1 (QN==4) / Aq0 (QN==2) of kt+2 ----
    READ_A_FRAGS(2);
    if (kt + 2 < nk) stageAq(p, kt + 2, (QN == 4) ? 1 : 0);
    LGKM_FENCE;
    MFMA_PH(2);
    __builtin_amdgcn_s_barrier();

    // ---- phase 3: A-frags(3); stage Aq2 (QN==4); counted gate ----
    READ_A_FRAGS(3);
    if constexpr (QN == 4) {
      if (kt + 2 < nk) stageAq(p, kt + 2, 2);
    }
    LGKM_FENCE;
    MFMA_PH(3);
    if (kt + 2 < nk) vm_gate<GATE>();
    else             vm_gate<0>();
    __builtin_amdgcn_s_barrier();
  }
#undef READ_A_FRAGS
#undef MFMA_PH
#undef LGKM_FENCE

#pragma unroll
  for (int m = 0; m < MREP; ++m)
#pragma unroll
    for (int n = 0; n < NREP; ++n)
#pragma unroll
      for (int jj = 0; jj < 4; ++jj) {
        size_t idx = (size_t)(m0 + wm * (MREP * 16) + m * 16 + lk * 4 + jj) * N +
                     n0 + wn * (NREP * 16) + n * 16 + lr;
        if constexpr (__is_same(CT, float))
          C[idx] = acc[m][n][jj];
        else
          C[idx] = __float2bfloat16(acc[m][n][jj]);
      }
}

// ---------------- epilogue: gate, v-update(+transpose), RoPE + RMSNorm ----------------
__global__ __launch_bounds__(256) void epilogue_kernel(
    const bf16* __restrict__ qkv, const float* __restrict__ x,
    const float* __restrict__ ve, const float* __restrict__ cosT,
    const float* __restrict__ sinT, const float* __restrict__ Wg,
    bf16* __restrict__ qn, bf16* __restrict__ kn, bf16* __restrict__ vT) {
  int row = blockIdx.x;
  int bi = row >> 11, t = row & 2047;
  int tid = threadIdx.x, lane = tid & 63, w = tid >> 6;
  __shared__ float gate[NKV];
  size_t rb = (size_t)row * 3072;

  if (tid < 128) {
    int g = tid >> 5, i = tid & 31;
    float p = x[(size_t)row * CDIM + i] * Wg[i * 4 + g];
    p += __shfl_xor(p, 1);  p += __shfl_xor(p, 2);
    p += __shfl_xor(p, 4);  p += __shfl_xor(p, 8);
    p += __shfl_xor(p, 16);
    if (i == 0) gate[g] = 2.f / (1.f + __expf(-p));
  }
  __syncthreads();

  float cv = cosT[t * 64 + lane];
  float sv = sinT[t * 64 + lane];

  for (int it = 0; it < 4; ++it) {
    int h = it * 4 + w;
    float x1 = __bfloat162float(qkv[rb + h * 128 + lane]);
    float x2 = __bfloat162float(qkv[rb + h * 128 + 64 + lane]);
    float y1 = x1 * cv + x2 * sv;
    float y2 = x2 * cv - x1 * sv;
    float ss = y1 * y1 + y2 * y2;
    ss += __shfl_xor(ss, 1);  ss += __shfl_xor(ss, 2);  ss += __shfl_xor(ss, 4);
    ss += __shfl_xor(ss, 8);  ss += __shfl_xor(ss, 16); ss += __shfl_xor(ss, 32);
    float r = rsqrtf(ss * (1.f / 128.f) + 1e-6f) * QSCALE;
    size_t ob = (size_t)row * (NH * HD) + h * 128;
    qn[ob + lane] = __float2bfloat16(y1 * r);
    qn[ob + 64 + lane] = __float2bfloat16(y2 * r);
  }
  {
    int h = w;
    float x1 = __bfloat162float(qkv[rb + 2048 + h * 128 + lane]);
    float x2 = __bfloat162float(qkv[rb + 2048 + h * 128 + 64 + lane]);
    float y1 = x1 * cv + x2 * sv;
    float y2 = x2 * cv - x1 * sv;
    float ss = y1 * y1 + y2 * y2;
    ss += __shfl_xor(ss, 1);  ss += __shfl_xor(ss, 2);  ss += __shfl_xor(ss, 4);
    ss += __shfl_xor(ss, 8);  ss += __shfl_xor(ss, 16); ss += __shfl_xor(ss, 32);
    float r = rsqrtf(ss * (1.f / 128.f) + 1e-6f);
    size_t ob = (size_t)row * (NKV * HD) + h * 128;
    kn[ob + lane] = __float2bfloat16(y1 * r);
    kn[ob + 64 + lane] = __float2bfloat16(y2 * r);
  }
  for (int e = tid; e < 512; e += 256) {
    int kv = e >> 7, d = e & 127;
    float val = __bfloat162float(qkv[rb + 2560 + e]) + gate[kv] * ve[(size_t)row * 512 + e];
    vT[((size_t)(bi * NKV + kv) * HD + d) * T_ + t] = __float2bfloat16(val);
  }
}

// ---------------- flash attention v5: swapped QK^T, in-register P, T14 staging ------
__global__ __launch_bounds__(256, 3) void attn_kernel(
    const bf16* __restrict__ qn, const bf16* __restrict__ kn,
    const bf16* __restrict__ vT, bf16* __restrict__ y,
    const int* __restrict__ winp) {
  __shared__ __align__(16) bf16 sK[64 * 128];   // [key][d], 16-slot XOR swizzle
  __shared__ __align__(16) bf16 sV[128 * 64];   // [d][key-permuted], XOR swizzle

  int win = *winp;
  int id = blockIdx.x;
  int g  = id & 7;
  int bi = g >> 2, kvh = g & 3;
  int rem = id >> 3;
  int h  = kvh * 4 + (rem & 3);
  int jslot = (rem >> 2) & 7;
  int s5 = rem >> 5;
  int q0i = (s5 == 0) ? (2 * jslot) : (s5 == 1) ? (2 * jslot + 1)
          : (s5 == 2) ? (16 + jslot) : (31 - jslot);
  int q0 = q0i << 6;
  int tid = threadIdx.x;
  int lane = tid & 63, w = tid >> 6;
  int lr = lane & 15, lk = lane >> 4;

  short8 qf[4];
  {
    const bf16* qrow = qn + (size_t)(bi * T_ + q0 + w * 16 + lr) * (NH * HD) + h * HD;
#pragma unroll
    for (int c = 0; c < 4; ++c) qf[c] = *(const short8*)(qrow + c * 32 + lk * 8);
  }

  int kge[4], klb[4], vge[4], vlbA[4], vlbB[4];
#pragma unroll
  for (int i = 0; i < 4; ++i) {
    int c = i * 256 + tid;
    int kr = c >> 4, ks = c & 15;
    kge[i] = kr * (NKV * HD) + ks * 8;
    klb[i] = kr * 256 + ((ks ^ (kr & 7)) << 4);
    int vr = c >> 3, vs = c & 7;
    vge[i] = vr * T_ + vs * 8;
    int hh = vs >> 2, m = vs & 3, a = m >> 1;
    int sA = 8 * ((2 * m) & 3) + 4 * a;
    int sB = 8 * ((2 * m + 1) & 3) + 4 * a;
    int tA = 64 * hh + 2 * sA, tB = 64 * hh + 2 * sB;
    vlbA[i] = vr * 128 + (((tA >> 4) ^ (vr & 7)) << 4) + (tA & 15);
    vlbB[i] = vr * 128 + (((tB >> 4) ^ (vr & 7)) << 4) + (tB & 15);
  }
  const bf16* kpane = kn + (size_t)bi * T_ * (NKV * HD) + kvh * HD;
  const bf16* vpane = vT + (size_t)(bi * NKV + kvh) * HD * T_;

  short8 kreg[4], vreg[4];
  auto LOAD = [&](int jtx) {
    const bf16* kb = kpane + (size_t)(jtx << 6) * (NKV * HD);
    const bf16* vb = vpane + (jtx << 6);
#pragma unroll
    for (int i = 0; i < 4; ++i) kreg[i] = *(const short8*)(kb + kge[i]);
#pragma unroll
    for (int i = 0; i < 4; ++i) vreg[i] = *(const short8*)(vb + vge[i]);
  };
  auto WRITE = [&]() {
#pragma unroll
    for (int i = 0; i < 4; ++i) *(short8*)((char*)sK + klb[i]) = kreg[i];
#pragma unroll
    for (int i = 0; i < 4; ++i) {
      union { short8 s8; short4v s4[2]; } u;
      u.s8 = vreg[i];
      *(short4v*)((char*)sV + vlbA[i]) = u.s4[0];
      *(short4v*)((char*)sV + vlbB[i]) = u.s4[1];
    }
  };

  f32x4 o[8];
#pragma unroll
  for (int i = 0; i < 8; ++i) o[i] = (f32x4){0.f, 0.f, 0.f, 0.f};
  float lpart = 0.f;

  int jt0 = q0 >> 6;
  int hi = q0 + 62 + win; if (hi > T_ - 1) hi = T_ - 1;
  int jt1 = hi >> 6;

  LOAD(jt0);
  WRITE();
  if (jt0 < jt1) LOAD(jt0 + 1);
  asm volatile("s_waitcnt lgkmcnt(0)\n\ts_barrier" ::: "memory");

  int irow = q0 + w * 16 + lr;
  int klo = lk * 4;

  for (int jt = jt0; jt <= jt1; ++jt) {
    int j0 = jt << 6;

    f32x4 s[4];
#pragma unroll
    for (int sub = 0; sub < 4; ++sub) s[sub] = (f32x4){0.f, 0.f, 0.f, 0.f};
    __builtin_amdgcn_s_setprio(1);
#pragma unroll
    for (int sub = 0; sub < 4; ++sub) {
      int kr = sub * 16 + lr;
      int rx = (kr & 7) << 4;
      const char* rowb = (const char*)sK + kr * 256;
#pragma unroll
      for (int c = 0; c < 4; ++c) {
        short8 kf = *(const short8*)(rowb + ((c * 64 + lk * 16) ^ rx));
        s[sub] = __builtin_amdgcn_mfma_f32_16x16x32_bf16(kf, qf[c], s[sub], 0, 0, 0);
      }
    }
    __builtin_amdgcn_s_setprio(0);

    bool full = (j0 >= q0 + 64) && (j0 + 64 <= q0 + win);
    int koff = j0 - irow;

    unsigned pk[8];
#pragma unroll
    for (int sub = 0; sub < 4; ++sub) {
      float p0 = exp2f(s[sub][0]), p1 = exp2f(s[sub][1]);
      float p2 = exp2f(s[sub][2]), p3 = exp2f(s[sub][3]);
      if (!full) {
        int base = koff + sub * 16 + klo;
        p0 = ((unsigned)(base + 0) < (unsigned)win) ? p0 : 0.f;
        p1 = ((unsigned)(base + 1) < (unsigned)win) ? p1 : 0.f;
        p2 = ((unsigned)(base + 2) < (unsigned)win) ? p2 : 0.f;
        p3 = ((unsigned)(base + 3) < (unsigned)win) ? p3 : 0.f;
      }
      lpart += (p0 + p1) + (p2 + p3);
      asm("v_cvt_pk_bf16_f32 %0, %1, %2" : "=v"(pk[sub * 2])     : "v"(p0), "v"(p1));
      asm("v_cvt_pk_bf16_f32 %0, %1, %2" : "=v"(pk[sub * 2 + 1]) : "v"(p2), "v"(p3));
    }
    union { unsigned u[4]; short8 s8; } c0, c1;
    c0.u[0] = pk[0]; c0.u[1] = pk[1]; c0.u[2] = pk[2]; c0.u[3] = pk[3];
    c1.u[0] = pk[4]; c1.u[1] = pk[5]; c1.u[2] = pk[6]; c1.u[3] = pk[7];
    short8 pf0 = c0.s8, pf1 = c1.s8;

    __builtin_amdgcn_s_setprio(1);
#pragma unroll
    for (int nb = 0; nb < 8; ++nb) {
      int vr = nb * 16 + lr;
      int vrx = (vr & 7) << 4;
      const char* vb = (const char*)sV + vr * 128;
      short8 vf0 = *(const short8*)(vb + ((lk * 16) ^ vrx));
      short8 vf1 = *(const short8*)(vb + ((64 + lk * 16) ^ vrx));
      o[nb] = __builtin_amdgcn_mfma_f32_16x16x32_bf16(pf0, vf0, o[nb], 0, 0, 0);
      o[nb] = __builtin_amdgcn_mfma_f32_16x16x32_bf16(pf1, vf1, o[nb], 0, 0, 0);
    }
    __builtin_amdgcn_s_setprio(0);

    asm volatile("s_waitcnt lgkmcnt(0)\n\ts_barrier" ::: "memory");
    if (jt < jt1) {
      WRITE();
      if (jt + 1 < jt1) LOAD(jt + 2);
      asm volatile("s_waitcnt lgkmcnt(0)\n\ts_barrier" ::: "memory");
    }
  }

  float l = lpart;
  l += __shfl_xor(l, 16);
  l += __shfl_xor(l, 32);
#pragma unroll
  for (int jj = 0; jj < 4; ++jj) {
    float inv = 1.f / __shfl(l, klo + jj);
    size_t ob = (size_t)(bi * T_ + q0 + w * 16 + klo + jj) * (NH * HD) + h * HD;
#pragma unroll
    for (int nb = 0; nb < 8; ++nb)
      y[ob + nb * 16 + lr] = __float2bfloat16(o[nb][jj] * inv);
  }
}

extern "C" void kernel_launch(void* const* d_in, const int* in_sizes, int n_in,
                              void* d_out, int out_size, void* d_ws, size_t ws_size,
                              hipStream_t stream) {
  const float* x    = (const float*)d_in[0];
  const float* ve   = (const float*)d_in[1];
  const float* cosT = (const float*)d_in[2];
  const float* sinT = (const float*)d_in[3];
  const float* Wq   = (const float*)d_in[4];
  const float* Wk   = (const float*)d_in[5];
  const float* Wv   = (const float*)d_in[6];
  const float* Wg   = (const float*)d_in[7];
  const float* Wo   = (const float*)d_in[8];
  const int*   win  = (const int*)d_in[9];
  float* out = (float*)d_out;

  char* ws = (char*)d_ws;
  bf16*  xb   = (bf16*)(ws);
  bf16*  wT   = (bf16*)(ws + 16777216);
  bf16*  woT  = (bf16*)(ws + 29360128);
  bf16*  qkvb = (bf16*)(ws + 37748736);
  bf16*  qn   = (bf16*)(ws + 62914560);
  bf16*  kn   = (bf16*)(ws + 79691776);
  bf16*  vTb  = (bf16*)(ws + 83886080);
  bf16*  y    = qkvb;

  cast_x_kernel<<<8192, 256, 0, stream>>>((const float4*)x, (ushort4*)xb, 2097152);
  cast_transpose<<<dim3(64, 64), 256, 0, stream>>>(Wq, wT, 2048, 2048);
  cast_transpose<<<dim3(16, 64), 256, 0, stream>>>(Wk, wT + (size_t)2048 * 2048, 2048, 512);
  cast_transpose<<<dim3(16, 64), 256, 0, stream>>>(Wv, wT + (size_t)2560 * 2048, 2048, 512);
  cast_transpose<<<dim3(64, 64), 256, 0, stream>>>(Wo, woT, 2048, 2048);

  // QKV: 16x16 tiles of 256x192 -> 256 blocks (100% CU fill); regions 4x8
  gemm_pp<8, 3, bf16><<<256, 512, 0, stream>>>(xb, wT, qkvb, 3072, 2048, 4, 8);
  epilogue_kernel<<<4096, 256, 0, stream>>>(qkvb, x, ve, cosT, sinT, Wg, qn, kn, vTb);
  attn_kernel<<<1024, 256, 0, stream>>>(qn, kn, vTb, y, win);
  // Wo: 32x8 tiles of 128x256 -> 256 blocks; regions 8x4
  gemm_pp<4, 4, float><<<256, 512, 0, stream>>>(y, woT, out, 2048, 2048, 8, 4);
}

// Round 9
// 195.583 us; speedup vs baseline: 1.7331x; 1.0127x over previous
//
#include <hip/hip_runtime.h>
#include <hip/hip_bf16.h>
#include <cstdint>

typedef __hip_bfloat16 bf16;
typedef __attribute__((ext_vector_type(8))) short short8;
typedef __attribute__((ext_vector_type(4))) short short4v;
typedef __attribute__((ext_vector_type(4))) float f32x4;

#define T_   2048
#define CDIM 2048
#define NH   16
#define NKV  4
#define HD   128
// 1/sqrt(128) * log2(e), folded into q at the epilogue so attn scores are exp2-ready
#define QSCALE (0.08838834764831845f * 1.44269504088896340f)

__device__ __forceinline__ void gload_lds16(const void* g, void* l) {
  __builtin_amdgcn_global_load_lds(
      (const __attribute__((address_space(1))) void*)g,
      (__attribute__((address_space(3))) void*)l, 16, 0, 0);
}

template <int G> __device__ __forceinline__ void vm_gate() {
  if constexpr (G == 6)      asm volatile("s_waitcnt vmcnt(6)" ::: "memory");
  else if constexpr (G == 5) asm volatile("s_waitcnt vmcnt(5)" ::: "memory");
  else                       asm volatile("s_waitcnt vmcnt(0)" ::: "memory");
}

// ---------------- cast x (fp32 -> bf16), vectorized ----------------
__global__ __launch_bounds__(256) void cast_x_kernel(const float4* __restrict__ in,
                                                     ushort4* __restrict__ out, int n4) {
  int i = blockIdx.x * 256 + threadIdx.x;
  if (i >= n4) return;
  float4 v = in[i];
  union { bf16 h[4]; ushort4 u; } cv;
  cv.h[0] = __float2bfloat16(v.x);
  cv.h[1] = __float2bfloat16(v.y);
  cv.h[2] = __float2bfloat16(v.z);
  cv.h[3] = __float2bfloat16(v.w);
  out[i] = cv.u;
}

// ---------------- cast + transpose W[K][N] fp32 -> WT[N][K] bf16 ----------------
__global__ __launch_bounds__(256) void cast_transpose(const float* __restrict__ W,
                                                      bf16* __restrict__ WT,
                                                      int K, int N) {
  __shared__ float tile[32][33];
  int k0 = blockIdx.y * 32, n0 = blockIdx.x * 32;
  int r = threadIdx.x >> 5, c = threadIdx.x & 31;  // r:0..7
  for (int i = 0; i < 4; ++i)
    tile[r + i * 8][c] = W[(size_t)(k0 + r + i * 8) * N + n0 + c];
  __syncthreads();
  for (int i = 0; i < 4; ++i)
    WT[(size_t)(n0 + r + i * 8) * K + k0 + c] = __float2bfloat16(tile[c][r + i * 8]);
}

// ---------------- unified per-phase GEMM (m201-faithful barriers) ----------------
// 8 waves (2M x 4N). BM=MREP*32, BN=NREP*64, BK=64; wave tile (MREP*16)x(NREP*16).
// Phase = {ds_read issue | stage issue -> s_barrier -> lgkmcnt(0)+sched_barrier ->
// setprio(1) MFMA setprio(0) -> s_barrier}: the ds-read latency drains DURING the
// first barrier wait (m201 pattern) instead of serializing before MFMA. Counted
// vmcnt(NREP+QN-1) once per K-tile. LDS rows 128B, 8x16B slots XOR row&7, source
// pre-swizzled (global_load_lds dest linear). XCD regions 4x2.
template <int MREP, int NREP, typename CT>
__global__ __launch_bounds__(512, 2) void gemm_pp(const bf16* __restrict__ A,
                                                  const bf16* __restrict__ BT,
                                                  CT* __restrict__ C,
                                                  int N, int K, int RY, int RX) {
  constexpr int BM = MREP * 32;
  constexpr int BN = NREP * 64;
  constexpr int QN = (MREP == 8) ? 4 : 2;   // A stage quanta per tile
  constexpr int MI = MREP / 4;              // A frags per phase
  constexpr int GATE = NREP + QN - 1;       // steady-state vmcnt
  __shared__ __align__(16) bf16 sA[2][BM * 64];
  __shared__ __align__(16) bf16 sB[2][BN * 64];

  int tid = threadIdx.x;
  int lane = tid & 63, w = tid >> 6;
  int wm = w >> 2, wn = w & 3;
  int lr = lane & 15, lk = lane >> 4;

  int xcd = blockIdx.x & 7, t = blockIdx.x >> 3;
  int by = (xcd >> 1) * RY + t / RX;
  int bx = (xcd & 1) * RX + t % RX;
  int m0 = by * BM, n0 = bx * BN;

  f32x4 acc[MREP][NREP];
#pragma unroll
  for (int m = 0; m < MREP; ++m)
#pragma unroll
    for (int n = 0; n < NREP; ++n) acc[m][n] = (f32x4){0.f, 0.f, 0.f, 0.f};

  const bf16* Abase = A + (size_t)m0 * K;
  const bf16* Bbase = BT + (size_t)n0 * K;

  auto stageB = [&](int p, int kt) {
    int kb = kt << 6;
#pragma unroll
    for (int i = 0; i < NREP; ++i) {
      int c = i * 512 + tid;
      int r = c >> 3, sl = c & 7;
      gload_lds16(Bbase + (size_t)r * K + kb + ((sl ^ (r & 7)) << 3),
                  (char*)(&sB[p][0]) + c * 16);
    }
  };
  auto stageAq = [&](int p, int kt, int q) {
    int kb = kt << 6;
    int rbase = 32 * q + ((w & 3) << 3) + ((w >> 2) * (BM / 2));
    int r = rbase + (lane >> 3), sl = lane & 7;
    gload_lds16(Abase + (size_t)r * K + kb + ((sl ^ (r & 7)) << 3),
                (char*)(&sA[p][0]) + rbase * 128 + lane * 16);
  };

  int nk = K >> 6;
  stageB(0, 0);
#pragma unroll
  for (int q = 0; q < QN; ++q) stageAq(0, 0, q);
  stageB(1, 1);
#pragma unroll
  for (int q = 0; q < QN - 1; ++q) stageAq(1, 1, q);
  vm_gate<GATE>();
  __builtin_amdgcn_s_barrier();

#define READ_A_FRAGS(PH)                                                   \
  {                                                                        \
    _Pragma("unroll")                                                      \
    for (int mi = 0; mi < MI; ++mi) {                                      \
      int row = wm * (MREP * 16) + ((PH) * MI + mi) * 16 + lr;             \
      const char* rb = sAb + row * 128;                                    \
      int rx = (row & 7) << 4;                                             \
      af[mi][0] = *(const short8*)(rb + ((lk * 16) ^ rx));                 \
      af[mi][1] = *(const short8*)(rb + ((64 + lk * 16) ^ rx));            \
    }                                                                      \
  }
#define MFMA_PH(PH)                                                        \
  __builtin_amdgcn_s_setprio(1);                                           \
  _Pragma("unroll")                                                        \
  for (int kk = 0; kk < 2; ++kk)                                           \
    _Pragma("unroll")                                                      \
    for (int mi = 0; mi < MI; ++mi)                                        \
      _Pragma("unroll")                                                    \
      for (int n = 0; n < NREP; ++n)                                       \
        acc[(PH) * MI + mi][n] = __builtin_amdgcn_mfma_f32_16x16x32_bf16(  \
            af[mi][kk], bfr[n][kk], acc[(PH) * MI + mi][n], 0, 0, 0);      \
  __builtin_amdgcn_s_setprio(0);
#define WAIT_LGKM                                                          \
  asm volatile("s_waitcnt lgkmcnt(0)" ::: "memory");                       \
  __builtin_amdgcn_sched_barrier(0);

  for (int kt = 0; kt < nk; ++kt) {
    int p = kt & 1;
    const char* sAb = (const char*)(&sA[p][0]);
    const char* sBb = (const char*)(&sB[p][0]);
    short8 bfr[NREP][2], af[MI][2];

    // ---- phase 0: issue B + A-frags(0) reads; stage last A-quantum of kt+1 ----
#pragma unroll
    for (int n = 0; n < NREP; ++n) {
      int row = wn * (NREP * 16) + n * 16 + lr;
      const char* rb = sBb + row * 128;
      int rx = (row & 7) << 4;
      bfr[n][0] = *(const short8*)(rb + ((lk * 16) ^ rx));
      bfr[n][1] = *(const short8*)(rb + ((64 + lk * 16) ^ rx));
    }
    READ_A_FRAGS(0);
    if (kt + 1 < nk) stageAq(p ^ 1, kt + 1, QN - 1);
    __builtin_amdgcn_s_barrier();   // ds-read latency drains during barrier wait
    WAIT_LGKM;
    MFMA_PH(0);
    __builtin_amdgcn_s_barrier();

    // ---- phase 1: A-frags(1); stage B(kt+2) [+Aq0 when QN==4] ----
    READ_A_FRAGS(1);
    if (kt + 2 < nk) {
      stageB(p, kt + 2);
      if constexpr (QN == 4) stageAq(p, kt + 2, 0);
    }
    __builtin_amdgcn_s_barrier();
    WAIT_LGKM;
    MFMA_PH(1);
    __builtin_amdgcn_s_barrier();

    // ---- phase 2: A-frags(2); stage Aq1 (QN==4) / Aq0 (QN==2) of kt+2 ----
    READ_A_FRAGS(2);
    if (kt + 2 < nk) stageAq(p, kt + 2, (QN == 4) ? 1 : 0);
    __builtin_amdgcn_s_barrier();
    WAIT_LGKM;
    MFMA_PH(2);
    __builtin_amdgcn_s_barrier();

    // ---- phase 3: A-frags(3); stage Aq2 (QN==4); counted gate ----
    READ_A_FRAGS(3);
    if constexpr (QN == 4) {
      if (kt + 2 < nk) stageAq(p, kt + 2, 2);
    }
    __builtin_amdgcn_s_barrier();
    WAIT_LGKM;
    MFMA_PH(3);
    if (kt + 2 < nk) vm_gate<GATE>();
    else             vm_gate<0>();
    __builtin_amdgcn_s_barrier();
  }
#undef READ_A_FRAGS
#undef MFMA_PH
#undef WAIT_LGKM

#pragma unroll
  for (int m = 0; m < MREP; ++m)
#pragma unroll
    for (int n = 0; n < NREP; ++n)
#pragma unroll
      for (int jj = 0; jj < 4; ++jj) {
        size_t idx = (size_t)(m0 + wm * (MREP * 16) + m * 16 + lk * 4 + jj) * N +
                     n0 + wn * (NREP * 16) + n * 16 + lr;
        if constexpr (__is_same(CT, float))
          C[idx] = acc[m][n][jj];
        else
          C[idx] = __float2bfloat16(acc[m][n][jj]);
      }
}

// ---------------- epilogue: gate, v-update(+transpose), RoPE + RMSNorm ----------------
__global__ __launch_bounds__(256) void epilogue_kernel(
    const bf16* __restrict__ qkv, const float* __restrict__ x,
    const float* __restrict__ ve, const float* __restrict__ cosT,
    const float* __restrict__ sinT, const float* __restrict__ Wg,
    bf16* __restrict__ qn, bf16* __restrict__ kn, bf16* __restrict__ vT) {
  int row = blockIdx.x;
  int bi = row >> 11, t = row & 2047;
  int tid = threadIdx.x, lane = tid & 63, w = tid >> 6;
  __shared__ float gate[NKV];
  size_t rb = (size_t)row * 3072;

  if (tid < 128) {
    int g = tid >> 5, i = tid & 31;
    float p = x[(size_t)row * CDIM + i] * Wg[i * 4 + g];
    p += __shfl_xor(p, 1);  p += __shfl_xor(p, 2);
    p += __shfl_xor(p, 4);  p += __shfl_xor(p, 8);
    p += __shfl_xor(p, 16);
    if (i == 0) gate[g] = 2.f / (1.f + __expf(-p));
  }
  __syncthreads();

  float cv = cosT[t * 64 + lane];
  float sv = sinT[t * 64 + lane];

  for (int it = 0; it < 4; ++it) {
    int h = it * 4 + w;
    float x1 = __bfloat162float(qkv[rb + h * 128 + lane]);
    float x2 = __bfloat162float(qkv[rb + h * 128 + 64 + lane]);
    float y1 = x1 * cv + x2 * sv;
    float y2 = x2 * cv - x1 * sv;
    float ss = y1 * y1 + y2 * y2;
    ss += __shfl_xor(ss, 1);  ss += __shfl_xor(ss, 2);  ss += __shfl_xor(ss, 4);
    ss += __shfl_xor(ss, 8);  ss += __shfl_xor(ss, 16); ss += __shfl_xor(ss, 32);
    float r = rsqrtf(ss * (1.f / 128.f) + 1e-6f) * QSCALE;
    size_t ob = (size_t)row * (NH * HD) + h * 128;
    qn[ob + lane] = __float2bfloat16(y1 * r);
    qn[ob + 64 + lane] = __float2bfloat16(y2 * r);
  }
  {
    int h = w;
    float x1 = __bfloat162float(qkv[rb + 2048 + h * 128 + lane]);
    float x2 = __bfloat162float(qkv[rb + 2048 + h * 128 + 64 + lane]);
    float y1 = x1 * cv + x2 * sv;
    float y2 = x2 * cv - x1 * sv;
    float ss = y1 * y1 + y2 * y2;
    ss += __shfl_xor(ss, 1);  ss += __shfl_xor(ss, 2);  ss += __shfl_xor(ss, 4);
    ss += __shfl_xor(ss, 8);  ss += __shfl_xor(ss, 16); ss += __shfl_xor(ss, 32);
    float r = rsqrtf(ss * (1.f / 128.f) + 1e-6f);
    size_t ob = (size_t)row * (NKV * HD) + h * 128;
    kn[ob + lane] = __float2bfloat16(y1 * r);
    kn[ob + 64 + lane] = __float2bfloat16(y2 * r);
  }
  for (int e = tid; e < 512; e += 256) {
    int kv = e >> 7, d = e & 127;
    float val = __bfloat162float(qkv[rb + 2560 + e]) + gate[kv] * ve[(size_t)row * 512 + e];
    vT[((size_t)(bi * NKV + kv) * HD + d) * T_ + t] = __float2bfloat16(val);
  }
}

// ---------------- flash attention v6: QBLK=128, shared K/V frags per wave ----------
// Each wave owns TWO 16-row q fragments (rows q0+w*32+{0..15} and +{16..31}); every
// K-fragment / V-fragment LDS read feeds both (s0/s1, o0/o1) -> LDS reads & staging
// per q-row HALVED vs QBLK=64. Swapped mfma(K,Q), in-register P (permuted V columns),
// T14 reg-staged K/V, no-max exp2 softmax (RMSNorm bounds |score| <= 16.33).
// 512 blocks; id&7 = (bi,kvh) pins K/V slice to one XCD; natural q0 order=heavy-first.
__global__ __launch_bounds__(256, 2) void attn_kernel(
    const bf16* __restrict__ qn, const bf16* __restrict__ kn,
    const bf16* __restrict__ vT, bf16* __restrict__ y,
    const int* __restrict__ winp) {
  __shared__ __align__(16) bf16 sK[64 * 128];   // [key][d], 16-slot XOR swizzle
  __shared__ __align__(16) bf16 sV[128 * 64];   // [d][key-permuted], XOR swizzle

  int win = *winp;
  int id = blockIdx.x;
  int g  = id & 7;
  int bi = g >> 2, kvh = g & 3;
  int rem = id >> 3;                 // 0..63
  int h  = kvh * 4 + (rem & 3);
  int q0 = (rem >> 2) << 7;          // 16 q-blocks of 128 rows, heavy-first
  int tid = threadIdx.x;
  int lane = tid & 63, w = tid >> 6;
  int lr = lane & 15, lk = lane >> 4;

  short8 qfA[4], qfB[4];             // two 16-row fragments
  {
    const bf16* qrA = qn + (size_t)(bi * T_ + q0 + w * 32 + lr) * (NH * HD) + h * HD;
    const bf16* qrB = qrA + (size_t)16 * (NH * HD);
#pragma unroll
    for (int c = 0; c < 4; ++c) {
      qfA[c] = *(const short8*)(qrA + c * 32 + lk * 8);
      qfB[c] = *(const short8*)(qrB + c * 32 + lk * 8);
    }
  }

  int kge[4], klb[4], vge[4], vlbA[4], vlbB[4];
#pragma unroll
  for (int i = 0; i < 4; ++i) {
    int c = i * 256 + tid;
    int kr = c >> 4, ks = c & 15;
    kge[i] = kr * (NKV * HD) + ks * 8;
    klb[i] = kr * 256 + ((ks ^ (kr & 7)) << 4);
    int vr = c >> 3, vs = c & 7;
    vge[i] = vr * T_ + vs * 8;
    int hh = vs >> 2, m = vs & 3, a = m >> 1;
    int sA = 8 * ((2 * m) & 3) + 4 * a;
    int sB = 8 * ((2 * m + 1) & 3) + 4 * a;
    int tA = 64 * hh + 2 * sA, tB = 64 * hh + 2 * sB;
    vlbA[i] = vr * 128 + (((tA >> 4) ^ (vr & 7)) << 4) + (tA & 15);
    vlbB[i] = vr * 128 + (((tB >> 4) ^ (vr & 7)) << 4) + (tB & 15);
  }
  const bf16* kpane = kn + (size_t)bi * T_ * (NKV * HD) + kvh * HD;
  const bf16* vpane = vT + (size_t)(bi * NKV + kvh) * HD * T_;

  short8 kreg[4], vreg[4];
  auto LOAD = [&](int jtx) {
    const bf16* kb = kpane + (size_t)(jtx << 6) * (NKV * HD);
    const bf16* vb = vpane + (jtx << 6);
#pragma unroll
    for (int i = 0; i < 4; ++i) kreg[i] = *(const short8*)(kb + kge[i]);
#pragma unroll
    for (int i = 0; i < 4; ++i) vreg[i] = *(const short8*)(vb + vge[i]);
  };
  auto WRITE = [&]() {
#pragma unroll
    for (int i = 0; i < 4; ++i) *(short8*)((char*)sK + klb[i]) = kreg[i];
#pragma unroll
    for (int i = 0; i < 4; ++i) {
      union { short8 s8; short4v s4[2]; } u;
      u.s8 = vreg[i];
      *(short4v*)((char*)sV + vlbA[i]) = u.s4[0];
      *(short4v*)((char*)sV + vlbB[i]) = u.s4[1];
    }
  };

  f32x4 o0[8], o1[8];
#pragma unroll
  for (int i = 0; i < 8; ++i) {
    o0[i] = (f32x4){0.f, 0.f, 0.f, 0.f};
    o1[i] = (f32x4){0.f, 0.f, 0.f, 0.f};
  }
  float lp0 = 0.f, lp1 = 0.f;

  int jt0 = q0 >> 6;
  int hi = q0 + 126 + win; if (hi > T_ - 1) hi = T_ - 1;
  int jt1 = hi >> 6;

  LOAD(jt0);
  WRITE();
  if (jt0 < jt1) LOAD(jt0 + 1);
  asm volatile("s_waitcnt lgkmcnt(0)\n\ts_barrier" ::: "memory");

  int irow0 = q0 + w * 32 + lr;      // qs=0 row; qs=1 row = irow0+16
  int klo = lk * 4;

  for (int jt = jt0; jt <= jt1; ++jt) {
    int j0 = jt << 6;

    f32x4 s0[4], s1[4];
#pragma unroll
    for (int sub = 0; sub < 4; ++sub) {
      s0[sub] = (f32x4){0.f, 0.f, 0.f, 0.f};
      s1[sub] = (f32x4){0.f, 0.f, 0.f, 0.f};
    }
    __builtin_amdgcn_s_setprio(1);
#pragma unroll
    for (int sub = 0; sub < 4; ++sub) {
      int kr = sub * 16 + lr;
      int rx = (kr & 7) << 4;
      const char* rowb = (const char*)sK + kr * 256;
#pragma unroll
      for (int c = 0; c < 4; ++c) {
        short8 kf = *(const short8*)(rowb + ((c * 64 + lk * 16) ^ rx));
        s0[sub] = __builtin_amdgcn_mfma_f32_16x16x32_bf16(kf, qfA[c], s0[sub], 0, 0, 0);
        s1[sub] = __builtin_amdgcn_mfma_f32_16x16x32_bf16(kf, qfB[c], s1[sub], 0, 0, 0);
      }
    }
    __builtin_amdgcn_s_setprio(0);

    bool full = (j0 >= q0 + 128) && (j0 + 64 <= q0 + win);
    int koff0 = j0 - irow0;
    int koff1 = koff0 - 16;

    short8 pA0, pA1, pB0, pB1;
    {
      unsigned pk[8];
#pragma unroll
      for (int sub = 0; sub < 4; ++sub) {
        float p0 = exp2f(s0[sub][0]), p1 = exp2f(s0[sub][1]);
        float p2 = exp2f(s0[sub][2]), p3 = exp2f(s0[sub][3]);
        if (!full) {
          int base = koff0 + sub * 16 + klo;
          p0 = ((unsigned)(base + 0) < (unsigned)win) ? p0 : 0.f;
          p1 = ((unsigned)(base + 1) < (unsigned)win) ? p1 : 0.f;
          p2 = ((unsigned)(base + 2) < (unsigned)win) ? p2 : 0.f;
          p3 = ((unsigned)(base + 3) < (unsigned)win) ? p3 : 0.f;
        }
        lp0 += (p0 + p1) + (p2 + p3);
        asm("v_cvt_pk_bf16_f32 %0, %1, %2" : "=v"(pk[sub * 2])     : "v"(p0), "v"(p1));
        asm("v_cvt_pk_bf16_f32 %0, %1, %2" : "=v"(pk[sub * 2 + 1]) : "v"(p2), "v"(p3));
      }
      union { unsigned u[4]; short8 s8; } c0, c1;
      c0.u[0] = pk[0]; c0.u[1] = pk[1]; c0.u[2] = pk[2]; c0.u[3] = pk[3];
      c1.u[0] = pk[4]; c1.u[1] = pk[5]; c1.u[2] = pk[6]; c1.u[3] = pk[7];
      pA0 = c0.s8; pA1 = c1.s8;
    }
    {
      unsigned pk[8];
#pragma unroll
      for (int sub = 0; sub < 4; ++sub) {
        float p0 = exp2f(s1[sub][0]), p1 = exp2f(s1[sub][1]);
        float p2 = exp2f(s1[sub][2]), p3 = exp2f(s1[sub][3]);
        if (!full) {
          int base = koff1 + sub * 16 + klo;
          p0 = ((unsigned)(base + 0) < (unsigned)win) ? p0 : 0.f;
          p1 = ((unsigned)(base + 1) < (unsigned)win) ? p1 : 0.f;
          p2 = ((unsigned)(base + 2) < (unsigned)win) ? p2 : 0.f;
          p3 = ((unsigned)(base + 3) < (unsigned)win) ? p3 : 0.f;
        }
        lp1 += (p0 + p1) + (p2 + p3);
        asm("v_cvt_pk_bf16_f32 %0, %1, %2" : "=v"(pk[sub * 2])     : "v"(p0), "v"(p1));
        asm("v_cvt_pk_bf16_f32 %0, %1, %2" : "=v"(pk[sub * 2 + 1]) : "v"(p2), "v"(p3));
      }
      union { unsigned u[4]; short8 s8; } c0, c1;
      c0.u[0] = pk[0]; c0.u[1] = pk[1]; c0.u[2] = pk[2]; c0.u[3] = pk[3];
      c1.u[0] = pk[4]; c1.u[1] = pk[5]; c1.u[2] = pk[6]; c1.u[3] = pk[7];
      pB0 = c0.s8; pB1 = c1.s8;
    }

    __builtin_amdgcn_s_setprio(1);
#pragma unroll
    for (int nb = 0; nb < 8; ++nb) {
      int vr = nb * 16 + lr;
      int vrx = (vr & 7) << 4;
      const char* vb = (const char*)sV + vr * 128;
      short8 vf0 = *(const short8*)(vb + ((lk * 16) ^ vrx));
      short8 vf1 = *(const short8*)(vb + ((64 + lk * 16) ^ vrx));
      o0[nb] = __builtin_amdgcn_mfma_f32_16x16x32_bf16(pA0, vf0, o0[nb], 0, 0, 0);
      o0[nb] = __builtin_amdgcn_mfma_f32_16x16x32_bf16(pA1, vf1, o0[nb], 0, 0, 0);
      o1[nb] = __builtin_amdgcn_mfma_f32_16x16x32_bf16(pB0, vf0, o1[nb], 0, 0, 0);
      o1[nb] = __builtin_amdgcn_mfma_f32_16x16x32_bf16(pB1, vf1, o1[nb], 0, 0, 0);
    }
    __builtin_amdgcn_s_setprio(0);

    asm volatile("s_waitcnt lgkmcnt(0)\n\ts_barrier" ::: "memory");
    if (jt < jt1) {
      WRITE();
      if (jt + 1 < jt1) LOAD(jt + 2);
      asm volatile("s_waitcnt lgkmcnt(0)\n\ts_barrier" ::: "memory");
    }
  }

  float l0 = lp0, l1 = lp1;
  l0 += __shfl_xor(l0, 16); l0 += __shfl_xor(l0, 32);
  l1 += __shfl_xor(l1, 16); l1 += __shfl_xor(l1, 32);
#pragma unroll
  for (int jj = 0; jj < 4; ++jj) {
    float inv0 = 1.f / __shfl(l0, klo + jj);
    float inv1 = 1.f / __shfl(l1, klo + jj);
    size_t ob0 = (size_t)(bi * T_ + q0 + w * 32 + klo + jj) * (NH * HD) + h * HD;
    size_t ob1 = ob0 + (size_t)16 * (NH * HD);
#pragma unroll
    for (int nb = 0; nb < 8; ++nb) {
      y[ob0 + nb * 16 + lr] = __float2bfloat16(o0[nb][jj] * inv0);
      y[ob1 + nb * 16 + lr] = __float2bfloat16(o1[nb][jj] * inv1);
    }
  }
}

extern "C" void kernel_launch(void* const* d_in, const int* in_sizes, int n_in,
                              void* d_out, int out_size, void* d_ws, size_t ws_size,
                              hipStream_t stream) {
  const float* x    = (const float*)d_in[0];
  const float* ve   = (const float*)d_in[1];
  const float* cosT = (const float*)d_in[2];
  const float* sinT = (const float*)d_in[3];
  const float* Wq   = (const float*)d_in[4];
  const float* Wk   = (const float*)d_in[5];
  const float* Wv   = (const float*)d_in[6];
  const float* Wg   = (const float*)d_in[7];
  const float* Wo   = (const float*)d_in[8];
  const int*   win  = (const int*)d_in[9];
  float* out = (float*)d_out;

  char* ws = (char*)d_ws;
  bf16*  xb   = (bf16*)(ws);
  bf16*  wT   = (bf16*)(ws + 16777216);
  bf16*  woT  = (bf16*)(ws + 29360128);
  bf16*  qkvb = (bf16*)(ws + 37748736);
  bf16*  qn   = (bf16*)(ws + 62914560);
  bf16*  kn   = (bf16*)(ws + 79691776);
  bf16*  vTb  = (bf16*)(ws + 83886080);
  bf16*  y    = qkvb;

  cast_x_kernel<<<8192, 256, 0, stream>>>((const float4*)x, (ushort4*)xb, 2097152);
  cast_transpose<<<dim3(64, 64), 256, 0, stream>>>(Wq, wT, 2048, 2048);
  cast_transpose<<<dim3(16, 64), 256, 0, stream>>>(Wk, wT + (size_t)2048 * 2048, 2048, 512);
  cast_transpose<<<dim3(16, 64), 256, 0, stream>>>(Wv, wT + (size_t)2560 * 2048, 2048, 512);
  cast_transpose<<<dim3(64, 64), 256, 0, stream>>>(Wo, woT, 2048, 2048);

  // QKV: 16x16 tiles of 256x192 -> 256 blocks (100% CU fill); regions 4x8
  gemm_pp<8, 3, bf16><<<256, 512, 0, stream>>>(xb, wT, qkvb, 3072, 2048, 4, 8);
  epilogue_kernel<<<4096, 256, 0, stream>>>(qkvb, x, ve, cosT, sinT, Wg, qn, kn, vTb);
  attn_kernel<<<512, 256, 0, stream>>>(qn, kn, vTb, y, win);
  // Wo: 32x8 tiles of 128x256 -> 256 blocks; regions 8x4
  gemm_pp<4, 4, float><<<256, 512, 0, stream>>>(y, woT, out, 2048, 2048, 8, 4);
}

// Round 10
// 193.438 us; speedup vs baseline: 1.7523x; 1.0111x over previous
//
#include <hip/hip_runtime.h>
#include <hip/hip_bf16.h>
#include <cstdint>

typedef __hip_bfloat16 bf16;
typedef __attribute__((ext_vector_type(8))) short short8;
typedef __attribute__((ext_vector_type(4))) short short4v;
typedef __attribute__((ext_vector_type(4))) float f32x4;

#define T_   2048
#define CDIM 2048
#define NH   16
#define NKV  4
#define HD   128
// 1/sqrt(128) * log2(e), folded into q at the epilogue so attn scores are exp2-ready
#define QSCALE (0.08838834764831845f * 1.44269504088896340f)

__device__ __forceinline__ void gload_lds16(const void* g, void* l) {
  __builtin_amdgcn_global_load_lds(
      (const __attribute__((address_space(1))) void*)g,
      (__attribute__((address_space(3))) void*)l, 16, 0, 0);
}

template <int G> __device__ __forceinline__ void vm_gate() {
  if constexpr (G == 6)      asm volatile("s_waitcnt vmcnt(6)" ::: "memory");
  else if constexpr (G == 5) asm volatile("s_waitcnt vmcnt(5)" ::: "memory");
  else                       asm volatile("s_waitcnt vmcnt(0)" ::: "memory");
}

// ---------------- cast x (fp32 -> bf16), vectorized ----------------
__global__ __launch_bounds__(256) void cast_x_kernel(const float4* __restrict__ in,
                                                     ushort4* __restrict__ out, int n4) {
  int i = blockIdx.x * 256 + threadIdx.x;
  if (i >= n4) return;
  float4 v = in[i];
  union { bf16 h[4]; ushort4 u; } cv;
  cv.h[0] = __float2bfloat16(v.x);
  cv.h[1] = __float2bfloat16(v.y);
  cv.h[2] = __float2bfloat16(v.z);
  cv.h[3] = __float2bfloat16(v.w);
  out[i] = cv.u;
}

// ---------------- cast + transpose W[K][N] fp32 -> WT[N][K] bf16 ----------------
__global__ __launch_bounds__(256) void cast_transpose(const float* __restrict__ W,
                                                      bf16* __restrict__ WT,
                                                      int K, int N) {
  __shared__ float tile[32][33];
  int k0 = blockIdx.y * 32, n0 = blockIdx.x * 32;
  int r = threadIdx.x >> 5, c = threadIdx.x & 31;  // r:0..7
  for (int i = 0; i < 4; ++i)
    tile[r + i * 8][c] = W[(size_t)(k0 + r + i * 8) * N + n0 + c];
  __syncthreads();
  for (int i = 0; i < 4; ++i)
    WT[(size_t)(n0 + r + i * 8) * K + k0 + c] = __float2bfloat16(tile[c][r + i * 8]);
}

// ---------------- unified per-phase GEMM (round-8 proven barrier pattern) ----------
// 8 waves (2M x 4N). BM=MREP*32, BN=NREP*64, BK=64; wave tile (MREP*16)x(NREP*16).
// Phase = {ds_read A-frags [+B at ph0] | stage one region -> lgkmcnt(0)+sched_barrier
// -> setprio(1) MFMA setprio(0) -> s_barrier}. Counted vmcnt(NREP+QN-1) once per
// K-tile. LDS rows 128B, 8x16B slots XOR row&7, source pre-swizzled. XCD regions 4x2.
template <int MREP, int NREP, typename CT>
__global__ __launch_bounds__(512, 2) void gemm_pp(const bf16* __restrict__ A,
                                                  const bf16* __restrict__ BT,
                                                  CT* __restrict__ C,
                                                  int N, int K, int RY, int RX) {
  constexpr int BM = MREP * 32;
  constexpr int BN = NREP * 64;
  constexpr int QN = (MREP == 8) ? 4 : 2;   // A stage quanta per tile
  constexpr int MI = MREP / 4;              // A frags per phase
  constexpr int GATE = NREP + QN - 1;       // steady-state vmcnt
  __shared__ __align__(16) bf16 sA[2][BM * 64];
  __shared__ __align__(16) bf16 sB[2][BN * 64];

  int tid = threadIdx.x;
  int lane = tid & 63, w = tid >> 6;
  int wm = w >> 2, wn = w & 3;
  int lr = lane & 15, lk = lane >> 4;

  int xcd = blockIdx.x & 7, t = blockIdx.x >> 3;
  int by = (xcd >> 1) * RY + t / RX;
  int bx = (xcd & 1) * RX + t % RX;
  int m0 = by * BM, n0 = bx * BN;

  f32x4 acc[MREP][NREP];
#pragma unroll
  for (int m = 0; m < MREP; ++m)
#pragma unroll
    for (int n = 0; n < NREP; ++n) acc[m][n] = (f32x4){0.f, 0.f, 0.f, 0.f};

  const bf16* Abase = A + (size_t)m0 * K;
  const bf16* Bbase = BT + (size_t)n0 * K;

  auto stageB = [&](int p, int kt) {
    int kb = kt << 6;
#pragma unroll
    for (int i = 0; i < NREP; ++i) {
      int c = i * 512 + tid;
      int r = c >> 3, sl = c & 7;
      gload_lds16(Bbase + (size_t)r * K + kb + ((sl ^ (r & 7)) << 3),
                  (char*)(&sB[p][0]) + c * 16);
    }
  };
  auto stageAq = [&](int p, int kt, int q) {
    int kb = kt << 6;
    int rbase = 32 * q + ((w & 3) << 3) + ((w >> 2) * (BM / 2));
    int r = rbase + (lane >> 3), sl = lane & 7;
    gload_lds16(Abase + (size_t)r * K + kb + ((sl ^ (r & 7)) << 3),
                (char*)(&sA[p][0]) + rbase * 128 + lane * 16);
  };

  int nk = K >> 6;
  stageB(0, 0);
#pragma unroll
  for (int q = 0; q < QN; ++q) stageAq(0, 0, q);
  stageB(1, 1);
#pragma unroll
  for (int q = 0; q < QN - 1; ++q) stageAq(1, 1, q);
  vm_gate<GATE>();
  __builtin_amdgcn_s_barrier();

#define READ_A_FRAGS(PH)                                                   \
  {                                                                        \
    _Pragma("unroll")                                                      \
    for (int mi = 0; mi < MI; ++mi) {                                      \
      int row = wm * (MREP * 16) + ((PH) * MI + mi) * 16 + lr;             \
      const char* rb = sAb + row * 128;                                    \
      int rx = (row & 7) << 4;                                             \
      af[mi][0] = *(const short8*)(rb + ((lk * 16) ^ rx));                 \
      af[mi][1] = *(const short8*)(rb + ((64 + lk * 16) ^ rx));            \
    }                                                                      \
  }
#define MFMA_PH(PH)                                                        \
  __builtin_amdgcn_s_setprio(1);                                           \
  _Pragma("unroll")                                                        \
  for (int kk = 0; kk < 2; ++kk)                                           \
    _Pragma("unroll")                                                      \
    for (int mi = 0; mi < MI; ++mi)                                        \
      _Pragma("unroll")                                                    \
      for (int n = 0; n < NREP; ++n)                                       \
        acc[(PH) * MI + mi][n] = __builtin_amdgcn_mfma_f32_16x16x32_bf16(  \
            af[mi][kk], bfr[n][kk], acc[(PH) * MI + mi][n], 0, 0, 0);      \
  __builtin_amdgcn_s_setprio(0);
#define LGKM_FENCE                                                         \
  asm volatile("s_waitcnt lgkmcnt(0)" ::: "memory");                       \
  __builtin_amdgcn_sched_barrier(0);

  for (int kt = 0; kt < nk; ++kt) {
    int p = kt & 1;
    const char* sAb = (const char*)(&sA[p][0]);
    const char* sBb = (const char*)(&sB[p][0]);
    short8 bfr[NREP][2], af[MI][2];

    // ---- phase 0: B + A-frags(0); stage last A-quantum of tile kt+1 ----
#pragma unroll
    for (int n = 0; n < NREP; ++n) {
      int row = wn * (NREP * 16) + n * 16 + lr;
      const char* rb = sBb + row * 128;
      int rx = (row & 7) << 4;
      bfr[n][0] = *(const short8*)(rb + ((lk * 16) ^ rx));
      bfr[n][1] = *(const short8*)(rb + ((64 + lk * 16) ^ rx));
    }
    READ_A_FRAGS(0);
    if (kt + 1 < nk) stageAq(p ^ 1, kt + 1, QN - 1);
    LGKM_FENCE;
    MFMA_PH(0);
    __builtin_amdgcn_s_barrier();

    // ---- phase 1: A-frags(1); stage B(kt+2) [+Aq0 when QN==4] ----
    READ_A_FRAGS(1);
    if (kt + 2 < nk) {
      stageB(p, kt + 2);
      if constexpr (QN == 4) stageAq(p, kt + 2, 0);
    }
    LGKM_FENCE;
    MFMA_PH(1);
    __builtin_amdgcn_s_barrier();

    // ---- phase 2: A-frags(2); stage Aq1 (QN==4) / Aq0 (QN==2) of kt+2 ----
    READ_A_FRAGS(2);
    if (kt + 2 < nk) stageAq(p, kt + 2, (QN == 4) ? 1 : 0);
    LGKM_FENCE;
    MFMA_PH(2);
    __builtin_amdgcn_s_barrier();

    // ---- phase 3: A-frags(3); stage Aq2 (QN==4); counted gate ----
    READ_A_FRAGS(3);
    if constexpr (QN == 4) {
      if (kt + 2 < nk) stageAq(p, kt + 2, 2);
    }
    LGKM_FENCE;
    MFMA_PH(3);
    if (kt + 2 < nk) vm_gate<GATE>();
    else             vm_gate<0>();
    __builtin_amdgcn_s_barrier();
  }
#undef READ_A_FRAGS
#undef MFMA_PH
#undef LGKM_FENCE

#pragma unroll
  for (int m = 0; m < MREP; ++m)
#pragma unroll
    for (int n = 0; n < NREP; ++n)
#pragma unroll
      for (int jj = 0; jj < 4; ++jj) {
        size_t idx = (size_t)(m0 + wm * (MREP * 16) + m * 16 + lk * 4 + jj) * N +
                     n0 + wn * (NREP * 16) + n * 16 + lr;
        if constexpr (__is_same(CT, float))
          C[idx] = acc[m][n][jj];
        else
          C[idx] = __float2bfloat16(acc[m][n][jj]);
      }
}

// ---------------- epilogue: gate, v-update(+transpose), RoPE + RMSNorm ----------------
__global__ __launch_bounds__(256) void epilogue_kernel(
    const bf16* __restrict__ qkv, const float* __restrict__ x,
    const float* __restrict__ ve, const float* __restrict__ cosT,
    const float* __restrict__ sinT, const float* __restrict__ Wg,
    bf16* __restrict__ qn, bf16* __restrict__ kn, bf16* __restrict__ vT) {
  int row = blockIdx.x;
  int bi = row >> 11, t = row & 2047;
  int tid = threadIdx.x, lane = tid & 63, w = tid >> 6;
  __shared__ float gate[NKV];
  size_t rb = (size_t)row * 3072;

  if (tid < 128) {
    int g = tid >> 5, i = tid & 31;
    float p = x[(size_t)row * CDIM + i] * Wg[i * 4 + g];
    p += __shfl_xor(p, 1);  p += __shfl_xor(p, 2);
    p += __shfl_xor(p, 4);  p += __shfl_xor(p, 8);
    p += __shfl_xor(p, 16);
    if (i == 0) gate[g] = 2.f / (1.f + __expf(-p));
  }
  __syncthreads();

  float cv = cosT[t * 64 + lane];
  float sv = sinT[t * 64 + lane];

  for (int it = 0; it < 4; ++it) {
    int h = it * 4 + w;
    float x1 = __bfloat162float(qkv[rb + h * 128 + lane]);
    float x2 = __bfloat162float(qkv[rb + h * 128 + 64 + lane]);
    float y1 = x1 * cv + x2 * sv;
    float y2 = x2 * cv - x1 * sv;
    float ss = y1 * y1 + y2 * y2;
    ss += __shfl_xor(ss, 1);  ss += __shfl_xor(ss, 2);  ss += __shfl_xor(ss, 4);
    ss += __shfl_xor(ss, 8);  ss += __shfl_xor(ss, 16); ss += __shfl_xor(ss, 32);
    float r = rsqrtf(ss * (1.f / 128.f) + 1e-6f) * QSCALE;
    size_t ob = (size_t)row * (NH * HD) + h * 128;
    qn[ob + lane] = __float2bfloat16(y1 * r);
    qn[ob + 64 + lane] = __float2bfloat16(y2 * r);
  }
  {
    int h = w;
    float x1 = __bfloat162float(qkv[rb + 2048 + h * 128 + lane]);
    float x2 = __bfloat162float(qkv[rb + 2048 + h * 128 + 64 + lane]);
    float y1 = x1 * cv + x2 * sv;
    float y2 = x2 * cv - x1 * sv;
    float ss = y1 * y1 + y2 * y2;
    ss += __shfl_xor(ss, 1);  ss += __shfl_xor(ss, 2);  ss += __shfl_xor(ss, 4);
    ss += __shfl_xor(ss, 8);  ss += __shfl_xor(ss, 16); ss += __shfl_xor(ss, 32);
    float r = rsqrtf(ss * (1.f / 128.f) + 1e-6f);
    size_t ob = (size_t)row * (NKV * HD) + h * 128;
    kn[ob + lane] = __float2bfloat16(y1 * r);
    kn[ob + 64 + lane] = __float2bfloat16(y2 * r);
  }
  for (int e = tid; e < 512; e += 256) {
    int kv = e >> 7, d = e & 127;
    float val = __bfloat162float(qkv[rb + 2560 + e]) + gate[kv] * ve[(size_t)row * 512 + e];
    vT[((size_t)(bi * NKV + kv) * HD + d) * T_ + t] = __float2bfloat16(val);
  }
}

// ---------------- flash attention v7: QBLK=128, double-buffered LDS, 1 barrier/tile --
// Each wave owns two 16-row q fragments (K/V LDS reads shared across both). Swapped
// mfma(K,Q), in-register P (permuted V cols), no-max exp2 softmax. K/V double-buffered
// in LDS (64 KB): the reg->LDS WRITE of tile t+1 (into buf p^1, last read at t-1) is
// hoisted to the TOP of tile t, overlapping QK/PV compute; a single lgkm-drain +
// s_barrier per tile orders reads-of-p and writes-of-p^1 for all waves.
__global__ __launch_bounds__(256, 2) void attn_kernel(
    const bf16* __restrict__ qn, const bf16* __restrict__ kn,
    const bf16* __restrict__ vT, bf16* __restrict__ y,
    const int* __restrict__ winp) {
  __shared__ __align__(16) bf16 sK[2][64 * 128];   // [key][d], 16-slot XOR swizzle
  __shared__ __align__(16) bf16 sV[2][128 * 64];   // [d][key-permuted], XOR swizzle

  int win = *winp;
  int id = blockIdx.x;
  int g  = id & 7;
  int bi = g >> 2, kvh = g & 3;
  int rem = id >> 3;                 // 0..63
  int h  = kvh * 4 + (rem & 3);
  int q0 = (rem >> 2) << 7;          // 16 q-blocks of 128 rows, heavy-first
  int tid = threadIdx.x;
  int lane = tid & 63, w = tid >> 6;
  int lr = lane & 15, lk = lane >> 4;

  short8 qfA[4], qfB[4];
  {
    const bf16* qrA = qn + (size_t)(bi * T_ + q0 + w * 32 + lr) * (NH * HD) + h * HD;
    const bf16* qrB = qrA + (size_t)16 * (NH * HD);
#pragma unroll
    for (int c = 0; c < 4; ++c) {
      qfA[c] = *(const short8*)(qrA + c * 32 + lk * 8);
      qfB[c] = *(const short8*)(qrB + c * 32 + lk * 8);
    }
  }

  int kge[4], klb[4], vge[4], vlbA[4], vlbB[4];
#pragma unroll
  for (int i = 0; i < 4; ++i) {
    int c = i * 256 + tid;
    int kr = c >> 4, ks = c & 15;
    kge[i] = kr * (NKV * HD) + ks * 8;
    klb[i] = kr * 256 + ((ks ^ (kr & 7)) << 4);
    int vr = c >> 3, vs = c & 7;
    vge[i] = vr * T_ + vs * 8;
    int hh = vs >> 2, m = vs & 3, a = m >> 1;
    int sA = 8 * ((2 * m) & 3) + 4 * a;
    int sB = 8 * ((2 * m + 1) & 3) + 4 * a;
    int tA = 64 * hh + 2 * sA, tB = 64 * hh + 2 * sB;
    vlbA[i] = vr * 128 + (((tA >> 4) ^ (vr & 7)) << 4) + (tA & 15);
    vlbB[i] = vr * 128 + (((tB >> 4) ^ (vr & 7)) << 4) + (tB & 15);
  }
  const bf16* kpane = kn + (size_t)bi * T_ * (NKV * HD) + kvh * HD;
  const bf16* vpane = vT + (size_t)(bi * NKV + kvh) * HD * T_;

  short8 kreg[4], vreg[4];
  auto LOAD = [&](int jtx) {
    const bf16* kb = kpane + (size_t)(jtx << 6) * (NKV * HD);
    const bf16* vb = vpane + (jtx << 6);
#pragma unroll
    for (int i = 0; i < 4; ++i) kreg[i] = *(const short8*)(kb + kge[i]);
#pragma unroll
    for (int i = 0; i < 4; ++i) vreg[i] = *(const short8*)(vb + vge[i]);
  };
  auto WRITE = [&](int b) {
    char* kBuf = (char*)(&sK[b][0]);
    char* vBuf = (char*)(&sV[b][0]);
#pragma unroll
    for (int i = 0; i < 4; ++i) *(short8*)(kBuf + klb[i]) = kreg[i];
#pragma unroll
    for (int i = 0; i < 4; ++i) {
      union { short8 s8; short4v s4[2]; } u;
      u.s8 = vreg[i];
      *(short4v*)(vBuf + vlbA[i]) = u.s4[0];
      *(short4v*)(vBuf + vlbB[i]) = u.s4[1];
    }
  };

  f32x4 o0[8], o1[8];
#pragma unroll
  for (int i = 0; i < 8; ++i) {
    o0[i] = (f32x4){0.f, 0.f, 0.f, 0.f};
    o1[i] = (f32x4){0.f, 0.f, 0.f, 0.f};
  }
  float lp0 = 0.f, lp1 = 0.f;

  int jt0 = q0 >> 6;
  int hi = q0 + 126 + win; if (hi > T_ - 1) hi = T_ - 1;
  int jt1 = hi >> 6;

  LOAD(jt0);
  WRITE(0);
  if (jt0 < jt1) LOAD(jt0 + 1);
  asm volatile("s_waitcnt lgkmcnt(0)\n\ts_barrier" ::: "memory");

  int irow0 = q0 + w * 32 + lr;
  int klo = lk * 4;

  int p = 0;
  for (int jt = jt0; jt <= jt1; ++jt) {
    int j0 = jt << 6;

    // hoisted: write tile jt+1 into buf p^1 (overlaps with this tile's compute),
    // then issue loads of tile jt+2 into regs
    if (jt < jt1) {
      WRITE(p ^ 1);
      if (jt + 1 < jt1) LOAD(jt + 2);
    }

    const char* sKb = (const char*)(&sK[p][0]);
    const char* sVb = (const char*)(&sV[p][0]);

    f32x4 s0[4], s1[4];
#pragma unroll
    for (int sub = 0; sub < 4; ++sub) {
      s0[sub] = (f32x4){0.f, 0.f, 0.f, 0.f};
      s1[sub] = (f32x4){0.f, 0.f, 0.f, 0.f};
    }
    __builtin_amdgcn_s_setprio(1);
#pragma unroll
    for (int sub = 0; sub < 4; ++sub) {
      int kr = sub * 16 + lr;
      int rx = (kr & 7) << 4;
      const char* rowb = sKb + kr * 256;
#pragma unroll
      for (int c = 0; c < 4; ++c) {
        short8 kf = *(const short8*)(rowb + ((c * 64 + lk * 16) ^ rx));
        s0[sub] = __builtin_amdgcn_mfma_f32_16x16x32_bf16(kf, qfA[c], s0[sub], 0, 0, 0);
        s1[sub] = __builtin_amdgcn_mfma_f32_16x16x32_bf16(kf, qfB[c], s1[sub], 0, 0, 0);
      }
    }
    __builtin_amdgcn_s_setprio(0);

    bool full = (j0 >= q0 + 128) && (j0 + 64 <= q0 + win);
    int koff0 = j0 - irow0;
    int koff1 = koff0 - 16;

    short8 pA0, pA1, pB0, pB1;
    {
      unsigned pk[8];
#pragma unroll
      for (int sub = 0; sub < 4; ++sub) {
        float p0 = exp2f(s0[sub][0]), p1 = exp2f(s0[sub][1]);
        float p2 = exp2f(s0[sub][2]), p3 = exp2f(s0[sub][3]);
        if (!full) {
          int base = koff0 + sub * 16 + klo;
          p0 = ((unsigned)(base + 0) < (unsigned)win) ? p0 : 0.f;
          p1 = ((unsigned)(base + 1) < (unsigned)win) ? p1 : 0.f;
          p2 = ((unsigned)(base + 2) < (unsigned)win) ? p2 : 0.f;
          p3 = ((unsigned)(base + 3) < (unsigned)win) ? p3 : 0.f;
        }
        lp0 += (p0 + p1) + (p2 + p3);
        asm("v_cvt_pk_bf16_f32 %0, %1, %2" : "=v"(pk[sub * 2])     : "v"(p0), "v"(p1));
        asm("v_cvt_pk_bf16_f32 %0, %1, %2" : "=v"(pk[sub * 2 + 1]) : "v"(p2), "v"(p3));
      }
      union { unsigned u[4]; short8 s8; } c0, c1;
      c0.u[0] = pk[0]; c0.u[1] = pk[1]; c0.u[2] = pk[2]; c0.u[3] = pk[3];
      c1.u[0] = pk[4]; c1.u[1] = pk[5]; c1.u[2] = pk[6]; c1.u[3] = pk[7];
      pA0 = c0.s8; pA1 = c1.s8;
    }
    {
      unsigned pk[8];
#pragma unroll
      for (int sub = 0; sub < 4; ++sub) {
        float p0 = exp2f(s1[sub][0]), p1 = exp2f(s1[sub][1]);
        float p2 = exp2f(s1[sub][2]), p3 = exp2f(s1[sub][3]);
        if (!full) {
          int base = koff1 + sub * 16 + klo;
          p0 = ((unsigned)(base + 0) < (unsigned)win) ? p0 : 0.f;
          p1 = ((unsigned)(base + 1) < (unsigned)win) ? p1 : 0.f;
          p2 = ((unsigned)(base + 2) < (unsigned)win) ? p2 : 0.f;
          p3 = ((unsigned)(base + 3) < (unsigned)win) ? p3 : 0.f;
        }
        lp1 += (p0 + p1) + (p2 + p3);
        asm("v_cvt_pk_bf16_f32 %0, %1, %2" : "=v"(pk[sub * 2])     : "v"(p0), "v"(p1));
        asm("v_cvt_pk_bf16_f32 %0, %1, %2" : "=v"(pk[sub * 2 + 1]) : "v"(p2), "v"(p3));
      }
      union { unsigned u[4]; short8 s8; } c0, c1;
      c0.u[0] = pk[0]; c0.u[1] = pk[1]; c0.u[2] = pk[2]; c0.u[3] = pk[3];
      c1.u[0] = pk[4]; c1.u[1] = pk[5]; c1.u[2] = pk[6]; c1.u[3] = pk[7];
      pB0 = c0.s8; pB1 = c1.s8;
    }

    __builtin_amdgcn_s_setprio(1);
#pragma unroll
    for (int nb = 0; nb < 8; ++nb) {
      int vr = nb * 16 + lr;
      int vrx = (vr & 7) << 4;
      const char* vb = sVb + vr * 128;
      short8 vf0 = *(const short8*)(vb + ((lk * 16) ^ vrx));
      short8 vf1 = *(const short8*)(vb + ((64 + lk * 16) ^ vrx));
      o0[nb] = __builtin_amdgcn_mfma_f32_16x16x32_bf16(pA0, vf0, o0[nb], 0, 0, 0);
      o0[nb] = __builtin_amdgcn_mfma_f32_16x16x32_bf16(pA1, vf1, o0[nb], 0, 0, 0);
      o1[nb] = __builtin_amdgcn_mfma_f32_16x16x32_bf16(pB0, vf0, o1[nb], 0, 0, 0);
      o1[nb] = __builtin_amdgcn_mfma_f32_16x16x32_bf16(pB1, vf1, o1[nb], 0, 0, 0);
    }
    __builtin_amdgcn_s_setprio(0);

    // one barrier per tile: orders this tile's reads of buf p AND writes of p^1
    asm volatile("s_waitcnt lgkmcnt(0)\n\ts_barrier" ::: "memory");
    p ^= 1;
  }

  float l0 = lp0, l1 = lp1;
  l0 += __shfl_xor(l0, 16); l0 += __shfl_xor(l0, 32);
  l1 += __shfl_xor(l1, 16); l1 += __shfl_xor(l1, 32);
#pragma unroll
  for (int jj = 0; jj < 4; ++jj) {
    float inv0 = 1.f / __shfl(l0, klo + jj);
    float inv1 = 1.f / __shfl(l1, klo + jj);
    size_t ob0 = (size_t)(bi * T_ + q0 + w * 32 + klo + jj) * (NH * HD) + h * HD;
    size_t ob1 = ob0 + (size_t)16 * (NH * HD);
#pragma unroll
    for (int nb = 0; nb < 8; ++nb) {
      y[ob0 + nb * 16 + lr] = __float2bfloat16(o0[nb][jj] * inv0);
      y[ob1 + nb * 16 + lr] = __float2bfloat16(o1[nb][jj] * inv1);
    }
  }
}

extern "C" void kernel_launch(void* const* d_in, const int* in_sizes, int n_in,
                              void* d_out, int out_size, void* d_ws, size_t ws_size,
                              hipStream_t stream) {
  const float* x    = (const float*)d_in[0];
  const float* ve   = (const float*)d_in[1];
  const float* cosT = (const float*)d_in[2];
  const float* sinT = (const float*)d_in[3];
  const float* Wq   = (const float*)d_in[4];
  const float* Wk   = (const float*)d_in[5];
  const float* Wv   = (const float*)d_in[6];
  const float* Wg   = (const float*)d_in[7];
  const float* Wo   = (const float*)d_in[8];
  const int*   win  = (const int*)d_in[9];
  float* out = (float*)d_out;

  char* ws = (char*)d_ws;
  bf16*  xb   = (bf16*)(ws);
  bf16*  wT   = (bf16*)(ws + 16777216);
  bf16*  woT  = (bf16*)(ws + 29360128);
  bf16*  qkvb = (bf16*)(ws + 37748736);
  bf16*  qn   = (bf16*)(ws + 62914560);
  bf16*  kn   = (bf16*)(ws + 79691776);
  bf16*  vTb  = (bf16*)(ws + 83886080);
  bf16*  y    = qkvb;

  cast_x_kernel<<<8192, 256, 0, stream>>>((const float4*)x, (ushort4*)xb, 2097152);
  cast_transpose<<<dim3(64, 64), 256, 0, stream>>>(Wq, wT, 2048, 2048);
  cast_transpose<<<dim3(16, 64), 256, 0, stream>>>(Wk, wT + (size_t)2048 * 2048, 2048, 512);
  cast_transpose<<<dim3(16, 64), 256, 0, stream>>>(Wv, wT + (size_t)2560 * 2048, 2048, 512);
  cast_transpose<<<dim3(64, 64), 256, 0, stream>>>(Wo, woT, 2048, 2048);

  // QKV: 16x16 tiles of 256x192 -> 256 blocks (100% CU fill); regions 4x8
  gemm_pp<8, 3, bf16><<<256, 512, 0, stream>>>(xb, wT, qkvb, 3072, 2048, 4, 8);
  epilogue_kernel<<<4096, 256, 0, stream>>>(qkvb, x, ve, cosT, sinT, Wg, qn, kn, vTb);
  attn_kernel<<<512, 256, 0, stream>>>(qn, kn, vTb, y, win);
  // Wo: 32x8 tiles of 128x256 -> 256 blocks; regions 8x4
  gemm_pp<4, 4, float><<<256, 512, 0, stream>>>(y, woT, out, 2048, 2048, 8, 4);
}